// Round 7
// baseline (12405.398 us; speedup 1.0000x reference)
//
#include <hip/hip_runtime.h>
#include <hip/hip_bf16.h>
#include <math.h>

#define BATCH 256
#define LAT 100
#define NCLS 10
#define CIN0 110   // LAT + NCLS
#define C1 512
#define C2 256
#define C3 128
#define NCH 3
#define EPS 1e-5f

typedef __hip_bfloat16 bf16;

__device__ __forceinline__ float b2f(bf16 v) { return __bfloat162float(v); }
__device__ __forceinline__ bf16 f2b(float v) { return __float2bfloat16(v); }

// ---------------- build x0: concat(noise, emb[labels]) ----------------
__global__ void build_x0(const float* __restrict__ nre, const float* __restrict__ nim,
                         const int* __restrict__ labels, const float* __restrict__ emb,
                         float* __restrict__ x0r, float* __restrict__ x0i) {
    int idx = blockIdx.x * blockDim.x + threadIdx.x;
    if (idx >= BATCH * CIN0) return;
    int b = idx / CIN0, c = idx - b * CIN0;
    float r, im;
    if (c < LAT) { r = nre[b * LAT + c]; im = nim[b * LAT + c]; }
    else { r = emb[labels[b] * NCLS + (c - LAT)]; im = 0.f; }
    x0r[idx] = r; x0i[idx] = im;
}

// ---------------- layer1: 1x1 -> 4x4 convT == matmul over cin ----------------
__global__ void conv1(const float* __restrict__ x0r, const float* __restrict__ x0i,
                      const float* __restrict__ wr, const float* __restrict__ wi,
                      const float* __restrict__ br, const float* __restrict__ bi,
                      bf16* __restrict__ yr, bf16* __restrict__ yi) {
    int idx = blockIdx.x * blockDim.x + threadIdx.x;  // b*C1*16 + co*16 + p
    if (idx >= BATCH * C1 * 16) return;
    int p = idx & 15;
    int co = (idx >> 4) & (C1 - 1);
    int b = idx >> 13;  // / (C1*16)
    float accr = br[co], acci = bi[co];
    const float* xrb = x0r + b * CIN0;
    const float* xib = x0i + b * CIN0;
    for (int ci = 0; ci < CIN0; ++ci) {
        float xr = xrb[ci], xi = xib[ci];
        float wrv = wr[(ci * C1 + co) * 16 + p];
        float wiv = wi[(ci * C1 + co) * 16 + p];
        accr += xr * wrv - xi * wiv;
        acci += xr * wiv + xi * wrv;
    }
    yr[idx] = f2b(accr); yi[idx] = f2b(acci);
}

// ---------------- complex BN: stats + folded affine coeffs ----------------
// one block per channel; coef[c*6] = {a_rr, a_ri, c_r, a_ir, a_ii, c_i}
__global__ void bn_stats(const bf16* __restrict__ xr, const bf16* __restrict__ xi,
                         const float* __restrict__ grr, const float* __restrict__ gri,
                         const float* __restrict__ gii,
                         const float* __restrict__ br, const float* __restrict__ bi,
                         float* __restrict__ coef, int C, int HW) {
    int c = blockIdx.x;
    int N = BATCH * HW;
    float sr = 0.f, si = 0.f, srr = 0.f, sii = 0.f, sri = 0.f;
    for (int i = threadIdx.x; i < N; i += blockDim.x) {
        int b = i / HW, p = i - b * HW;
        int off = (b * C + c) * HW + p;
        float r = b2f(xr[off]), im = b2f(xi[off]);
        sr += r; si += im; srr += r * r; sii += im * im; sri += r * im;
    }
    for (int o = 32; o > 0; o >>= 1) {
        sr  += __shfl_down(sr, o, 64);
        si  += __shfl_down(si, o, 64);
        srr += __shfl_down(srr, o, 64);
        sii += __shfl_down(sii, o, 64);
        sri += __shfl_down(sri, o, 64);
    }
    __shared__ float sh[5][4];
    int wave = threadIdx.x >> 6, lane = threadIdx.x & 63;
    if (lane == 0) { sh[0][wave] = sr; sh[1][wave] = si; sh[2][wave] = srr; sh[3][wave] = sii; sh[4][wave] = sri; }
    __syncthreads();
    if (threadIdx.x == 0) {
        sr = sh[0][0] + sh[0][1] + sh[0][2] + sh[0][3];
        si = sh[1][0] + sh[1][1] + sh[1][2] + sh[1][3];
        srr = sh[2][0] + sh[2][1] + sh[2][2] + sh[2][3];
        sii = sh[3][0] + sh[3][1] + sh[3][2] + sh[3][3];
        sri = sh[4][0] + sh[4][1] + sh[4][2] + sh[4][3];
        float invN = 1.f / (float)N;
        float mr = sr * invN, mi = si * invN;
        float crr = srr * invN - mr * mr + EPS;
        float cii = sii * invN - mi * mi + EPS;
        float cri = sri * invN - mr * mi;
        float s = sqrtf(crr * cii - cri * cri);
        float t = sqrtf(crr + cii + 2.f * s);
        float inv = 1.f / (s * t);
        float rrr = (cii + s) * inv, rii = (crr + s) * inv, rri = -cri * inv;
        float Grr = grr[c], Gri = gri[c], Gii = gii[c];
        float arr = Grr * rrr + Gri * rri;
        float ari = Grr * rri + Gri * rii;
        float air = Gri * rrr + Gii * rri;
        float aii = Gri * rri + Gii * rii;
        coef[c * 6 + 0] = arr;
        coef[c * 6 + 1] = ari;
        coef[c * 6 + 2] = br[c] - arr * mr - ari * mi;
        coef[c * 6 + 3] = air;
        coef[c * 6 + 4] = aii;
        coef[c * 6 + 5] = bi[c] - air * mr - aii * mi;
    }
}

__global__ void bn_apply_relu(bf16* __restrict__ xr, bf16* __restrict__ xi,
                              const float* __restrict__ coef, int C, int HW, int total) {
    int idx = blockIdx.x * blockDim.x + threadIdx.x;
    if (idx >= total) return;
    int c = (idx / HW) % C;
    const float* k = coef + c * 6;
    float r = b2f(xr[idx]), im = b2f(xi[idx]);
    float orr = fmaxf(k[0] * r + k[1] * im + k[2], 0.f);
    float oii = fmaxf(k[3] * r + k[4] * im + k[5], 0.f);
    xr[idx] = f2b(orr); xi[idx] = f2b(oii);
}

// ---------------- stride-2 pad-1 k=4 complex convT (gather form) ----------------
__global__ void convt_s2(const bf16* __restrict__ xr, const bf16* __restrict__ xi,
                         const float* __restrict__ wr, const float* __restrict__ wi,
                         const float* __restrict__ bre, const float* __restrict__ bim,
                         bf16* __restrict__ yr, bf16* __restrict__ yi,
                         int Cin, int Hin, int Cout, int Hout) {
    int idx = blockIdx.x * blockDim.x + threadIdx.x;
    int total = BATCH * Cout * Hout * Hout;
    if (idx >= total) return;
    int ow = idx % Hout;
    int oh = (idx / Hout) % Hout;
    int co = (idx / (Hout * Hout)) % Cout;
    int b  = idx / (Hout * Hout * Cout);

    int khs[2], ihs[2], nh = 0;
    for (int kh = 0; kh < 4; ++kh) {
        int t = oh + 1 - kh;
        if (t >= 0 && !(t & 1)) { int ih = t >> 1; if (ih < Hin) { khs[nh] = kh; ihs[nh] = ih; ++nh; } }
    }
    int kws[2], iws[2], nw = 0;
    for (int kw = 0; kw < 4; ++kw) {
        int t = ow + 1 - kw;
        if (t >= 0 && !(t & 1)) { int iw = t >> 1; if (iw < Hin) { kws[nw] = kw; iws[nw] = iw; ++nw; } }
    }

    float accr = bre[co], acci = bim[co];
    for (int ci = 0; ci < Cin; ++ci) {
        const bf16* xrb = xr + (size_t)(b * Cin + ci) * Hin * Hin;
        const bf16* xib = xi + (size_t)(b * Cin + ci) * Hin * Hin;
        const float* wrb = wr + (size_t)(ci * Cout + co) * 16;
        const float* wib = wi + (size_t)(ci * Cout + co) * 16;
        for (int a = 0; a < nh; ++a) {
            int xoff = ihs[a] * Hin;
            int woff = khs[a] * 4;
            for (int e = 0; e < nw; ++e) {
                float xrv = b2f(xrb[xoff + iws[e]]);
                float xiv = b2f(xib[xoff + iws[e]]);
                float wrv = wrb[woff + kws[e]];
                float wiv = wib[woff + kws[e]];
                accr += xrv * wrv - xiv * wiv;
                acci += xrv * wiv + xiv * wrv;
            }
        }
    }
    yr[idx] = f2b(accr); yi[idx] = f2b(acci);
}

// ------- layer4 + tanh; OUTPUT = fp32, REAL PART ONLY (786,432 floats) -------
// complex64 ref -> harness "else" branch -> float*; numpy complex->float32
// cast discards imag. Buffer is exactly 786,432*4 = 3,145,728 B (R1/R2/R4
// 6.29MB writes crashed; 3.15MB writes never did).
__global__ void convt_s2_tanh(const bf16* __restrict__ xr, const bf16* __restrict__ xi,
                              const float* __restrict__ wr, const float* __restrict__ wi,
                              const float* __restrict__ bre, const float* __restrict__ bim,
                              float* __restrict__ out) {
    const int Cin = C3, Hin = 16, Cout = NCH, Hout = 32;
    int idx = blockIdx.x * blockDim.x + threadIdx.x;
    int total = BATCH * Cout * Hout * Hout;
    if (idx >= total) return;
    int ow = idx % Hout;
    int oh = (idx / Hout) % Hout;
    int co = (idx / (Hout * Hout)) % Cout;
    int b  = idx / (Hout * Hout * Cout);

    int khs[2], ihs[2], nh = 0;
    for (int kh = 0; kh < 4; ++kh) {
        int t = oh + 1 - kh;
        if (t >= 0 && !(t & 1)) { int ih = t >> 1; if (ih < Hin) { khs[nh] = kh; ihs[nh] = ih; ++nh; } }
    }
    int kws[2], iws[2], nw = 0;
    for (int kw = 0; kw < 4; ++kw) {
        int t = ow + 1 - kw;
        if (t >= 0 && !(t & 1)) { int iw = t >> 1; if (iw < Hin) { kws[nw] = kw; iws[nw] = iw; ++nw; } }
    }

    float accr = bre[co];
    for (int ci = 0; ci < Cin; ++ci) {
        const bf16* xrb = xr + (size_t)(b * Cin + ci) * Hin * Hin;
        const bf16* xib = xi + (size_t)(b * Cin + ci) * Hin * Hin;
        const float* wrb = wr + (size_t)(ci * Cout + co) * 16;
        const float* wib = wi + (size_t)(ci * Cout + co) * 16;
        for (int a = 0; a < nh; ++a) {
            int xoff = ihs[a] * Hin;
            int woff = khs[a] * 4;
            for (int e = 0; e < nw; ++e) {
                float xrv = b2f(xrb[xoff + iws[e]]);
                float xiv = b2f(xib[xoff + iws[e]]);
                float wrv = wrb[woff + kws[e]];
                float wiv = wib[woff + kws[e]];
                accr += xrv * wrv - xiv * wiv;
            }
        }
    }
    out[idx] = tanhf(accr);
}

extern "C" void kernel_launch(void* const* d_in, const int* in_sizes, int n_in,
                              void* d_out, int out_size, void* d_ws, size_t ws_size,
                              hipStream_t stream) {
    // DTYPE MAP (established R0-R6):
    //   inputs = fp32, labels = int32.
    //   output buffer = 3,145,728 bytes. complex64 reference -> harness
    //   'else' branch -> float* -> 786,432 fp32 = REAL PART ONLY (numpy
    //   complex->float32 cast drops imag). bf16 pair layouts (interleaved,
    //   planar) both gave full-scale error (R5: 1.68, R6: 1.63) — consistent
    //   with bf16 pairs being misread as fp32 words (bounded by ~2).
    const float* noise_re = (const float*)d_in[0];
    const float* noise_im = (const float*)d_in[1];
    const int*   labels   = (const int*)d_in[2];
    const float* emb      = (const float*)d_in[3];
    const float* w1r = (const float*)d_in[4],  *w1i = (const float*)d_in[5];
    const float* b1r = (const float*)d_in[6],  *b1i = (const float*)d_in[7];
    const float* g1rr = (const float*)d_in[8], *g1ri = (const float*)d_in[9], *g1ii = (const float*)d_in[10];
    const float* n1br = (const float*)d_in[11], *n1bi = (const float*)d_in[12];
    const float* w2r = (const float*)d_in[13], *w2i = (const float*)d_in[14];
    const float* b2r = (const float*)d_in[15], *b2i = (const float*)d_in[16];
    const float* g2rr = (const float*)d_in[17], *g2ri = (const float*)d_in[18], *g2ii = (const float*)d_in[19];
    const float* n2br = (const float*)d_in[20], *n2bi = (const float*)d_in[21];
    const float* w3r = (const float*)d_in[22], *w3i = (const float*)d_in[23];
    const float* b3r = (const float*)d_in[24], *b3i = (const float*)d_in[25];
    const float* g3rr = (const float*)d_in[26], *g3ri = (const float*)d_in[27], *g3ii = (const float*)d_in[28];
    const float* n3br = (const float*)d_in[29], *n3bi = (const float*)d_in[30];
    const float* w4r = (const float*)d_in[31], *w4i = (const float*)d_in[32];
    const float* b4r = (const float*)d_in[33], *b4i = (const float*)d_in[34];

    // Workspace layout byte-identical to R3/R5/R6 (proven to not fault):
    //   bf16 x2r [0,4194304) x2i [4194304,8388608)            (256*256*8*8)
    //   bf16 x1r [8388608,10485760) x1i [10485760,12582912)   (256*512*4*4)
    //   bf16 x3r [8388608,16777216) x3i [16777216,25165824)   (256*128*16*16, reuses dead x1)
    //   fp32 tail at byte 50331648: x0r, x0i, coef1/2/3. ~50.6 MB total.
    bf16* bws = (bf16*)d_ws;
    bf16* x2r = bws;
    bf16* x2i = bws + 4194304;
    bf16* x1r = bws + 8388608;
    bf16* x1i = bws + 10485760;
    bf16* x3r = bws + 8388608;
    bf16* x3i = bws + 16777216;
    float* fx = (float*)((char*)d_ws + 50331648);
    float* x0r = fx;
    float* x0i = x0r + BATCH * CIN0;
    float* coef1 = x0i + BATCH * CIN0;
    float* coef2 = coef1 + C1 * 6;
    float* coef3 = coef2 + C2 * 6;

    const int TB = 256;
    build_x0<<<(BATCH * CIN0 + TB - 1) / TB, TB, 0, stream>>>(noise_re, noise_im, labels, emb, x0r, x0i);

    conv1<<<(BATCH * C1 * 16) / TB, TB, 0, stream>>>(x0r, x0i, w1r, w1i, b1r, b1i, x1r, x1i);
    bn_stats<<<C1, TB, 0, stream>>>(x1r, x1i, g1rr, g1ri, g1ii, n1br, n1bi, coef1, C1, 16);
    bn_apply_relu<<<(BATCH * C1 * 16) / TB, TB, 0, stream>>>(x1r, x1i, coef1, C1, 16, BATCH * C1 * 16);

    convt_s2<<<(BATCH * C2 * 64) / TB, TB, 0, stream>>>(x1r, x1i, w2r, w2i, b2r, b2i, x2r, x2i, C1, 4, C2, 8);
    bn_stats<<<C2, TB, 0, stream>>>(x2r, x2i, g2rr, g2ri, g2ii, n2br, n2bi, coef2, C2, 64);
    bn_apply_relu<<<(BATCH * C2 * 64) / TB, TB, 0, stream>>>(x2r, x2i, coef2, C2, 64, BATCH * C2 * 64);

    convt_s2<<<(BATCH * C3 * 256) / TB, TB, 0, stream>>>(x2r, x2i, w3r, w3i, b3r, b3i, x3r, x3i, C2, 8, C3, 16);
    bn_stats<<<C3, TB, 0, stream>>>(x3r, x3i, g3rr, g3ri, g3ii, n3br, n3bi, coef3, C3, 256);
    bn_apply_relu<<<(BATCH * C3 * 256) / TB, TB, 0, stream>>>(x3r, x3i, coef3, C3, 256, BATCH * C3 * 256);

    convt_s2_tanh<<<(BATCH * NCH * 1024) / TB, TB, 0, stream>>>(x3r, x3i, w4r, w4i, b4r, b4i, (float*)d_out);
}

// Round 9
// 1626.799 us; speedup vs baseline: 7.6256x; 7.6256x over previous
//
#include <hip/hip_runtime.h>
#include <hip/hip_bf16.h>
#include <math.h>

#define BATCH 256
#define LAT 100
#define NCLS 10
#define CIN0 110
#define C1 512
#define C2 256
#define C3 128
#define NCH 3
#define EPS 1e-5f

typedef __hip_bfloat16 bf16;
typedef short bf16x8 __attribute__((ext_vector_type(8)));
typedef float f32x4 __attribute__((ext_vector_type(4)));

__device__ __forceinline__ float b2f(bf16 v) { return __bfloat162float(v); }
__device__ __forceinline__ bf16 f2b(float v) { return __float2bfloat16(v); }

// ---------------- build x0 ----------------
__global__ void build_x0(const float* __restrict__ nre, const float* __restrict__ nim,
                         const int* __restrict__ labels, const float* __restrict__ emb,
                         float* __restrict__ x0r, float* __restrict__ x0i) {
    int idx = blockIdx.x * blockDim.x + threadIdx.x;
    if (idx >= BATCH * CIN0) return;
    int b = idx / CIN0, c = idx - b * CIN0;
    float r, im;
    if (c < LAT) { r = nre[b * LAT + c]; im = nim[b * LAT + c]; }
    else { r = emb[labels[b] * NCLS + (c - LAT)]; im = 0.f; }
    x0r[idx] = r; x0i[idx] = im;
}

// ---------------- layer1 -> channels-last [b*16][1024] (real<512, imag>=512) ----------------
__global__ void conv1_cl(const float* __restrict__ x0r, const float* __restrict__ x0i,
                         const float* __restrict__ wr, const float* __restrict__ wi,
                         const float* __restrict__ br, const float* __restrict__ bi,
                         bf16* __restrict__ Y) {
    int idx = blockIdx.x * blockDim.x + threadIdx.x;
    if (idx >= BATCH * C1 * 16) return;
    int p = idx & 15;
    int co = (idx >> 4) & (C1 - 1);
    int b = idx >> 13;
    float accr = br[co], acci = bi[co];
    const float* xrb = x0r + b * CIN0;
    const float* xib = x0i + b * CIN0;
    for (int ci = 0; ci < CIN0; ++ci) {
        float xr = xrb[ci], xi = xib[ci];
        float wrv = wr[(ci * C1 + co) * 16 + p];
        float wiv = wi[(ci * C1 + co) * 16 + p];
        accr += xr * wrv - xi * wiv;
        acci += xr * wiv + xi * wrv;
    }
    size_t base = (size_t)(b * 16 + p) * 1024;
    Y[base + co] = f2b(accr);
    Y[base + 512 + co] = f2b(acci);
}

// ---------------- BN stats: lane=channel, atomics into stats[c*5..] ----------------
__global__ void bn_stats_cl(const bf16* __restrict__ Y, float* __restrict__ stats,
                            int C, int rowsPerThread) {
    int c = blockIdx.x * 64 + (threadIdx.x & 63);
    int CC = 2 * C;
    long r0 = (long)(blockIdx.y * 4 + (threadIdx.x >> 6)) * rowsPerThread;
    float sr = 0, si = 0, srr = 0, sii = 0, sri = 0;
    for (int r = 0; r < rowsPerThread; ++r) {
        size_t base = (size_t)(r0 + r) * CC;
        float vr = b2f(Y[base + c]);
        float vi = b2f(Y[base + C + c]);
        sr += vr; si += vi; srr += vr * vr; sii += vi * vi; sri += vr * vi;
    }
    atomicAdd(&stats[c * 5 + 0], sr);
    atomicAdd(&stats[c * 5 + 1], si);
    atomicAdd(&stats[c * 5 + 2], srr);
    atomicAdd(&stats[c * 5 + 3], sii);
    atomicAdd(&stats[c * 5 + 4], sri);
}

__global__ void bn_coef(const float* __restrict__ stats,
                        const float* __restrict__ grr, const float* __restrict__ gri,
                        const float* __restrict__ gii,
                        const float* __restrict__ betar, const float* __restrict__ betai,
                        float* __restrict__ coef, int C, float invN) {
    int c = blockIdx.x * blockDim.x + threadIdx.x;
    if (c >= C) return;
    float sr = stats[c*5+0], si = stats[c*5+1], srr = stats[c*5+2], sii = stats[c*5+3], sri = stats[c*5+4];
    float mr = sr * invN, mi = si * invN;
    float crr = srr * invN - mr * mr + EPS;
    float cii = sii * invN - mi * mi + EPS;
    float cri = sri * invN - mr * mi;
    float s = sqrtf(crr * cii - cri * cri);
    float t = sqrtf(crr + cii + 2.f * s);
    float inv = 1.f / (s * t);
    float rrr = (cii + s) * inv, rii = (crr + s) * inv, rri = -cri * inv;
    float Grr = grr[c], Gri = gri[c], Gii = gii[c];
    float arr = Grr * rrr + Gri * rri, ari = Grr * rri + Gri * rii;
    float air = Gri * rrr + Gii * rri, aii = Gri * rri + Gii * rii;
    coef[c*6+0] = arr; coef[c*6+1] = ari; coef[c*6+2] = betar[c] - arr * mr - ari * mi;
    coef[c*6+3] = air; coef[c*6+4] = aii; coef[c*6+5] = betai[c] - air * mr - aii * mi;
}

__global__ void bn_apply_cl(bf16* __restrict__ Y, const float* __restrict__ coef,
                            int C, size_t total) {
    size_t idx = (size_t)blockIdx.x * 256 + threadIdx.x;
    if (idx >= total) return;
    int c = (int)(idx % C);
    size_t base = (idx / C) * 2 * C;
    const float* k = coef + c * 6;
    float vr = b2f(Y[base + c]), vi = b2f(Y[base + C + c]);
    float orr = fmaxf(k[0] * vr + k[1] * vi + k[2], 0.f);
    float oii = fmaxf(k[3] * vr + k[4] * vi + k[5], 0.f);
    Y[base + c] = f2b(orr); Y[base + C + c] = f2b(oii);
}

// ---------------- W' prep: [2N][2K] bf16, k-contiguous, per class ----------------
__global__ void wprep(const float* __restrict__ wr, const float* __restrict__ wi,
                      bf16* __restrict__ W, int CIN, int N, int py, int px) {
    int K = 4 * CIN, TWOK = 8 * CIN;
    int idx = blockIdx.x * 256 + threadIdx.x;
    if (idx >= 2 * N * TWOK) return;
    int n = idx / TWOK, k = idx - n * TWOK;
    int p = k >= K; int kk = k - p * K;
    int t = kk / CIN, ci = kk - t * CIN;
    int a = t >> 1, e = t & 1;
    int kh = py ? (a ? 2 : 0) : (a ? 3 : 1);
    int kw = px ? (e ? 2 : 0) : (e ? 3 : 1);
    int co = (n < N) ? n : n - N;
    size_t widx = ((size_t)ci * N + co) * 16 + kh * 4 + kw;
    float vr = wr[widx], vi = wi[widx];
    float v = (n < N) ? (p ? -vi : vr) : (p ? vr : vi);
    W[idx] = f2b(v);
}

// ---------------- MFMA GEMM for one parity class of a stride-2 convT ----------------
// X: [B][S][S][2*CIN] (bf16, BN-applied). W: [2N][2K] bf16. Y: [B][2S][2S][2N].
template<int CIN, int S, int N>
__global__ __launch_bounds__(256, 1) void gemm_convt(
    const bf16* __restrict__ X, const bf16* __restrict__ W,
    const float* __restrict__ biasr, const float* __restrict__ biasi,
    bf16* __restrict__ Y, int py, int px) {
    constexpr int K = 4 * CIN, TWOK = 8 * CIN, C2I = 2 * CIN, C2O = 2 * N, HOUT = 2 * S;
    __shared__ short As[128][40];
    __shared__ short Bs[128][40];
    const int tid = threadIdx.x;
    const int mBase = blockIdx.x * 128, nBase = blockIdx.y * 128;
    const int wid = tid >> 6, lane = tid & 63;
    const int wm = (wid >> 1) * 64, wn = (wid & 1) * 64;
    const int lm = lane & 15, lq = lane >> 4;
    const int dh0 = py ? 1 : 0, dh1 = py ? 0 : -1;
    const int dw0 = px ? 1 : 0, dw1 = px ? 0 : -1;

    f32x4 acc[4][4] = {};

    for (int k0 = 0; k0 < TWOK; k0 += 32) {
#pragma unroll
        for (int it = 0; it < 2; ++it) {
            int slot = tid + it * 256;          // 512 slots of 8 bf16
            int row = slot >> 2, kc = (slot & 3) * 8;
            int k = k0 + kc;
            int p = k >= K; int kk = k - p * K;
            int t = kk / CIN, ci = kk - t * CIN;
            int a = t >> 1, e = t & 1;
            int m = mBase + row;
            int b = m / (S * S); int rem = m - b * (S * S);
            int i = rem / S, j = rem % S;
            int ih = i + (a ? dh1 : dh0);
            int iw = j + (e ? dw1 : dw0);
            uint4 v = {0u, 0u, 0u, 0u};
            if ((unsigned)ih < (unsigned)S && (unsigned)iw < (unsigned)S)
                v = *(const uint4*)(X + ((size_t)((b * S + ih) * S + iw) * C2I + p * CIN + ci));
            *(uint4*)(&As[row][kc]) = v;
            uint4 w = *(const uint4*)(W + (size_t)(nBase + row) * TWOK + k);
            *(uint4*)(&Bs[row][kc]) = w;
        }
        __syncthreads();
        bf16x8 af[4], bfr[4];
#pragma unroll
        for (int s = 0; s < 4; ++s) {
            af[s]  = *(const bf16x8*)(&As[wm + s * 16 + lm][lq * 8]);
            bfr[s] = *(const bf16x8*)(&Bs[wn + s * 16 + lm][lq * 8]);
        }
#pragma unroll
        for (int sm = 0; sm < 4; ++sm)
#pragma unroll
            for (int sn = 0; sn < 4; ++sn)
                acc[sm][sn] = __builtin_amdgcn_mfma_f32_16x16x32_bf16(af[sm], bfr[sn], acc[sm][sn], 0, 0, 0);
        __syncthreads();
    }

    // epilogue: C/D layout col=lane&15 (=n), row=quad*4+v (=m)
#pragma unroll
    for (int sm = 0; sm < 4; ++sm) {
#pragma unroll
        for (int v = 0; v < 4; ++v) {
            int m = mBase + wm + sm * 16 + lq * 4 + v;
            int b = m / (S * S); int rem = m - b * (S * S);
            int i = rem / S, j = rem % S;
            int oh = 2 * i + py, ow = 2 * j + px;
            size_t rowoff = (size_t)((b * HOUT + oh) * HOUT + ow) * C2O;
#pragma unroll
            for (int sn = 0; sn < 4; ++sn) {
                int n = nBase + wn + sn * 16 + lm;
                float bias = (n < N) ? biasr[n] : biasi[n - N];
                Y[rowoff + n] = f2b(acc[sm][sn][v] + bias);
            }
        }
    }
}

// ---------------- layer4 + tanh, real part only, fp32 out ----------------
__global__ void conv4_tanh(const bf16* __restrict__ X, const float* __restrict__ wr,
                           const float* __restrict__ wi, const float* __restrict__ br,
                           float* __restrict__ out) {
    int idx = blockIdx.x * 256 + threadIdx.x;
    if (idx >= BATCH * NCH * 1024) return;
    int ow = idx & 31, oh = (idx >> 5) & 31;
    int co = (idx >> 10) % NCH, b = idx / (NCH * 1024);
    int i = oh >> 1, py = oh & 1, j = ow >> 1, px = ow & 1;
    float acc = br[co];
    for (int a = 0; a < 2; ++a) {
        int ih = i + (a ? (py ? 0 : -1) : (py ? 1 : 0));
        if ((unsigned)ih >= 16u) continue;
        int kh = py ? (a ? 2 : 0) : (a ? 3 : 1);
        for (int e = 0; e < 2; ++e) {
            int iw = j + (e ? (px ? 0 : -1) : (px ? 1 : 0));
            if ((unsigned)iw >= 16u) continue;
            int kw = px ? (e ? 2 : 0) : (e ? 3 : 1);
            const bf16* xp = X + (size_t)((b * 16 + ih) * 16 + iw) * 256;
            const float* wrp = wr + (co * 16 + kh * 4 + kw);
            const float* wip = wi + (co * 16 + kh * 4 + kw);
            for (int ci = 0; ci < 128; ++ci) {
                acc += b2f(xp[ci]) * wrp[(size_t)ci * 48] - b2f(xp[128 + ci]) * wip[(size_t)ci * 48];
            }
        }
    }
    out[idx] = tanhf(acc);
}

extern "C" void kernel_launch(void* const* d_in, const int* in_sizes, int n_in,
                              void* d_out, int out_size, void* d_ws, size_t ws_size,
                              hipStream_t stream) {
    const float* noise_re = (const float*)d_in[0];
    const float* noise_im = (const float*)d_in[1];
    const int*   labels   = (const int*)d_in[2];
    const float* emb      = (const float*)d_in[3];
    const float* w1r = (const float*)d_in[4],  *w1i = (const float*)d_in[5];
    const float* b1r = (const float*)d_in[6],  *b1i = (const float*)d_in[7];
    const float* g1rr = (const float*)d_in[8], *g1ri = (const float*)d_in[9], *g1ii = (const float*)d_in[10];
    const float* n1br = (const float*)d_in[11], *n1bi = (const float*)d_in[12];
    const float* w2r = (const float*)d_in[13], *w2i = (const float*)d_in[14];
    const float* b2r = (const float*)d_in[15], *b2i = (const float*)d_in[16];
    const float* g2rr = (const float*)d_in[17], *g2ri = (const float*)d_in[18], *g2ii = (const float*)d_in[19];
    const float* n2br = (const float*)d_in[20], *n2bi = (const float*)d_in[21];
    const float* w3r = (const float*)d_in[22], *w3i = (const float*)d_in[23];
    const float* b3r = (const float*)d_in[24], *b3i = (const float*)d_in[25];
    const float* g3rr = (const float*)d_in[26], *g3ri = (const float*)d_in[27], *g3ii = (const float*)d_in[28];
    const float* n3br = (const float*)d_in[29], *n3bi = (const float*)d_in[30];
    const float* w4r = (const float*)d_in[31], *w4i = (const float*)d_in[32];
    const float* b4r = (const float*)d_in[33], *b4i = (const float*)d_in[34];

    // ---- workspace layout (bytes) ----
    // [0, 33554432)         y3cl  [256][16][16][256] bf16
    //    overlay: x1cl [0, 8388608)  (dead before gemm3 writes y3cl)
    //    overlay: x0 fp32 [8388608, 8833888)  (dead after conv1)
    // [33554432, 50331648)  y2cl  [256][8][8][512] bf16
    // [50331648, 54525952)  W' class buffer (max 4,194,304 B for L2)
    // [54525952, ...)       fp32 tail: stats(10240B) coef1/2/3
    char* ws = (char*)d_ws;
    bf16* y3cl = (bf16*)ws;
    bf16* x1cl = (bf16*)ws;
    float* x0r = (float*)(ws + 8388608);
    float* x0i = x0r + BATCH * CIN0;
    bf16* y2cl = (bf16*)(ws + 33554432);
    bf16* Wbuf = (bf16*)(ws + 50331648);
    float* stats = (float*)(ws + 54525952);
    float* coef1 = stats + 2560;          // 512*5 floats max for stats
    float* coef2 = coef1 + C1 * 6;
    float* coef3 = coef2 + C2 * 6;

    build_x0<<<110, 256, 0, stream>>>(noise_re, noise_im, labels, emb, x0r, x0i);
    conv1_cl<<<8192, 256, 0, stream>>>(x0r, x0i, w1r, w1i, b1r, b1i, x1cl);

    // BN1 (C=512, rows=4096)
    (void)hipMemsetAsync(stats, 0, 2560 * sizeof(float), stream);
    bn_stats_cl<<<dim3(8, 16), 256, 0, stream>>>(x1cl, stats, C1, 64);
    bn_coef<<<2, 256, 0, stream>>>(stats, g1rr, g1ri, g1ii, n1br, n1bi, coef1, C1, 1.f / 4096.f);
    bn_apply_cl<<<8192, 256, 0, stream>>>(x1cl, coef1, C1, (size_t)4096 * C1);

    // L2: 4 classes, Cin=512, S=4, N=256
    for (int cls = 0; cls < 4; ++cls) {
        int py = cls >> 1, px = cls & 1;
        wprep<<<8192, 256, 0, stream>>>(w2r, w2i, Wbuf, C1, C2, py, px);
        gemm_convt<C1, 4, C2><<<dim3(32, 4), 256, 0, stream>>>(x1cl, Wbuf, b2r, b2i, y2cl, py, px);
    }

    // BN2 (C=256, rows=16384)
    (void)hipMemsetAsync(stats, 0, 2560 * sizeof(float), stream);
    bn_stats_cl<<<dim3(4, 16), 256, 0, stream>>>(y2cl, stats, C2, 256);
    bn_coef<<<1, 256, 0, stream>>>(stats, g2rr, g2ri, g2ii, n2br, n2bi, coef2, C2, 1.f / 16384.f);
    bn_apply_cl<<<16384, 256, 0, stream>>>(y2cl, coef2, C2, (size_t)16384 * C2);

    // L3: 4 classes, Cin=256, S=8, N=128
    for (int cls = 0; cls < 4; ++cls) {
        int py = cls >> 1, px = cls & 1;
        wprep<<<2048, 256, 0, stream>>>(w3r, w3i, Wbuf, C2, C3, py, px);
        gemm_convt<C2, 8, C3><<<dim3(128, 2), 256, 0, stream>>>(y2cl, Wbuf, b3r, b3i, y3cl, py, px);
    }

    // BN3 (C=128, rows=65536)
    (void)hipMemsetAsync(stats, 0, 2560 * sizeof(float), stream);
    bn_stats_cl<<<dim3(2, 64), 256, 0, stream>>>(y3cl, stats, C3, 256);
    bn_coef<<<1, 256, 0, stream>>>(stats, g3rr, g3ri, g3ii, n3br, n3bi, coef3, C3, 1.f / 65536.f);
    bn_apply_cl<<<32768, 256, 0, stream>>>(y3cl, coef3, C3, (size_t)65536 * C3);

    conv4_tanh<<<3072, 256, 0, stream>>>(y3cl, w4r, w4i, b4r, (float*)d_out);
}

// Round 10
// 881.015 us; speedup vs baseline: 14.0808x; 1.8465x over previous
//
#include <hip/hip_runtime.h>
#include <hip/hip_bf16.h>
#include <math.h>

#define BATCH 256
#define LAT 100
#define NCLS 10
#define CIN0 110
#define C1 512
#define C2 256
#define C3 128
#define NCH 3
#define EPS 1e-5f

typedef __hip_bfloat16 bf16;
typedef short bf16x8 __attribute__((ext_vector_type(8)));
typedef float f32x4 __attribute__((ext_vector_type(4)));

__device__ __forceinline__ float b2f(bf16 v) { return __bfloat162float(v); }
__device__ __forceinline__ bf16 f2b(float v) { return __float2bfloat16(v); }

// ---------------- build x0 ----------------
__global__ void build_x0(const float* __restrict__ nre, const float* __restrict__ nim,
                         const int* __restrict__ labels, const float* __restrict__ emb,
                         float* __restrict__ x0r, float* __restrict__ x0i) {
    int idx = blockIdx.x * blockDim.x + threadIdx.x;
    if (idx >= BATCH * CIN0) return;
    int b = idx / CIN0, c = idx - b * CIN0;
    float r, im;
    if (c < LAT) { r = nre[b * LAT + c]; im = nim[b * LAT + c]; }
    else { r = emb[labels[b] * NCLS + (c - LAT)]; im = 0.f; }
    x0r[idx] = r; x0i[idx] = im;
}

// ---------------- layer1 -> channels-last [b*16][1024] (real<512, imag>=512) ----------------
__global__ void conv1_cl(const float* __restrict__ x0r, const float* __restrict__ x0i,
                         const float* __restrict__ wr, const float* __restrict__ wi,
                         const float* __restrict__ br, const float* __restrict__ bi,
                         bf16* __restrict__ Y) {
    int idx = blockIdx.x * blockDim.x + threadIdx.x;
    if (idx >= BATCH * C1 * 16) return;
    int p = idx & 15;
    int co = (idx >> 4) & (C1 - 1);
    int b = idx >> 13;
    float accr = br[co], acci = bi[co];
    const float* xrb = x0r + b * CIN0;
    const float* xib = x0i + b * CIN0;
    for (int ci = 0; ci < CIN0; ++ci) {
        float xr = xrb[ci], xi = xib[ci];
        float wrv = wr[(ci * C1 + co) * 16 + p];
        float wiv = wi[(ci * C1 + co) * 16 + p];
        accr += xr * wrv - xi * wiv;
        acci += xr * wiv + xi * wrv;
    }
    size_t base = (size_t)(b * 16 + p) * 1024;
    Y[base + co] = f2b(accr);
    Y[base + 512 + co] = f2b(acci);
}

// ---------------- BN stats: lane=channel, atomics into stats[c*5..] ----------------
__global__ void bn_stats_cl(const bf16* __restrict__ Y, float* __restrict__ stats,
                            int C, int rowsPerThread) {
    int c = blockIdx.x * 64 + (threadIdx.x & 63);
    int CC = 2 * C;
    long r0 = (long)(blockIdx.y * 4 + (threadIdx.x >> 6)) * rowsPerThread;
    float sr = 0, si = 0, srr = 0, sii = 0, sri = 0;
    for (int r = 0; r < rowsPerThread; ++r) {
        size_t base = (size_t)(r0 + r) * CC;
        float vr = b2f(Y[base + c]);
        float vi = b2f(Y[base + C + c]);
        sr += vr; si += vi; srr += vr * vr; sii += vi * vi; sri += vr * vi;
    }
    atomicAdd(&stats[c * 5 + 0], sr);
    atomicAdd(&stats[c * 5 + 1], si);
    atomicAdd(&stats[c * 5 + 2], srr);
    atomicAdd(&stats[c * 5 + 3], sii);
    atomicAdd(&stats[c * 5 + 4], sri);
}

__global__ void bn_coef(const float* __restrict__ stats,
                        const float* __restrict__ grr, const float* __restrict__ gri,
                        const float* __restrict__ gii,
                        const float* __restrict__ betar, const float* __restrict__ betai,
                        float* __restrict__ coef, int C, float invN) {
    int c = blockIdx.x * blockDim.x + threadIdx.x;
    if (c >= C) return;
    float sr = stats[c*5+0], si = stats[c*5+1], srr = stats[c*5+2], sii = stats[c*5+3], sri = stats[c*5+4];
    float mr = sr * invN, mi = si * invN;
    float crr = srr * invN - mr * mr + EPS;
    float cii = sii * invN - mi * mi + EPS;
    float cri = sri * invN - mr * mi;
    float s = sqrtf(crr * cii - cri * cri);
    float t = sqrtf(crr + cii + 2.f * s);
    float inv = 1.f / (s * t);
    float rrr = (cii + s) * inv, rii = (crr + s) * inv, rri = -cri * inv;
    float Grr = grr[c], Gri = gri[c], Gii = gii[c];
    float arr = Grr * rrr + Gri * rri, ari = Grr * rri + Gri * rii;
    float air = Gri * rrr + Gii * rri, aii = Gri * rri + Gii * rii;
    coef[c*6+0] = arr; coef[c*6+1] = ari; coef[c*6+2] = betar[c] - arr * mr - ari * mi;
    coef[c*6+3] = air; coef[c*6+4] = aii; coef[c*6+5] = betai[c] - air * mr - aii * mi;
}

__global__ void bn_apply_cl(bf16* __restrict__ Y, const float* __restrict__ coef,
                            int C, size_t total) {
    size_t idx = (size_t)blockIdx.x * 256 + threadIdx.x;
    if (idx >= total) return;
    int c = (int)(idx % C);
    size_t base = (idx / C) * 2 * C;
    const float* k = coef + c * 6;
    float vr = b2f(Y[base + c]), vi = b2f(Y[base + C + c]);
    float orr = fmaxf(k[0] * vr + k[1] * vi + k[2], 0.f);
    float oii = fmaxf(k[3] * vr + k[4] * vi + k[5], 0.f);
    Y[base + c] = f2b(orr); Y[base + C + c] = f2b(oii);
}

// ---------------- W' prep, ALL 4 classes: Wall[cls][2N][2K] bf16 ----------------
__global__ void wprep_all(const float* __restrict__ wr, const float* __restrict__ wi,
                          bf16* __restrict__ W, int CIN, int N) {
    int K = 4 * CIN, TWOK = 8 * CIN;
    size_t per = (size_t)2 * N * TWOK;
    size_t idx = (size_t)blockIdx.x * 256 + threadIdx.x;
    if (idx >= 4 * per) return;
    int cls = (int)(idx / per);
    int rem = (int)(idx - (size_t)cls * per);
    int py = cls >> 1, px = cls & 1;
    int n = rem / TWOK, k = rem - n * TWOK;
    int p = k >= K; int kk = k - p * K;
    int t = kk / CIN, ci = kk - t * CIN;
    int a = t >> 1, e = t & 1;
    int kh = py ? (a ? 2 : 0) : (a ? 3 : 1);
    int kw = px ? (e ? 2 : 0) : (e ? 3 : 1);
    int co = (n < N) ? n : n - N;
    size_t widx = ((size_t)ci * N + co) * 16 + kh * 4 + kw;
    float vr = wr[widx], vi = wi[widx];
    float v = (n < N) ? (p ? -vi : vr) : (p ? vr : vi);
    W[idx] = f2b(v);
}

// ---- W4 prep: real-part-only, Wall[cls][16][1024], n>=3 zero-padded ----
__global__ void wprep4(const float* __restrict__ wr, const float* __restrict__ wi,
                       bf16* __restrict__ W) {
    int idx = blockIdx.x * 256 + threadIdx.x;   // 4*16*1024 = 65536
    if (idx >= 65536) return;
    int cls = idx >> 14, rem = idx & 16383;
    int py = cls >> 1, px = cls & 1;
    int n = rem >> 10, k = rem & 1023;
    float v = 0.f;
    if (n < NCH) {
        int p = k >= 512; int kk = k - p * 512;
        int t = kk >> 7, ci = kk & 127;
        int a = t >> 1, e = t & 1;
        int kh = py ? (a ? 2 : 0) : (a ? 3 : 1);
        int kw = px ? (e ? 2 : 0) : (e ? 3 : 1);
        size_t widx = ((size_t)ci * NCH + n) * 16 + kh * 4 + kw;
        v = p ? -wi[widx] : wr[widx];
    }
    W[idx] = f2b(v);
}

// ---------------- MFMA GEMM, all 4 parity classes via blockIdx.z ----------------
// X: [B][S][S][2*CIN]. Wall: [4][2N][2K]. Y: [B][2S][2S][2N].
template<int CIN, int S, int N>
__global__ __launch_bounds__(256, 1) void gemm_convt(
    const bf16* __restrict__ X, const bf16* __restrict__ Wall,
    const float* __restrict__ biasr, const float* __restrict__ biasi,
    bf16* __restrict__ Y) {
    constexpr int K = 4 * CIN, TWOK = 8 * CIN, C2I = 2 * CIN, C2O = 2 * N, HOUT = 2 * S;
    __shared__ short As[128][40];
    __shared__ short Bs[128][40];
    const int cls = blockIdx.z;
    const int py = cls >> 1, px = cls & 1;
    const bf16* W = Wall + (size_t)cls * 2 * N * TWOK;
    const int tid = threadIdx.x;
    const int mBase = blockIdx.x * 128, nBase = blockIdx.y * 128;
    const int wid = tid >> 6, lane = tid & 63;
    const int wm = (wid >> 1) * 64, wn = (wid & 1) * 64;
    const int lm = lane & 15, lq = lane >> 4;
    const int dh0 = py ? 1 : 0, dh1 = py ? 0 : -1;
    const int dw0 = px ? 1 : 0, dw1 = px ? 0 : -1;

    f32x4 acc[4][4] = {};

    for (int k0 = 0; k0 < TWOK; k0 += 32) {
#pragma unroll
        for (int it = 0; it < 2; ++it) {
            int slot = tid + it * 256;
            int row = slot >> 2, kc = (slot & 3) * 8;
            int k = k0 + kc;
            int p = k >= K; int kk = k - p * K;
            int t = kk / CIN, ci = kk - t * CIN;
            int a = t >> 1, e = t & 1;
            int m = mBase + row;
            int b = m / (S * S); int rem = m - b * (S * S);
            int i = rem / S, j = rem % S;
            int ih = i + (a ? dh1 : dh0);
            int iw = j + (e ? dw1 : dw0);
            uint4 v = {0u, 0u, 0u, 0u};
            if ((unsigned)ih < (unsigned)S && (unsigned)iw < (unsigned)S)
                v = *(const uint4*)(X + ((size_t)((b * S + ih) * S + iw) * C2I + p * CIN + ci));
            *(uint4*)(&As[row][kc]) = v;
            uint4 w = *(const uint4*)(W + (size_t)(nBase + row) * TWOK + k);
            *(uint4*)(&Bs[row][kc]) = w;
        }
        __syncthreads();
        bf16x8 af[4], bfr[4];
#pragma unroll
        for (int s = 0; s < 4; ++s) {
            af[s]  = *(const bf16x8*)(&As[wm + s * 16 + lm][lq * 8]);
            bfr[s] = *(const bf16x8*)(&Bs[wn + s * 16 + lm][lq * 8]);
        }
#pragma unroll
        for (int sm = 0; sm < 4; ++sm)
#pragma unroll
            for (int sn = 0; sn < 4; ++sn)
                acc[sm][sn] = __builtin_amdgcn_mfma_f32_16x16x32_bf16(af[sm], bfr[sn], acc[sm][sn], 0, 0, 0);
        __syncthreads();
    }

#pragma unroll
    for (int sm = 0; sm < 4; ++sm) {
#pragma unroll
        for (int v = 0; v < 4; ++v) {
            int m = mBase + wm + sm * 16 + lq * 4 + v;
            int b = m / (S * S); int rem = m - b * (S * S);
            int i = rem / S, j = rem % S;
            int oh = 2 * i + py, ow = 2 * j + px;
            size_t rowoff = (size_t)((b * HOUT + oh) * HOUT + ow) * C2O;
#pragma unroll
            for (int sn = 0; sn < 4; ++sn) {
                int n = nBase + wn + sn * 16 + lm;
                float bias = (n < N) ? biasr[n] : biasi[n - N];
                Y[rowoff + n] = f2b(acc[sm][sn][v] + bias);
            }
        }
    }
}

// ---------------- layer4 via MFMA: N-tile 16 (3 channels + pad), real-part only ----------------
__global__ __launch_bounds__(256, 2) void conv4_mfma(
    const bf16* __restrict__ X, const bf16* __restrict__ Wall,
    const float* __restrict__ br, float* __restrict__ out) {
    constexpr int CIN = 128, S = 16, K = 512, TWOK = 1024, C2I = 256;
    __shared__ short As[128][40];
    __shared__ short Bs[16][40];
    const int cls = blockIdx.z;
    const int py = cls >> 1, px = cls & 1;
    const bf16* W = Wall + (size_t)cls * 16 * TWOK;
    const int tid = threadIdx.x;
    const int mBase = blockIdx.x * 128;
    const int wid = tid >> 6, lane = tid & 63;
    const int wm = wid * 32;
    const int lm = lane & 15, lq = lane >> 4;
    const int dh0 = py ? 1 : 0, dh1 = py ? 0 : -1;
    const int dw0 = px ? 1 : 0, dw1 = px ? 0 : -1;

    f32x4 acc[2] = {};

    for (int k0 = 0; k0 < TWOK; k0 += 32) {
#pragma unroll
        for (int it = 0; it < 2; ++it) {
            int slot = tid + it * 256;
            int row = slot >> 2, kc = (slot & 3) * 8;
            int k = k0 + kc;
            int p = k >= K; int kk = k - p * K;
            int t = kk >> 7, ci = kk & 127;
            int a = t >> 1, e = t & 1;
            int m = mBase + row;
            int b = m >> 8; int rem = m & 255;
            int i = rem >> 4, j = rem & 15;
            int ih = i + (a ? dh1 : dh0);
            int iw = j + (e ? dw1 : dw0);
            uint4 v = {0u, 0u, 0u, 0u};
            if ((unsigned)ih < (unsigned)S && (unsigned)iw < (unsigned)S)
                v = *(const uint4*)(X + ((size_t)((b * S + ih) * S + iw) * C2I + p * CIN + ci));
            *(uint4*)(&As[row][kc]) = v;
        }
        if (tid < 64) {
            int row = tid >> 2, kc = (tid & 3) * 8;
            uint4 w = *(const uint4*)(W + (size_t)row * TWOK + k0 + kc);
            *(uint4*)(&Bs[row][kc]) = w;
        }
        __syncthreads();
        bf16x8 bfr = *(const bf16x8*)(&Bs[lm][lq * 8]);
        bf16x8 af0 = *(const bf16x8*)(&As[wm + lm][lq * 8]);
        bf16x8 af1 = *(const bf16x8*)(&As[wm + 16 + lm][lq * 8]);
        acc[0] = __builtin_amdgcn_mfma_f32_16x16x32_bf16(af0, bfr, acc[0], 0, 0, 0);
        acc[1] = __builtin_amdgcn_mfma_f32_16x16x32_bf16(af1, bfr, acc[1], 0, 0, 0);
        __syncthreads();
    }

    int n = lm;
    if (n < NCH) {
        float bias = br[n];
#pragma unroll
        for (int s = 0; s < 2; ++s) {
#pragma unroll
            for (int v = 0; v < 4; ++v) {
                int m = mBase + wm + s * 16 + lq * 4 + v;
                int b = m >> 8; int rem = m & 255;
                int i = rem >> 4, j = rem & 15;
                int oh = 2 * i + py, ow = 2 * j + px;
                out[((size_t)(b * NCH + n) * 32 + oh) * 32 + ow] = tanhf(acc[s][v] + bias);
            }
        }
    }
}

extern "C" void kernel_launch(void* const* d_in, const int* in_sizes, int n_in,
                              void* d_out, int out_size, void* d_ws, size_t ws_size,
                              hipStream_t stream) {
    const float* noise_re = (const float*)d_in[0];
    const float* noise_im = (const float*)d_in[1];
    const int*   labels   = (const int*)d_in[2];
    const float* emb      = (const float*)d_in[3];
    const float* w1r = (const float*)d_in[4],  *w1i = (const float*)d_in[5];
    const float* b1r = (const float*)d_in[6],  *b1i = (const float*)d_in[7];
    const float* g1rr = (const float*)d_in[8], *g1ri = (const float*)d_in[9], *g1ii = (const float*)d_in[10];
    const float* n1br = (const float*)d_in[11], *n1bi = (const float*)d_in[12];
    const float* w2r = (const float*)d_in[13], *w2i = (const float*)d_in[14];
    const float* b2r = (const float*)d_in[15], *b2i = (const float*)d_in[16];
    const float* g2rr = (const float*)d_in[17], *g2ri = (const float*)d_in[18], *g2ii = (const float*)d_in[19];
    const float* n2br = (const float*)d_in[20], *n2bi = (const float*)d_in[21];
    const float* w3r = (const float*)d_in[22], *w3i = (const float*)d_in[23];
    const float* b3r = (const float*)d_in[24], *b3i = (const float*)d_in[25];
    const float* g3rr = (const float*)d_in[26], *g3ri = (const float*)d_in[27], *g3ii = (const float*)d_in[28];
    const float* n3br = (const float*)d_in[29], *n3bi = (const float*)d_in[30];
    const float* w4r = (const float*)d_in[31], *w4i = (const float*)d_in[32];
    const float* b4r = (const float*)d_in[33], *b4i = (const float*)d_in[34];

    // ---- workspace layout (bytes) ----
    // [0, 33554432)          y3cl [256][16][16][256] bf16
    //    overlay: x1cl [0, 8388608)          (dead before gemm3)
    //    overlay: x0 fp32 [8388608, 8833888) (dead after conv1)
    //    overlay: W2_all [12582912, 29360128) [4][512][4096] bf16 (dead before gemm3)
    // [33554432, 50331648)   y2cl [256][8][8][512] bf16
    // [50331648, 54525952)   W3_all [4][256][2048] bf16
    // [54525952, 54558720)   fp32 stats+coefs
    // [54591488, 54722560)   W4_all [4][16][1024] bf16
    char* ws = (char*)d_ws;
    bf16* y3cl = (bf16*)ws;
    bf16* x1cl = (bf16*)ws;
    float* x0r = (float*)(ws + 8388608);
    float* x0i = x0r + BATCH * CIN0;
    bf16* W2all = (bf16*)(ws + 12582912);
    bf16* y2cl = (bf16*)(ws + 33554432);
    bf16* W3all = (bf16*)(ws + 50331648);
    float* stats = (float*)(ws + 54525952);
    float* coef1 = stats + 2560;
    float* coef2 = coef1 + C1 * 6;
    float* coef3 = coef2 + C2 * 6;
    bf16* W4all = (bf16*)(ws + 54591488);

    build_x0<<<110, 256, 0, stream>>>(noise_re, noise_im, labels, emb, x0r, x0i);
    conv1_cl<<<8192, 256, 0, stream>>>(x0r, x0i, w1r, w1i, b1r, b1i, x1cl);

    // BN1 (C=512, rows=4096)
    (void)hipMemsetAsync(stats, 0, 2560 * sizeof(float), stream);
    bn_stats_cl<<<dim3(8, 16), 256, 0, stream>>>(x1cl, stats, C1, 64);
    bn_coef<<<2, 256, 0, stream>>>(stats, g1rr, g1ri, g1ii, n1br, n1bi, coef1, C1, 1.f / 4096.f);
    bn_apply_cl<<<8192, 256, 0, stream>>>(x1cl, coef1, C1, (size_t)4096 * C1);

    // L2: merged 4-class GEMM, Cin=512, S=4, N=256 -> 512 blocks
    wprep_all<<<32768, 256, 0, stream>>>(w2r, w2i, W2all, C1, C2);
    gemm_convt<C1, 4, C2><<<dim3(32, 4, 4), 256, 0, stream>>>(x1cl, W2all, b2r, b2i, y2cl);

    // BN2 (C=256, rows=16384)
    (void)hipMemsetAsync(stats, 0, 2560 * sizeof(float), stream);
    bn_stats_cl<<<dim3(4, 16), 256, 0, stream>>>(y2cl, stats, C2, 256);
    bn_coef<<<1, 256, 0, stream>>>(stats, g2rr, g2ri, g2ii, n2br, n2bi, coef2, C2, 1.f / 16384.f);
    bn_apply_cl<<<16384, 256, 0, stream>>>(y2cl, coef2, C2, (size_t)16384 * C2);

    // L3: merged 4-class GEMM, Cin=256, S=8, N=128 -> 1024 blocks
    wprep_all<<<8192, 256, 0, stream>>>(w3r, w3i, W3all, C2, C3);
    gemm_convt<C2, 8, C3><<<dim3(128, 2, 4), 256, 0, stream>>>(y2cl, W3all, b3r, b3i, y3cl);

    // BN3 (C=128, rows=65536)
    (void)hipMemsetAsync(stats, 0, 2560 * sizeof(float), stream);
    bn_stats_cl<<<dim3(2, 64), 256, 0, stream>>>(y3cl, stats, C3, 256);
    bn_coef<<<1, 256, 0, stream>>>(stats, g3rr, g3ri, g3ii, n3br, n3bi, coef3, C3, 1.f / 65536.f);
    bn_apply_cl<<<32768, 256, 0, stream>>>(y3cl, coef3, C3, (size_t)65536 * C3);

    // L4: MFMA, 4 classes, M=65536/class, N-tile 16 (3 used) -> 2048 blocks
    wprep4<<<256, 256, 0, stream>>>(w4r, w4i, W4all);
    conv4_mfma<<<dim3(512, 1, 4), 256, 0, stream>>>(y3cl, W4all, b4r, (float*)d_out);
}

// Round 11
// 813.213 us; speedup vs baseline: 15.2548x; 1.0834x over previous
//
#include <hip/hip_runtime.h>
#include <hip/hip_bf16.h>
#include <math.h>

#define BATCH 256
#define LAT 100
#define NCLS 10
#define CIN0 110
#define C1 512
#define C2 256
#define C3 128
#define NCH 3
#define EPS 1e-5f

typedef __hip_bfloat16 bf16;
typedef short bf16x8 __attribute__((ext_vector_type(8)));
typedef float f32x4 __attribute__((ext_vector_type(4)));

__device__ __forceinline__ float b2f(bf16 v) { return __bfloat162float(v); }
__device__ __forceinline__ bf16 f2b(float v) { return __float2bfloat16(v); }

// ---------------- build x0 as bf16 GEMM-A: [256][224], k<112 real (pad), k>=112 imag ----------------
__global__ void build_x0bf(const float* __restrict__ nre, const float* __restrict__ nim,
                           const int* __restrict__ labels, const float* __restrict__ emb,
                           bf16* __restrict__ A) {
    int idx = blockIdx.x * blockDim.x + threadIdx.x;
    if (idx >= BATCH * 224) return;
    int b = idx / 224, k = idx - b * 224;
    int p = k >= 112; int ci = k - p * 112;
    float v = 0.f;
    if (ci < CIN0) {
        if (!p) v = (ci < LAT) ? nre[b * LAT + ci] : emb[labels[b] * NCLS + (ci - LAT)];
        else    v = (ci < LAT) ? nim[b * LAT + ci] : 0.f;
    }
    A[idx] = f2b(v);
}

// ---------------- B1 prep: [16384][224] bf16, n = p*1024 + co' ----------------
__global__ void w1prep(const float* __restrict__ wr, const float* __restrict__ wi,
                       bf16* __restrict__ B) {
    int idx = blockIdx.x * 256 + threadIdx.x;   // 16384*224 = 3,670,016
    if (idx >= 16384 * 224) return;
    int n = idx / 224, k = idx - n * 224;
    int p = n >> 10, cop = n & 1023;
    int pk = k >= 112; int ci = k - pk * 112;
    float v = 0.f;
    if (ci < CIN0) {
        int co = (cop < C1) ? cop : cop - C1;
        size_t widx = ((size_t)ci * C1 + co) * 16 + p;
        float vr = wr[widx], vi = wi[widx];
        v = (cop < C1) ? (pk ? -vi : vr) : (pk ? vr : vi);
    }
    B[idx] = f2b(v);
}

// ---------------- gemm1: C[256][16384] = A[256][224] x B1^T; writes x1cl directly ----------------
__global__ __launch_bounds__(256, 1) void gemm1(
    const bf16* __restrict__ A, const bf16* __restrict__ B,
    const float* __restrict__ b1r, const float* __restrict__ b1i,
    bf16* __restrict__ Y) {
    __shared__ short As[128][40];
    __shared__ short Bs[128][40];
    const int tid = threadIdx.x;
    const int mBase = blockIdx.x * 128, nBase = blockIdx.y * 128;
    const int wid = tid >> 6, lane = tid & 63;
    const int wm = (wid >> 1) * 64, wn = (wid & 1) * 64;
    const int lm = lane & 15, lq = lane >> 4;

    f32x4 acc[4][4] = {};

    for (int k0 = 0; k0 < 224; k0 += 32) {
#pragma unroll
        for (int it = 0; it < 2; ++it) {
            int slot = tid + it * 256;
            int row = slot >> 2, kc = (slot & 3) * 8;
            int k = k0 + kc;
            *(uint4*)(&As[row][kc]) = *(const uint4*)(A + (size_t)(mBase + row) * 224 + k);
            *(uint4*)(&Bs[row][kc]) = *(const uint4*)(B + (size_t)(nBase + row) * 224 + k);
        }
        __syncthreads();
        bf16x8 af[4], bfr[4];
#pragma unroll
        for (int s = 0; s < 4; ++s) {
            af[s]  = *(const bf16x8*)(&As[wm + s * 16 + lm][lq * 8]);
            bfr[s] = *(const bf16x8*)(&Bs[wn + s * 16 + lm][lq * 8]);
        }
#pragma unroll
        for (int sm = 0; sm < 4; ++sm)
#pragma unroll
            for (int sn = 0; sn < 4; ++sn)
                acc[sm][sn] = __builtin_amdgcn_mfma_f32_16x16x32_bf16(af[sm], bfr[sn], acc[sm][sn], 0, 0, 0);
        __syncthreads();
    }

#pragma unroll
    for (int sm = 0; sm < 4; ++sm) {
#pragma unroll
        for (int v = 0; v < 4; ++v) {
            int m = mBase + wm + sm * 16 + lq * 4 + v;
#pragma unroll
            for (int sn = 0; sn < 4; ++sn) {
                int n = nBase + wn + sn * 16 + lm;
                int cop = n & 1023;
                float bias = (cop < C1) ? b1r[cop] : b1i[cop - C1];
                Y[(size_t)m * 16384 + n] = f2b(acc[sm][sn][v] + bias);
            }
        }
    }
}

// ---------------- BN stats / coef / apply (unchanged) ----------------
__global__ void bn_stats_cl(const bf16* __restrict__ Y, float* __restrict__ stats,
                            int C, int rowsPerThread) {
    int c = blockIdx.x * 64 + (threadIdx.x & 63);
    int CC = 2 * C;
    long r0 = (long)(blockIdx.y * 4 + (threadIdx.x >> 6)) * rowsPerThread;
    float sr = 0, si = 0, srr = 0, sii = 0, sri = 0;
    for (int r = 0; r < rowsPerThread; ++r) {
        size_t base = (size_t)(r0 + r) * CC;
        float vr = b2f(Y[base + c]);
        float vi = b2f(Y[base + C + c]);
        sr += vr; si += vi; srr += vr * vr; sii += vi * vi; sri += vr * vi;
    }
    atomicAdd(&stats[c * 5 + 0], sr);
    atomicAdd(&stats[c * 5 + 1], si);
    atomicAdd(&stats[c * 5 + 2], srr);
    atomicAdd(&stats[c * 5 + 3], sii);
    atomicAdd(&stats[c * 5 + 4], sri);
}

__global__ void bn_coef(const float* __restrict__ stats,
                        const float* __restrict__ grr, const float* __restrict__ gri,
                        const float* __restrict__ gii,
                        const float* __restrict__ betar, const float* __restrict__ betai,
                        float* __restrict__ coef, int C, float invN) {
    int c = blockIdx.x * blockDim.x + threadIdx.x;
    if (c >= C) return;
    float sr = stats[c*5+0], si = stats[c*5+1], srr = stats[c*5+2], sii = stats[c*5+3], sri = stats[c*5+4];
    float mr = sr * invN, mi = si * invN;
    float crr = srr * invN - mr * mr + EPS;
    float cii = sii * invN - mi * mi + EPS;
    float cri = sri * invN - mr * mi;
    float s = sqrtf(crr * cii - cri * cri);
    float t = sqrtf(crr + cii + 2.f * s);
    float inv = 1.f / (s * t);
    float rrr = (cii + s) * inv, rii = (crr + s) * inv, rri = -cri * inv;
    float Grr = grr[c], Gri = gri[c], Gii = gii[c];
    float arr = Grr * rrr + Gri * rri, ari = Grr * rri + Gri * rii;
    float air = Gri * rrr + Gii * rri, aii = Gri * rri + Gii * rii;
    coef[c*6+0] = arr; coef[c*6+1] = ari; coef[c*6+2] = betar[c] - arr * mr - ari * mi;
    coef[c*6+3] = air; coef[c*6+4] = aii; coef[c*6+5] = betai[c] - air * mr - aii * mi;
}

__global__ void bn_apply_cl(bf16* __restrict__ Y, const float* __restrict__ coef,
                            int C, size_t total) {
    size_t idx = (size_t)blockIdx.x * 256 + threadIdx.x;
    if (idx >= total) return;
    int c = (int)(idx % C);
    size_t base = (idx / C) * 2 * C;
    const float* k = coef + c * 6;
    float vr = b2f(Y[base + c]), vi = b2f(Y[base + C + c]);
    float orr = fmaxf(k[0] * vr + k[1] * vi + k[2], 0.f);
    float oii = fmaxf(k[3] * vr + k[4] * vi + k[5], 0.f);
    Y[base + c] = f2b(orr); Y[base + C + c] = f2b(oii);
}

// ---------------- W' prep, ALL 4 classes: Wall[cls][2N][2K] bf16 ----------------
__global__ void wprep_all(const float* __restrict__ wr, const float* __restrict__ wi,
                          bf16* __restrict__ W, int CIN, int N) {
    int K = 4 * CIN, TWOK = 8 * CIN;
    size_t per = (size_t)2 * N * TWOK;
    size_t idx = (size_t)blockIdx.x * 256 + threadIdx.x;
    if (idx >= 4 * per) return;
    int cls = (int)(idx / per);
    int rem = (int)(idx - (size_t)cls * per);
    int py = cls >> 1, px = cls & 1;
    int n = rem / TWOK, k = rem - n * TWOK;
    int p = k >= K; int kk = k - p * K;
    int t = kk / CIN, ci = kk - t * CIN;
    int a = t >> 1, e = t & 1;
    int kh = py ? (a ? 2 : 0) : (a ? 3 : 1);
    int kw = px ? (e ? 2 : 0) : (e ? 3 : 1);
    int co = (n < N) ? n : n - N;
    size_t widx = ((size_t)ci * N + co) * 16 + kh * 4 + kw;
    float vr = wr[widx], vi = wi[widx];
    float v = (n < N) ? (p ? -vi : vr) : (p ? vr : vi);
    W[idx] = f2b(v);
}

// ---- W4 prep: real-part-only, Wall[cls][16][1024], n>=3 zero-padded ----
__global__ void wprep4(const float* __restrict__ wr, const float* __restrict__ wi,
                       bf16* __restrict__ W) {
    int idx = blockIdx.x * 256 + threadIdx.x;
    if (idx >= 65536) return;
    int cls = idx >> 14, rem = idx & 16383;
    int py = cls >> 1, px = cls & 1;
    int n = rem >> 10, k = rem & 1023;
    float v = 0.f;
    if (n < NCH) {
        int p = k >= 512; int kk = k - p * 512;
        int t = kk >> 7, ci = kk & 127;
        int a = t >> 1, e = t & 1;
        int kh = py ? (a ? 2 : 0) : (a ? 3 : 1);
        int kw = px ? (e ? 2 : 0) : (e ? 3 : 1);
        size_t widx = ((size_t)ci * NCH + n) * 16 + kh * 4 + kw;
        v = p ? -wi[widx] : wr[widx];
    }
    W[idx] = f2b(v);
}

// ---------------- MFMA GEMM 128x128, 4 classes via blockIdx.z (L3) ----------------
template<int CIN, int S, int N>
__global__ __launch_bounds__(256, 1) void gemm_convt(
    const bf16* __restrict__ X, const bf16* __restrict__ Wall,
    const float* __restrict__ biasr, const float* __restrict__ biasi,
    bf16* __restrict__ Y) {
    constexpr int K = 4 * CIN, TWOK = 8 * CIN, C2I = 2 * CIN, C2O = 2 * N, HOUT = 2 * S;
    __shared__ short As[128][40];
    __shared__ short Bs[128][40];
    const int cls = blockIdx.z;
    const int py = cls >> 1, px = cls & 1;
    const bf16* W = Wall + (size_t)cls * 2 * N * TWOK;
    const int tid = threadIdx.x;
    const int mBase = blockIdx.x * 128, nBase = blockIdx.y * 128;
    const int wid = tid >> 6, lane = tid & 63;
    const int wm = (wid >> 1) * 64, wn = (wid & 1) * 64;
    const int lm = lane & 15, lq = lane >> 4;
    const int dh0 = py ? 1 : 0, dh1 = py ? 0 : -1;
    const int dw0 = px ? 1 : 0, dw1 = px ? 0 : -1;

    f32x4 acc[4][4] = {};

    for (int k0 = 0; k0 < TWOK; k0 += 32) {
#pragma unroll
        for (int it = 0; it < 2; ++it) {
            int slot = tid + it * 256;
            int row = slot >> 2, kc = (slot & 3) * 8;
            int k = k0 + kc;
            int p = k >= K; int kk = k - p * K;
            int t = kk / CIN, ci = kk - t * CIN;
            int a = t >> 1, e = t & 1;
            int m = mBase + row;
            int b = m / (S * S); int rem = m - b * (S * S);
            int i = rem / S, j = rem % S;
            int ih = i + (a ? dh1 : dh0);
            int iw = j + (e ? dw1 : dw0);
            uint4 v = {0u, 0u, 0u, 0u};
            if ((unsigned)ih < (unsigned)S && (unsigned)iw < (unsigned)S)
                v = *(const uint4*)(X + ((size_t)((b * S + ih) * S + iw) * C2I + p * CIN + ci));
            *(uint4*)(&As[row][kc]) = v;
            uint4 w = *(const uint4*)(W + (size_t)(nBase + row) * TWOK + k);
            *(uint4*)(&Bs[row][kc]) = w;
        }
        __syncthreads();
        bf16x8 af[4], bfr[4];
#pragma unroll
        for (int s = 0; s < 4; ++s) {
            af[s]  = *(const bf16x8*)(&As[wm + s * 16 + lm][lq * 8]);
            bfr[s] = *(const bf16x8*)(&Bs[wn + s * 16 + lm][lq * 8]);
        }
#pragma unroll
        for (int sm = 0; sm < 4; ++sm)
#pragma unroll
            for (int sn = 0; sn < 4; ++sn)
                acc[sm][sn] = __builtin_amdgcn_mfma_f32_16x16x32_bf16(af[sm], bfr[sn], acc[sm][sn], 0, 0, 0);
        __syncthreads();
    }

#pragma unroll
    for (int sm = 0; sm < 4; ++sm) {
#pragma unroll
        for (int v = 0; v < 4; ++v) {
            int m = mBase + wm + sm * 16 + lq * 4 + v;
            int b = m / (S * S); int rem = m - b * (S * S);
            int i = rem / S, j = rem % S;
            int oh = 2 * i + py, ow = 2 * j + px;
            size_t rowoff = (size_t)((b * HOUT + oh) * HOUT + ow) * C2O;
#pragma unroll
            for (int sn = 0; sn < 4; ++sn) {
                int n = nBase + wn + sn * 16 + lm;
                float bias = (n < N) ? biasr[n] : biasi[n - N];
                Y[rowoff + n] = f2b(acc[sm][sn][v] + bias);
            }
        }
    }
}

// ---------------- MFMA GEMM 64x128 tiles (L2: more blocks -> 4/CU) ----------------
template<int CIN, int S, int N>
__global__ __launch_bounds__(256, 4) void gemm_convt64(
    const bf16* __restrict__ X, const bf16* __restrict__ Wall,
    const float* __restrict__ biasr, const float* __restrict__ biasi,
    bf16* __restrict__ Y) {
    constexpr int K = 4 * CIN, TWOK = 8 * CIN, C2I = 2 * CIN, C2O = 2 * N, HOUT = 2 * S;
    __shared__ short As[64][40];
    __shared__ short Bs[128][40];
    const int cls = blockIdx.z;
    const int py = cls >> 1, px = cls & 1;
    const bf16* W = Wall + (size_t)cls * 2 * N * TWOK;
    const int tid = threadIdx.x;
    const int mBase = blockIdx.x * 64, nBase = blockIdx.y * 128;
    const int wid = tid >> 6, lane = tid & 63;
    const int lm = lane & 15, lq = lane >> 4;
    const int dh0 = py ? 1 : 0, dh1 = py ? 0 : -1;
    const int dw0 = px ? 1 : 0, dw1 = px ? 0 : -1;

    f32x4 acc[8] = {};

    for (int k0 = 0; k0 < TWOK; k0 += 32) {
        {   // A: 256 slots (64 rows x 4)
            int row = tid >> 2, kc = (tid & 3) * 8;
            int k = k0 + kc;
            int p = k >= K; int kk = k - p * K;
            int t = kk / CIN, ci = kk - t * CIN;
            int a = t >> 1, e = t & 1;
            int m = mBase + row;
            int b = m / (S * S); int rem = m - b * (S * S);
            int i = rem / S, j = rem % S;
            int ih = i + (a ? dh1 : dh0);
            int iw = j + (e ? dw1 : dw0);
            uint4 v = {0u, 0u, 0u, 0u};
            if ((unsigned)ih < (unsigned)S && (unsigned)iw < (unsigned)S)
                v = *(const uint4*)(X + ((size_t)((b * S + ih) * S + iw) * C2I + p * CIN + ci));
            *(uint4*)(&As[row][kc]) = v;
        }
#pragma unroll
        for (int it = 0; it < 2; ++it) {  // B: 512 slots
            int slot = tid + it * 256;
            int row = slot >> 2, kc = (slot & 3) * 8;
            uint4 w = *(const uint4*)(W + (size_t)(nBase + row) * TWOK + k0 + kc);
            *(uint4*)(&Bs[row][kc]) = w;
        }
        __syncthreads();
        bf16x8 af = *(const bf16x8*)(&As[wid * 16 + lm][lq * 8]);
#pragma unroll
        for (int sn = 0; sn < 8; ++sn) {
            bf16x8 bfr = *(const bf16x8*)(&Bs[sn * 16 + lm][lq * 8]);
            acc[sn] = __builtin_amdgcn_mfma_f32_16x16x32_bf16(af, bfr, acc[sn], 0, 0, 0);
        }
        __syncthreads();
    }

#pragma unroll
    for (int v = 0; v < 4; ++v) {
        int m = mBase + wid * 16 + lq * 4 + v;
        int b = m / (S * S); int rem = m - b * (S * S);
        int i = rem / S, j = rem % S;
        int oh = 2 * i + py, ow = 2 * j + px;
        size_t rowoff = (size_t)((b * HOUT + oh) * HOUT + ow) * C2O;
#pragma unroll
        for (int sn = 0; sn < 8; ++sn) {
            int n = nBase + sn * 16 + lm;
            float bias = (n < N) ? biasr[n] : biasi[n - N];
            Y[rowoff + n] = f2b(acc[sn][v] + bias);
        }
    }
}

// ---------------- layer4 via MFMA (unchanged) ----------------
__global__ __launch_bounds__(256, 2) void conv4_mfma(
    const bf16* __restrict__ X, const bf16* __restrict__ Wall,
    const float* __restrict__ br, float* __restrict__ out) {
    constexpr int CIN = 128, S = 16, K = 512, TWOK = 1024, C2I = 256;
    __shared__ short As[128][40];
    __shared__ short Bs[16][40];
    const int cls = blockIdx.z;
    const int py = cls >> 1, px = cls & 1;
    const bf16* W = Wall + (size_t)cls * 16 * TWOK;
    const int tid = threadIdx.x;
    const int mBase = blockIdx.x * 128;
    const int wid = tid >> 6, lane = tid & 63;
    const int wm = wid * 32;
    const int lm = lane & 15, lq = lane >> 4;
    const int dh0 = py ? 1 : 0, dh1 = py ? 0 : -1;
    const int dw0 = px ? 1 : 0, dw1 = px ? 0 : -1;

    f32x4 acc[2] = {};

    for (int k0 = 0; k0 < TWOK; k0 += 32) {
#pragma unroll
        for (int it = 0; it < 2; ++it) {
            int slot = tid + it * 256;
            int row = slot >> 2, kc = (slot & 3) * 8;
            int k = k0 + kc;
            int p = k >= K; int kk = k - p * K;
            int t = kk >> 7, ci = kk & 127;
            int a = t >> 1, e = t & 1;
            int m = mBase + row;
            int b = m >> 8; int rem = m & 255;
            int i = rem >> 4, j = rem & 15;
            int ih = i + (a ? dh1 : dh0);
            int iw = j + (e ? dw1 : dw0);
            uint4 v = {0u, 0u, 0u, 0u};
            if ((unsigned)ih < (unsigned)S && (unsigned)iw < (unsigned)S)
                v = *(const uint4*)(X + ((size_t)((b * S + ih) * S + iw) * C2I + p * CIN + ci));
            *(uint4*)(&As[row][kc]) = v;
        }
        if (tid < 64) {
            int row = tid >> 2, kc = (tid & 3) * 8;
            uint4 w = *(const uint4*)(W + (size_t)row * TWOK + k0 + kc);
            *(uint4*)(&Bs[row][kc]) = w;
        }
        __syncthreads();
        bf16x8 bfr = *(const bf16x8*)(&Bs[lm][lq * 8]);
        bf16x8 af0 = *(const bf16x8*)(&As[wm + lm][lq * 8]);
        bf16x8 af1 = *(const bf16x8*)(&As[wm + 16 + lm][lq * 8]);
        acc[0] = __builtin_amdgcn_mfma_f32_16x16x32_bf16(af0, bfr, acc[0], 0, 0, 0);
        acc[1] = __builtin_amdgcn_mfma_f32_16x16x32_bf16(af1, bfr, acc[1], 0, 0, 0);
        __syncthreads();
    }

    int n = lm;
    if (n < NCH) {
        float bias = br[n];
#pragma unroll
        for (int s = 0; s < 2; ++s) {
#pragma unroll
            for (int v = 0; v < 4; ++v) {
                int m = mBase + wm + s * 16 + lq * 4 + v;
                int b = m >> 8; int rem = m & 255;
                int i = rem >> 4, j = rem & 15;
                int oh = 2 * i + py, ow = 2 * j + px;
                out[((size_t)(b * NCH + n) * 32 + oh) * 32 + ow] = tanhf(acc[s][v] + bias);
            }
        }
    }
}

extern "C" void kernel_launch(void* const* d_in, const int* in_sizes, int n_in,
                              void* d_out, int out_size, void* d_ws, size_t ws_size,
                              hipStream_t stream) {
    const float* noise_re = (const float*)d_in[0];
    const float* noise_im = (const float*)d_in[1];
    const int*   labels   = (const int*)d_in[2];
    const float* emb      = (const float*)d_in[3];
    const float* w1r = (const float*)d_in[4],  *w1i = (const float*)d_in[5];
    const float* b1r = (const float*)d_in[6],  *b1i = (const float*)d_in[7];
    const float* g1rr = (const float*)d_in[8], *g1ri = (const float*)d_in[9], *g1ii = (const float*)d_in[10];
    const float* n1br = (const float*)d_in[11], *n1bi = (const float*)d_in[12];
    const float* w2r = (const float*)d_in[13], *w2i = (const float*)d_in[14];
    const float* b2r = (const float*)d_in[15], *b2i = (const float*)d_in[16];
    const float* g2rr = (const float*)d_in[17], *g2ri = (const float*)d_in[18], *g2ii = (const float*)d_in[19];
    const float* n2br = (const float*)d_in[20], *n2bi = (const float*)d_in[21];
    const float* w3r = (const float*)d_in[22], *w3i = (const float*)d_in[23];
    const float* b3r = (const float*)d_in[24], *b3i = (const float*)d_in[25];
    const float* g3rr = (const float*)d_in[26], *g3ri = (const float*)d_in[27], *g3ii = (const float*)d_in[28];
    const float* n3br = (const float*)d_in[29], *n3bi = (const float*)d_in[30];
    const float* w4r = (const float*)d_in[31], *w4i = (const float*)d_in[32];
    const float* b4r = (const float*)d_in[33], *b4i = (const float*)d_in[34];

    // ---- workspace layout (bytes) ----
    // [0, 33554432)          y3cl [256][16][16][256] bf16
    //    overlay: x1cl [0, 8388608)
    //    overlay: B1 [12582912, 19922944) [16384][224] bf16 (dead before wprep_all W2)
    //    overlay: W2_all [12582912, 29360128) (dead before gemm3 writes y3cl)
    // [33554432, 50331648)   y2cl [256][8][8][512] bf16
    // [50331648, 54525952)   W3_all [4][256][2048] bf16
    // [54525952, 54591488)   fp32 stats+coefs
    // [54591488, 54722560)   W4_all [4][16][1024] bf16
    // [54722560, 54837248)   x0bf [256][224] bf16
    char* ws = (char*)d_ws;
    bf16* y3cl = (bf16*)ws;
    bf16* x1cl = (bf16*)ws;
    bf16* B1   = (bf16*)(ws + 12582912);
    bf16* W2all = (bf16*)(ws + 12582912);
    bf16* y2cl = (bf16*)(ws + 33554432);
    bf16* W3all = (bf16*)(ws + 50331648);
    float* stats = (float*)(ws + 54525952);
    float* coef1 = stats + 2560;
    float* coef2 = coef1 + C1 * 6;
    float* coef3 = coef2 + C2 * 6;
    bf16* W4all = (bf16*)(ws + 54591488);
    bf16* x0bf  = (bf16*)(ws + 54722560);

    // L1 as MFMA GEMM: C[256][16384] = x0[256][224] * B1^T -> x1cl channels-last
    build_x0bf<<<224, 256, 0, stream>>>(noise_re, noise_im, labels, emb, x0bf);
    w1prep<<<14336, 256, 0, stream>>>(w1r, w1i, B1);
    gemm1<<<dim3(2, 128), 256, 0, stream>>>(x0bf, B1, b1r, b1i, x1cl);

    // BN1 (C=512, rows=4096)
    (void)hipMemsetAsync(stats, 0, 2560 * sizeof(float), stream);
    bn_stats_cl<<<dim3(8, 16), 256, 0, stream>>>(x1cl, stats, C1, 64);
    bn_coef<<<2, 256, 0, stream>>>(stats, g1rr, g1ri, g1ii, n1br, n1bi, coef1, C1, 1.f / 4096.f);
    bn_apply_cl<<<8192, 256, 0, stream>>>(x1cl, coef1, C1, (size_t)4096 * C1);

    // L2: 64x128-tile merged 4-class GEMM -> 1024 blocks (4/CU)
    wprep_all<<<32768, 256, 0, stream>>>(w2r, w2i, W2all, C1, C2);
    gemm_convt64<C1, 4, C2><<<dim3(64, 4, 4), 256, 0, stream>>>(x1cl, W2all, b2r, b2i, y2cl);

    // BN2 (C=256, rows=16384)
    (void)hipMemsetAsync(stats, 0, 2560 * sizeof(float), stream);
    bn_stats_cl<<<dim3(4, 16), 256, 0, stream>>>(y2cl, stats, C2, 256);
    bn_coef<<<1, 256, 0, stream>>>(stats, g2rr, g2ri, g2ii, n2br, n2bi, coef2, C2, 1.f / 16384.f);
    bn_apply_cl<<<16384, 256, 0, stream>>>(y2cl, coef2, C2, (size_t)16384 * C2);

    // L3: 128x128 merged 4-class GEMM -> 1024 blocks
    wprep_all<<<8192, 256, 0, stream>>>(w3r, w3i, W3all, C2, C3);
    gemm_convt<C2, 8, C3><<<dim3(128, 2, 4), 256, 0, stream>>>(y2cl, W3all, b3r, b3i, y3cl);

    // BN3 (C=128, rows=65536)
    (void)hipMemsetAsync(stats, 0, 2560 * sizeof(float), stream);
    bn_stats_cl<<<dim3(2, 64), 256, 0, stream>>>(y3cl, stats, C3, 256);
    bn_coef<<<1, 256, 0, stream>>>(stats, g3rr, g3ri, g3ii, n3br, n3bi, coef3, C3, 1.f / 65536.f);
    bn_apply_cl<<<32768, 256, 0, stream>>>(y3cl, coef3, C3, (size_t)65536 * C3);

    // L4: MFMA, 4 classes
    wprep4<<<256, 256, 0, stream>>>(w4r, w4i, W4all);
    conv4_mfma<<<dim3(512, 1, 4), 256, 0, stream>>>(y3cl, W4all, b4r, (float*)d_out);
}

// Round 12
// 714.728 us; speedup vs baseline: 17.3568x; 1.1378x over previous
//
#include <hip/hip_runtime.h>
#include <hip/hip_bf16.h>
#include <math.h>

#define BATCH 256
#define LAT 100
#define NCLS 10
#define CIN0 110
#define C1 512
#define C2 256
#define C3 128
#define NCH 3
#define EPS 1e-5f

typedef __hip_bfloat16 bf16;
typedef short bf16x8 __attribute__((ext_vector_type(8)));
typedef float f32x4 __attribute__((ext_vector_type(4)));

__device__ __forceinline__ float b2f(bf16 v) { return __bfloat162float(v); }
__device__ __forceinline__ bf16 f2b(float v) { return __float2bfloat16(v); }
__device__ __forceinline__ float s2f(short s) {
    unsigned u = ((unsigned)(unsigned short)s) << 16;
    return __builtin_bit_cast(float, u);
}
__device__ __forceinline__ short f2s(float f) {
    bf16 b = __float2bfloat16(f);
    return *(short*)&b;
}

// ---------------- build x0 as bf16 GEMM-A: [256][224] ----------------
__global__ void build_x0bf(const float* __restrict__ nre, const float* __restrict__ nim,
                           const int* __restrict__ labels, const float* __restrict__ emb,
                           bf16* __restrict__ A) {
    int idx = blockIdx.x * blockDim.x + threadIdx.x;
    if (idx >= BATCH * 224) return;
    int b = idx / 224, k = idx - b * 224;
    int p = k >= 112; int ci = k - p * 112;
    float v = 0.f;
    if (ci < CIN0) {
        if (!p) v = (ci < LAT) ? nre[b * LAT + ci] : emb[labels[b] * NCLS + (ci - LAT)];
        else    v = (ci < LAT) ? nim[b * LAT + ci] : 0.f;
    }
    A[idx] = f2b(v);
}

// ---------------- combined weight prep: B1 | W2all | W3all | W4all ----------------
#define NB_W1 14336
#define NB_W2 32768
#define NB_W3 8192
#define NB_W4 256

__device__ __forceinline__ void w1prep_body(const float* wr, const float* wi, bf16* B, int idx) {
    if (idx >= 16384 * 224) return;
    int n = idx / 224, k = idx - n * 224;
    int p = n >> 10, cop = n & 1023;
    int pk = k >= 112; int ci = k - pk * 112;
    float v = 0.f;
    if (ci < CIN0) {
        int co = (cop < C1) ? cop : cop - C1;
        size_t widx = ((size_t)ci * C1 + co) * 16 + p;
        float vr = wr[widx], vi = wi[widx];
        v = (cop < C1) ? (pk ? -vi : vr) : (pk ? vr : vi);
    }
    B[idx] = f2b(v);
}

__device__ __forceinline__ void wprep_body(const float* wr, const float* wi, bf16* W,
                                           int CIN, int N, size_t idx) {
    int K = 4 * CIN, TWOK = 8 * CIN;
    size_t per = (size_t)2 * N * TWOK;
    if (idx >= 4 * per) return;
    int cls = (int)(idx / per);
    int rem = (int)(idx - (size_t)cls * per);
    int py = cls >> 1, px = cls & 1;
    int n = rem / TWOK, k = rem - n * TWOK;
    int p = k >= K; int kk = k - p * K;
    int t = kk / CIN, ci = kk - t * CIN;
    int a = t >> 1, e = t & 1;
    int kh = py ? (a ? 2 : 0) : (a ? 3 : 1);
    int kw = px ? (e ? 2 : 0) : (e ? 3 : 1);
    int co = (n < N) ? n : n - N;
    size_t widx = ((size_t)ci * N + co) * 16 + kh * 4 + kw;
    float vr = wr[widx], vi = wi[widx];
    float v = (n < N) ? (p ? -vi : vr) : (p ? vr : vi);
    W[idx] = f2b(v);
}

__device__ __forceinline__ void wprep4_body(const float* wr, const float* wi, bf16* W, int idx) {
    if (idx >= 65536) return;
    int cls = idx >> 14, rem = idx & 16383;
    int py = cls >> 1, px = cls & 1;
    int n = rem >> 10, k = rem & 1023;
    float v = 0.f;
    if (n < NCH) {
        int p = k >= 512; int kk = k - p * 512;
        int t = kk >> 7, ci = kk & 127;
        int a = t >> 1, e = t & 1;
        int kh = py ? (a ? 2 : 0) : (a ? 3 : 1);
        int kw = px ? (e ? 2 : 0) : (e ? 3 : 1);
        size_t widx = ((size_t)ci * NCH + n) * 16 + kh * 4 + kw;
        v = p ? -wi[widx] : wr[widx];
    }
    W[idx] = f2b(v);
}

__global__ void wprep_combined(const float* __restrict__ w1r, const float* __restrict__ w1i,
                               const float* __restrict__ w2r, const float* __restrict__ w2i,
                               const float* __restrict__ w3r, const float* __restrict__ w3i,
                               const float* __restrict__ w4r, const float* __restrict__ w4i,
                               bf16* __restrict__ B1, bf16* __restrict__ W2all,
                               bf16* __restrict__ W3all, bf16* __restrict__ W4all) {
    int bid = blockIdx.x;
    if (bid < NB_W1) {
        w1prep_body(w1r, w1i, B1, bid * 256 + threadIdx.x);
    } else if (bid < NB_W1 + NB_W2) {
        wprep_body(w2r, w2i, W2all, C1, C2, (size_t)(bid - NB_W1) * 256 + threadIdx.x);
    } else if (bid < NB_W1 + NB_W2 + NB_W3) {
        wprep_body(w3r, w3i, W3all, C2, C3, (size_t)(bid - NB_W1 - NB_W2) * 256 + threadIdx.x);
    } else {
        wprep4_body(w4r, w4i, W4all, (bid - NB_W1 - NB_W2 - NB_W3) * 256 + threadIdx.x);
    }
}

// ---------------- gemm1: C[256][16384] = A[256][224] x B1^T -> x1cl ----------------
__global__ __launch_bounds__(256, 1) void gemm1(
    const bf16* __restrict__ A, const bf16* __restrict__ B,
    const float* __restrict__ b1r, const float* __restrict__ b1i,
    bf16* __restrict__ Y) {
    __shared__ short As[128][40];
    __shared__ short Bs[128][40];
    const int tid = threadIdx.x;
    const int mBase = blockIdx.x * 128, nBase = blockIdx.y * 128;
    const int wid = tid >> 6, lane = tid & 63;
    const int wm = (wid >> 1) * 64, wn = (wid & 1) * 64;
    const int lm = lane & 15, lq = lane >> 4;

    f32x4 acc[4][4] = {};

    for (int k0 = 0; k0 < 224; k0 += 32) {
#pragma unroll
        for (int it = 0; it < 2; ++it) {
            int slot = tid + it * 256;
            int row = slot >> 2, kc = (slot & 3) * 8;
            int k = k0 + kc;
            *(uint4*)(&As[row][kc]) = *(const uint4*)(A + (size_t)(mBase + row) * 224 + k);
            *(uint4*)(&Bs[row][kc]) = *(const uint4*)(B + (size_t)(nBase + row) * 224 + k);
        }
        __syncthreads();
        bf16x8 af[4], bfr[4];
#pragma unroll
        for (int s = 0; s < 4; ++s) {
            af[s]  = *(const bf16x8*)(&As[wm + s * 16 + lm][lq * 8]);
            bfr[s] = *(const bf16x8*)(&Bs[wn + s * 16 + lm][lq * 8]);
        }
#pragma unroll
        for (int sm = 0; sm < 4; ++sm)
#pragma unroll
            for (int sn = 0; sn < 4; ++sn)
                acc[sm][sn] = __builtin_amdgcn_mfma_f32_16x16x32_bf16(af[sm], bfr[sn], acc[sm][sn], 0, 0, 0);
        __syncthreads();
    }

#pragma unroll
    for (int sm = 0; sm < 4; ++sm) {
#pragma unroll
        for (int v = 0; v < 4; ++v) {
            int m = mBase + wm + sm * 16 + lq * 4 + v;
#pragma unroll
            for (int sn = 0; sn < 4; ++sn) {
                int n = nBase + wn + sn * 16 + lm;
                int cop = n & 1023;
                float bias = (cop < C1) ? b1r[cop] : b1i[cop - C1];
                Y[(size_t)m * 16384 + n] = f2b(acc[sm][sn][v] + bias);
            }
        }
    }
}

// ---------------- BN stats: vectorized x8, per-block partials (no memset/atomics) ----------------
// grid.x = 32 blocks; partials[block][C][5]
__global__ void bn_stats_v(const bf16* __restrict__ Y, float* __restrict__ P,
                           int C, int logG, int rowsPerSlice) {
    const int tid = threadIdx.x;
    const int G = 1 << logG;
    const int g = tid & (G - 1);
    const int slice = tid >> logG;
    const int nsl = 256 >> logG;
    const int r0 = blockIdx.x * rowsPerSlice * nsl + slice * rowsPerSlice;
    const int CC = 2 * C;

    float sr[8] = {}, si[8] = {}, srr[8] = {}, sii[8] = {}, sri[8] = {};
    for (int r = r0; r < r0 + rowsPerSlice; ++r) {
        const bf16* p = Y + (size_t)r * CC + g * 8;
        bf16x8 vr8 = *(const bf16x8*)p;
        bf16x8 vi8 = *(const bf16x8*)(p + C);
#pragma unroll
        for (int j = 0; j < 8; ++j) {
            float vr = s2f(vr8[j]), vi = s2f(vi8[j]);
            sr[j] += vr; si[j] += vi;
            srr[j] += vr * vr; sii[j] += vi * vi; sri[j] += vr * vi;
        }
    }
    __shared__ float red[5][512];
    for (int i = tid; i < 5 * 512; i += 256) ((float*)red)[i] = 0.f;
    __syncthreads();
#pragma unroll
    for (int j = 0; j < 8; ++j) {
        int c = g * 8 + j;
        atomicAdd(&red[0][c], sr[j]);
        atomicAdd(&red[1][c], si[j]);
        atomicAdd(&red[2][c], srr[j]);
        atomicAdd(&red[3][c], sii[j]);
        atomicAdd(&red[4][c], sri[j]);
    }
    __syncthreads();
    for (int c = tid; c < C; c += 256) {
        float* dst = P + ((size_t)blockIdx.x * C + c) * 5;
        dst[0] = red[0][c]; dst[1] = red[1][c]; dst[2] = red[2][c];
        dst[3] = red[3][c]; dst[4] = red[4][c];
    }
}

// ---------------- coef: reduce 32 partials + whitening + affine fold (SoA out) ----------------
__global__ void bn_coef_v(const float* __restrict__ P,
                          const float* __restrict__ grr, const float* __restrict__ gri,
                          const float* __restrict__ gii,
                          const float* __restrict__ betar, const float* __restrict__ betai,
                          float* __restrict__ coef, int C, float invN) {
    int c = blockIdx.x * blockDim.x + threadIdx.x;
    if (c >= C) return;
    float sr = 0, si = 0, srr = 0, sii = 0, sri = 0;
    for (int b = 0; b < 32; ++b) {
        const float* p = P + ((size_t)b * C + c) * 5;
        sr += p[0]; si += p[1]; srr += p[2]; sii += p[3]; sri += p[4];
    }
    float mr = sr * invN, mi = si * invN;
    float crr = srr * invN - mr * mr + EPS;
    float cii = sii * invN - mi * mi + EPS;
    float cri = sri * invN - mr * mi;
    float s = sqrtf(crr * cii - cri * cri);
    float t = sqrtf(crr + cii + 2.f * s);
    float inv = 1.f / (s * t);
    float rrr = (cii + s) * inv, rii = (crr + s) * inv, rri = -cri * inv;
    float Grr = grr[c], Gri = gri[c], Gii = gii[c];
    float arr = Grr * rrr + Gri * rri, ari = Grr * rri + Gri * rii;
    float air = Gri * rrr + Gii * rri, aii = Gri * rri + Gii * rii;
    coef[0 * C + c] = arr;
    coef[1 * C + c] = ari;
    coef[2 * C + c] = betar[c] - arr * mr - ari * mi;
    coef[3 * C + c] = air;
    coef[4 * C + c] = aii;
    coef[5 * C + c] = betai[c] - air * mr - aii * mi;
}

// ---------------- BN apply+ReLU: vectorized x8 ----------------
__global__ void bn_apply_v(bf16* __restrict__ Y, const float* __restrict__ coef,
                           int C, int logG, int total) {
    int idx = blockIdx.x * 256 + threadIdx.x;
    if (idx >= total) return;
    int G = 1 << logG;
    int g = idx & (G - 1);
    size_t base = (size_t)(idx >> logG) * 2 * C + g * 8;
    bf16x8 vr8 = *(const bf16x8*)(Y + base);
    bf16x8 vi8 = *(const bf16x8*)(Y + base + C);
    bf16x8 or8, oi8;
#pragma unroll
    for (int j = 0; j < 8; ++j) {
        int c = g * 8 + j;
        float vr = s2f(vr8[j]), vi = s2f(vi8[j]);
        float orr = fmaxf(coef[0 * C + c] * vr + coef[1 * C + c] * vi + coef[2 * C + c], 0.f);
        float oii = fmaxf(coef[3 * C + c] * vr + coef[4 * C + c] * vi + coef[5 * C + c], 0.f);
        or8[j] = f2s(orr); oi8[j] = f2s(oii);
    }
    *(bf16x8*)(Y + base) = or8;
    *(bf16x8*)(Y + base + C) = oi8;
}

// ---------------- MFMA GEMM 128x128, 4 classes via blockIdx.z (L3) ----------------
template<int CIN, int S, int N>
__global__ __launch_bounds__(256, 1) void gemm_convt(
    const bf16* __restrict__ X, const bf16* __restrict__ Wall,
    const float* __restrict__ biasr, const float* __restrict__ biasi,
    bf16* __restrict__ Y) {
    constexpr int K = 4 * CIN, TWOK = 8 * CIN, C2I = 2 * CIN, C2O = 2 * N, HOUT = 2 * S;
    __shared__ short As[128][40];
    __shared__ short Bs[128][40];
    const int cls = blockIdx.z;
    const int py = cls >> 1, px = cls & 1;
    const bf16* W = Wall + (size_t)cls * 2 * N * TWOK;
    const int tid = threadIdx.x;
    const int mBase = blockIdx.x * 128, nBase = blockIdx.y * 128;
    const int wid = tid >> 6, lane = tid & 63;
    const int wm = (wid >> 1) * 64, wn = (wid & 1) * 64;
    const int lm = lane & 15, lq = lane >> 4;
    const int dh0 = py ? 1 : 0, dh1 = py ? 0 : -1;
    const int dw0 = px ? 1 : 0, dw1 = px ? 0 : -1;

    f32x4 acc[4][4] = {};

    for (int k0 = 0; k0 < TWOK; k0 += 32) {
#pragma unroll
        for (int it = 0; it < 2; ++it) {
            int slot = tid + it * 256;
            int row = slot >> 2, kc = (slot & 3) * 8;
            int k = k0 + kc;
            int p = k >= K; int kk = k - p * K;
            int t = kk / CIN, ci = kk - t * CIN;
            int a = t >> 1, e = t & 1;
            int m = mBase + row;
            int b = m / (S * S); int rem = m - b * (S * S);
            int i = rem / S, j = rem % S;
            int ih = i + (a ? dh1 : dh0);
            int iw = j + (e ? dw1 : dw0);
            uint4 v = {0u, 0u, 0u, 0u};
            if ((unsigned)ih < (unsigned)S && (unsigned)iw < (unsigned)S)
                v = *(const uint4*)(X + ((size_t)((b * S + ih) * S + iw) * C2I + p * CIN + ci));
            *(uint4*)(&As[row][kc]) = v;
            uint4 w = *(const uint4*)(W + (size_t)(nBase + row) * TWOK + k);
            *(uint4*)(&Bs[row][kc]) = w;
        }
        __syncthreads();
        bf16x8 af[4], bfr[4];
#pragma unroll
        for (int s = 0; s < 4; ++s) {
            af[s]  = *(const bf16x8*)(&As[wm + s * 16 + lm][lq * 8]);
            bfr[s] = *(const bf16x8*)(&Bs[wn + s * 16 + lm][lq * 8]);
        }
#pragma unroll
        for (int sm = 0; sm < 4; ++sm)
#pragma unroll
            for (int sn = 0; sn < 4; ++sn)
                acc[sm][sn] = __builtin_amdgcn_mfma_f32_16x16x32_bf16(af[sm], bfr[sn], acc[sm][sn], 0, 0, 0);
        __syncthreads();
    }

#pragma unroll
    for (int sm = 0; sm < 4; ++sm) {
#pragma unroll
        for (int v = 0; v < 4; ++v) {
            int m = mBase + wm + sm * 16 + lq * 4 + v;
            int b = m / (S * S); int rem = m - b * (S * S);
            int i = rem / S, j = rem % S;
            int oh = 2 * i + py, ow = 2 * j + px;
            size_t rowoff = (size_t)((b * HOUT + oh) * HOUT + ow) * C2O;
#pragma unroll
            for (int sn = 0; sn < 4; ++sn) {
                int n = nBase + wn + sn * 16 + lm;
                float bias = (n < N) ? biasr[n] : biasi[n - N];
                Y[rowoff + n] = f2b(acc[sm][sn][v] + bias);
            }
        }
    }
}

// ---------------- MFMA GEMM 64x128 tiles (L2) ----------------
template<int CIN, int S, int N>
__global__ __launch_bounds__(256, 4) void gemm_convt64(
    const bf16* __restrict__ X, const bf16* __restrict__ Wall,
    const float* __restrict__ biasr, const float* __restrict__ biasi,
    bf16* __restrict__ Y) {
    constexpr int K = 4 * CIN, TWOK = 8 * CIN, C2I = 2 * CIN, C2O = 2 * N, HOUT = 2 * S;
    __shared__ short As[64][40];
    __shared__ short Bs[128][40];
    const int cls = blockIdx.z;
    const int py = cls >> 1, px = cls & 1;
    const bf16* W = Wall + (size_t)cls * 2 * N * TWOK;
    const int tid = threadIdx.x;
    const int mBase = blockIdx.x * 64, nBase = blockIdx.y * 128;
    const int wid = tid >> 6, lane = tid & 63;
    const int lm = lane & 15, lq = lane >> 4;
    const int dh0 = py ? 1 : 0, dh1 = py ? 0 : -1;
    const int dw0 = px ? 1 : 0, dw1 = px ? 0 : -1;

    f32x4 acc[8] = {};

    for (int k0 = 0; k0 < TWOK; k0 += 32) {
        {
            int row = tid >> 2, kc = (tid & 3) * 8;
            int k = k0 + kc;
            int p = k >= K; int kk = k - p * K;
            int t = kk / CIN, ci = kk - t * CIN;
            int a = t >> 1, e = t & 1;
            int m = mBase + row;
            int b = m / (S * S); int rem = m - b * (S * S);
            int i = rem / S, j = rem % S;
            int ih = i + (a ? dh1 : dh0);
            int iw = j + (e ? dw1 : dw0);
            uint4 v = {0u, 0u, 0u, 0u};
            if ((unsigned)ih < (unsigned)S && (unsigned)iw < (unsigned)S)
                v = *(const uint4*)(X + ((size_t)((b * S + ih) * S + iw) * C2I + p * CIN + ci));
            *(uint4*)(&As[row][kc]) = v;
        }
#pragma unroll
        for (int it = 0; it < 2; ++it) {
            int slot = tid + it * 256;
            int row = slot >> 2, kc = (slot & 3) * 8;
            uint4 w = *(const uint4*)(W + (size_t)(nBase + row) * TWOK + k0 + kc);
            *(uint4*)(&Bs[row][kc]) = w;
        }
        __syncthreads();
        bf16x8 af = *(const bf16x8*)(&As[wid * 16 + lm][lq * 8]);
#pragma unroll
        for (int sn = 0; sn < 8; ++sn) {
            bf16x8 bfr = *(const bf16x8*)(&Bs[sn * 16 + lm][lq * 8]);
            acc[sn] = __builtin_amdgcn_mfma_f32_16x16x32_bf16(af, bfr, acc[sn], 0, 0, 0);
        }
        __syncthreads();
    }

#pragma unroll
    for (int v = 0; v < 4; ++v) {
        int m = mBase + wid * 16 + lq * 4 + v;
        int b = m / (S * S); int rem = m - b * (S * S);
        int i = rem / S, j = rem % S;
        int oh = 2 * i + py, ow = 2 * j + px;
        size_t rowoff = (size_t)((b * HOUT + oh) * HOUT + ow) * C2O;
#pragma unroll
        for (int sn = 0; sn < 8; ++sn) {
            int n = nBase + sn * 16 + lm;
            float bias = (n < N) ? biasr[n] : biasi[n - N];
            Y[rowoff + n] = f2b(acc[sn][v] + bias);
        }
    }
}

// ---------------- layer4 via MFMA ----------------
__global__ __launch_bounds__(256, 2) void conv4_mfma(
    const bf16* __restrict__ X, const bf16* __restrict__ Wall,
    const float* __restrict__ br, float* __restrict__ out) {
    constexpr int CIN = 128, S = 16, K = 512, TWOK = 1024, C2I = 256;
    __shared__ short As[128][40];
    __shared__ short Bs[16][40];
    const int cls = blockIdx.z;
    const int py = cls >> 1, px = cls & 1;
    const bf16* W = Wall + (size_t)cls * 16 * TWOK;
    const int tid = threadIdx.x;
    const int mBase = blockIdx.x * 128;
    const int wid = tid >> 6, lane = tid & 63;
    const int wm = wid * 32;
    const int lm = lane & 15, lq = lane >> 4;
    const int dh0 = py ? 1 : 0, dh1 = py ? 0 : -1;
    const int dw0 = px ? 1 : 0, dw1 = px ? 0 : -1;

    f32x4 acc[2] = {};

    for (int k0 = 0; k0 < TWOK; k0 += 32) {
#pragma unroll
        for (int it = 0; it < 2; ++it) {
            int slot = tid + it * 256;
            int row = slot >> 2, kc = (slot & 3) * 8;
            int k = k0 + kc;
            int p = k >= K; int kk = k - p * K;
            int t = kk >> 7, ci = kk & 127;
            int a = t >> 1, e = t & 1;
            int m = mBase + row;
            int b = m >> 8; int rem = m & 255;
            int i = rem >> 4, j = rem & 15;
            int ih = i + (a ? dh1 : dh0);
            int iw = j + (e ? dw1 : dw0);
            uint4 v = {0u, 0u, 0u, 0u};
            if ((unsigned)ih < (unsigned)S && (unsigned)iw < (unsigned)S)
                v = *(const uint4*)(X + ((size_t)((b * S + ih) * S + iw) * C2I + p * CIN + ci));
            *(uint4*)(&As[row][kc]) = v;
        }
        if (tid < 64) {
            int row = tid >> 2, kc = (tid & 3) * 8;
            uint4 w = *(const uint4*)(W + (size_t)row * TWOK + k0 + kc);
            *(uint4*)(&Bs[row][kc]) = w;
        }
        __syncthreads();
        bf16x8 bfr = *(const bf16x8*)(&Bs[lm][lq * 8]);
        bf16x8 af0 = *(const bf16x8*)(&As[wm + lm][lq * 8]);
        bf16x8 af1 = *(const bf16x8*)(&As[wm + 16 + lm][lq * 8]);
        acc[0] = __builtin_amdgcn_mfma_f32_16x16x32_bf16(af0, bfr, acc[0], 0, 0, 0);
        acc[1] = __builtin_amdgcn_mfma_f32_16x16x32_bf16(af1, bfr, acc[1], 0, 0, 0);
        __syncthreads();
    }

    int n = lm;
    if (n < NCH) {
        float bias = br[n];
#pragma unroll
        for (int s = 0; s < 2; ++s) {
#pragma unroll
            for (int v = 0; v < 4; ++v) {
                int m = mBase + wm + s * 16 + lq * 4 + v;
                int b = m >> 8; int rem = m & 255;
                int i = rem >> 4, j = rem & 15;
                int oh = 2 * i + py, ow = 2 * j + px;
                out[((size_t)(b * NCH + n) * 32 + oh) * 32 + ow] = tanhf(acc[s][v] + bias);
            }
        }
    }
}

extern "C" void kernel_launch(void* const* d_in, const int* in_sizes, int n_in,
                              void* d_out, int out_size, void* d_ws, size_t ws_size,
                              hipStream_t stream) {
    const float* noise_re = (const float*)d_in[0];
    const float* noise_im = (const float*)d_in[1];
    const int*   labels   = (const int*)d_in[2];
    const float* emb      = (const float*)d_in[3];
    const float* w1r = (const float*)d_in[4],  *w1i = (const float*)d_in[5];
    const float* b1r = (const float*)d_in[6],  *b1i = (const float*)d_in[7];
    const float* g1rr = (const float*)d_in[8], *g1ri = (const float*)d_in[9], *g1ii = (const float*)d_in[10];
    const float* n1br = (const float*)d_in[11], *n1bi = (const float*)d_in[12];
    const float* w2r = (const float*)d_in[13], *w2i = (const float*)d_in[14];
    const float* b2r = (const float*)d_in[15], *b2i = (const float*)d_in[16];
    const float* g2rr = (const float*)d_in[17], *g2ri = (const float*)d_in[18], *g2ii = (const float*)d_in[19];
    const float* n2br = (const float*)d_in[20], *n2bi = (const float*)d_in[21];
    const float* w3r = (const float*)d_in[22], *w3i = (const float*)d_in[23];
    const float* b3r = (const float*)d_in[24], *b3i = (const float*)d_in[25];
    const float* g3rr = (const float*)d_in[26], *g3ri = (const float*)d_in[27], *g3ii = (const float*)d_in[28];
    const float* n3br = (const float*)d_in[29], *n3bi = (const float*)d_in[30];
    const float* w4r = (const float*)d_in[31], *w4i = (const float*)d_in[32];
    const float* b4r = (const float*)d_in[33], *b4i = (const float*)d_in[34];

    // ---- workspace layout (bytes) ----
    // y3cl region [0, 33554432)  [256][16][16][256] bf16, written by gemmL3
    //   overlay (all dead before gemmL3):
    //     x1cl   [0, 8388608)
    //     B1     [8388608, 15728640)       [16384][224] bf16
    //     W2all  [15728640, 32505856)      [4][512][4096] bf16
    //     partials12 [32505856, 32833536)  32*512*5 fp32 (used for BN1/BN2 stats)
    // y2cl  [33554432, 50331648)  [256][8][8][512] bf16
    // W3all [50331648, 54525952)  [4][256][2048] bf16; after gemmL3: partials3 overlay
    // tail:
    //   coefSoA1 [54525952, 54538240)  6*512 fp32
    //   coefSoA2 [54538240, 54544384)  6*256 fp32
    //   coefSoA3 [54544384, 54547456)  6*128 fp32
    //   x0bf     [54547456, 54662144)  [256][224] bf16
    //   W4all    [54662144, 54793216)  [4][16][1024] bf16
    char* ws = (char*)d_ws;
    bf16* y3cl = (bf16*)ws;
    bf16* x1cl = (bf16*)ws;
    bf16* B1    = (bf16*)(ws + 8388608);
    bf16* W2all = (bf16*)(ws + 15728640);
    float* part12 = (float*)(ws + 32505856);
    bf16* y2cl  = (bf16*)(ws + 33554432);
    bf16* W3all = (bf16*)(ws + 50331648);
    float* part3 = (float*)(ws + 50331648);   // overlays W3all AFTER gemmL3 consumed it
    float* coef1 = (float*)(ws + 54525952);
    float* coef2 = (float*)(ws + 54538240);
    float* coef3 = (float*)(ws + 54544384);
    bf16* x0bf  = (bf16*)(ws + 54547456);
    bf16* W4all = (bf16*)(ws + 54662144);

    build_x0bf<<<224, 256, 0, stream>>>(noise_re, noise_im, labels, emb, x0bf);
    wprep_combined<<<NB_W1 + NB_W2 + NB_W3 + NB_W4, 256, 0, stream>>>(
        w1r, w1i, w2r, w2i, w3r, w3i, w4r, w4i, B1, W2all, W3all, W4all);

    // L1 GEMM -> x1cl
    gemm1<<<dim3(2, 128), 256, 0, stream>>>(x0bf, B1, b1r, b1i, x1cl);

    // BN1 (C=512, rows=4096): logG=6, rowsPerSlice = 4096/32/4 = 32
    bn_stats_v<<<32, 256, 0, stream>>>(x1cl, part12, C1, 6, 32);
    bn_coef_v<<<2, 256, 0, stream>>>(part12, g1rr, g1ri, g1ii, n1br, n1bi, coef1, C1, 1.f / 4096.f);
    bn_apply_v<<<1024, 256, 0, stream>>>(x1cl, coef1, C1, 6, 4096 * 64);

    // L2 GEMM (merged 4-class, 64x128 tiles) -> y2cl
    gemm_convt64<C1, 4, C2><<<dim3(64, 4, 4), 256, 0, stream>>>(x1cl, W2all, b2r, b2i, y2cl);

    // BN2 (C=256, rows=16384): logG=5, rowsPerSlice = 16384/32/8 = 64
    bn_stats_v<<<32, 256, 0, stream>>>(y2cl, part12, C2, 5, 64);
    bn_coef_v<<<1, 256, 0, stream>>>(part12, g2rr, g2ri, g2ii, n2br, n2bi, coef2, C2, 1.f / 16384.f);
    bn_apply_v<<<2048, 256, 0, stream>>>(y2cl, coef2, C2, 5, 16384 * 32);

    // L3 GEMM (merged 4-class, 128x128 tiles) -> y3cl
    gemm_convt<C2, 8, C3><<<dim3(128, 2, 4), 256, 0, stream>>>(y2cl, W3all, b3r, b3i, y3cl);

    // BN3 (C=128, rows=65536): logG=4, rowsPerSlice = 65536/32/16 = 128
    bn_stats_v<<<32, 256, 0, stream>>>(y3cl, part3, C3, 4, 128);
    bn_coef_v<<<1, 256, 0, stream>>>(part3, g3rr, g3ri, g3ii, n3br, n3bi, coef3, C3, 1.f / 65536.f);
    bn_apply_v<<<4096, 256, 0, stream>>>(y3cl, coef3, C3, 4, 65536 * 16);

    // L4: MFMA + tanh -> d_out (real part, fp32)
    conv4_mfma<<<dim3(512, 1, 4), 256, 0, stream>>>(y3cl, W4all, b4r, (float*)d_out);
}

// Round 13
// 577.752 us; speedup vs baseline: 21.4719x; 1.2371x over previous
//
#include <hip/hip_runtime.h>
#include <hip/hip_bf16.h>
#include <math.h>

#define BATCH 256
#define LAT 100
#define NCLS 10
#define CIN0 110
#define C1 512
#define C2 256
#define C3 128
#define NCH 3
#define EPS 1e-5f

typedef __hip_bfloat16 bf16;
typedef short bf16x8 __attribute__((ext_vector_type(8)));
typedef float f32x4 __attribute__((ext_vector_type(4)));

__device__ __forceinline__ float b2f(bf16 v) { return __bfloat162float(v); }
__device__ __forceinline__ bf16 f2b(float v) { return __float2bfloat16(v); }
__device__ __forceinline__ float s2f(short s) {
    unsigned u = ((unsigned)(unsigned short)s) << 16;
    return __builtin_bit_cast(float, u);
}
__device__ __forceinline__ short f2s(float f) {
    bf16 b = __float2bfloat16(f);
    return *(short*)&b;
}

// ---------------- build x0 as bf16 GEMM-A: [256][224] ----------------
__global__ void build_x0bf(const float* __restrict__ nre, const float* __restrict__ nim,
                           const int* __restrict__ labels, const float* __restrict__ emb,
                           bf16* __restrict__ A) {
    int idx = blockIdx.x * blockDim.x + threadIdx.x;
    if (idx >= BATCH * 224) return;
    int b = idx / 224, k = idx - b * 224;
    int p = k >= 112; int ci = k - p * 112;
    float v = 0.f;
    if (ci < CIN0) {
        if (!p) v = (ci < LAT) ? nre[b * LAT + ci] : emb[labels[b] * NCLS + (ci - LAT)];
        else    v = (ci < LAT) ? nim[b * LAT + ci] : 0.f;
    }
    A[idx] = f2b(v);
}

// ---------------- combined weight prep ----------------
// B1: [16384][224] row-major (for gemm1's LDS path).
// W2all/W3all: MFMA-fragment panel layout:
//   panel(cls, nb, kb) at ((cls*(2N/128)+nb)*(TWOK/32)+kb)*4096 elements, 8KB each;
//   within panel: element (f, l, j) at (f*64+l)*8+j  holds
//   W[n = nb*128 + (f>>2)*64 + (f&3)*16 + (l&15)][k = kb*32 + (l>>4)*8 + j]
// W4all: [cls][16][1024] row-major (conv4's LDS path).
#define NB_W1 14336
#define NB_W2 32768
#define NB_W3 8192
#define NB_W4 256

__device__ __forceinline__ float wval(const float* wr, const float* wi,
                                      int CIN, int N, int K, int cls, int n, int k) {
    int py = cls >> 1, px = cls & 1;
    int p = k >= K; int kk = k - p * K;
    int t = kk / CIN, ci = kk - t * CIN;
    int a = t >> 1, e = t & 1;
    int kh = py ? (a ? 2 : 0) : (a ? 3 : 1);
    int kw = px ? (e ? 2 : 0) : (e ? 3 : 1);
    int co = (n < N) ? n : n - N;
    size_t widx = ((size_t)ci * N + co) * 16 + kh * 4 + kw;
    float vr = wr[widx], vi = wi[widx];
    return (n < N) ? (p ? -vi : vr) : (p ? vr : vi);
}

__device__ __forceinline__ void w1prep_body(const float* wr, const float* wi, bf16* B, int idx) {
    if (idx >= 16384 * 224) return;
    int n = idx / 224, k = idx - n * 224;
    int p = n >> 10, cop = n & 1023;
    int pk = k >= 112; int ci = k - pk * 112;
    float v = 0.f;
    if (ci < CIN0) {
        int co = (cop < C1) ? cop : cop - C1;
        size_t widx = ((size_t)ci * C1 + co) * 16 + p;
        float vr = wr[widx], vi = wi[widx];
        v = (cop < C1) ? (pk ? -vi : vr) : (pk ? vr : vi);
    }
    B[idx] = f2b(v);
}

__device__ __forceinline__ void wprep_panel_body(const float* wr, const float* wi, bf16* W,
                                                 int CIN, int N, size_t idx) {
    int K = 4 * CIN, TWOK = 8 * CIN;
    size_t per_cls = (size_t)2 * N * TWOK;
    if (idx >= 4 * per_cls) return;
    int cls = (int)(idx / per_cls);
    size_t r = idx - (size_t)cls * per_cls;
    size_t chunk_nb = (size_t)TWOK * 128;
    int nb = (int)(r / chunk_nb);
    int r2 = (int)(r - (size_t)nb * chunk_nb);
    int kb = r2 >> 12;          // /4096
    int w = r2 & 4095;
    int f = w >> 9;             // /512
    int l = (w >> 3) & 63;
    int j = w & 7;
    int n = nb * 128 + (f >> 2) * 64 + (f & 3) * 16 + (l & 15);
    int k = kb * 32 + (l >> 4) * 8 + j;
    W[idx] = f2b(wval(wr, wi, CIN, N, K, cls, n, k));
}

__device__ __forceinline__ void wprep4_body(const float* wr, const float* wi, bf16* W, int idx) {
    if (idx >= 65536) return;
    int cls = idx >> 14, rem = idx & 16383;
    int py = cls >> 1, px = cls & 1;
    int n = rem >> 10, k = rem & 1023;
    float v = 0.f;
    if (n < NCH) {
        int p = k >= 512; int kk = k - p * 512;
        int t = kk >> 7, ci = kk & 127;
        int a = t >> 1, e = t & 1;
        int kh = py ? (a ? 2 : 0) : (a ? 3 : 1);
        int kw = px ? (e ? 2 : 0) : (e ? 3 : 1);
        size_t widx = ((size_t)ci * NCH + n) * 16 + kh * 4 + kw;
        v = p ? -wi[widx] : wr[widx];
    }
    W[idx] = f2b(v);
}

__global__ void wprep_combined(const float* __restrict__ w1r, const float* __restrict__ w1i,
                               const float* __restrict__ w2r, const float* __restrict__ w2i,
                               const float* __restrict__ w3r, const float* __restrict__ w3i,
                               const float* __restrict__ w4r, const float* __restrict__ w4i,
                               bf16* __restrict__ B1, bf16* __restrict__ W2all,
                               bf16* __restrict__ W3all, bf16* __restrict__ W4all) {
    int bid = blockIdx.x;
    if (bid < NB_W1) {
        w1prep_body(w1r, w1i, B1, bid * 256 + threadIdx.x);
    } else if (bid < NB_W1 + NB_W2) {
        wprep_panel_body(w2r, w2i, W2all, C1, C2, (size_t)(bid - NB_W1) * 256 + threadIdx.x);
    } else if (bid < NB_W1 + NB_W2 + NB_W3) {
        wprep_panel_body(w3r, w3i, W3all, C2, C3, (size_t)(bid - NB_W1 - NB_W2) * 256 + threadIdx.x);
    } else {
        wprep4_body(w4r, w4i, W4all, (bid - NB_W1 - NB_W2 - NB_W3) * 256 + threadIdx.x);
    }
}

// ---------------- gemm1: C[256][16384] = A[256][224] x B1^T -> x1cl ----------------
__global__ __launch_bounds__(256, 1) void gemm1(
    const bf16* __restrict__ A, const bf16* __restrict__ B,
    const float* __restrict__ b1r, const float* __restrict__ b1i,
    bf16* __restrict__ Y) {
    __shared__ short As[128][40];
    __shared__ short Bs[128][40];
    const int tid = threadIdx.x;
    const int mBase = blockIdx.x * 128, nBase = blockIdx.y * 128;
    const int wid = tid >> 6, lane = tid & 63;
    const int wm = (wid >> 1) * 64, wn = (wid & 1) * 64;
    const int lm = lane & 15, lq = lane >> 4;

    f32x4 acc[4][4] = {};

    for (int k0 = 0; k0 < 224; k0 += 32) {
#pragma unroll
        for (int it = 0; it < 2; ++it) {
            int slot = tid + it * 256;
            int row = slot >> 2, kc = (slot & 3) * 8;
            int k = k0 + kc;
            *(uint4*)(&As[row][kc]) = *(const uint4*)(A + (size_t)(mBase + row) * 224 + k);
            *(uint4*)(&Bs[row][kc]) = *(const uint4*)(B + (size_t)(nBase + row) * 224 + k);
        }
        __syncthreads();
        bf16x8 af[4], bfr[4];
#pragma unroll
        for (int s = 0; s < 4; ++s) {
            af[s]  = *(const bf16x8*)(&As[wm + s * 16 + lm][lq * 8]);
            bfr[s] = *(const bf16x8*)(&Bs[wn + s * 16 + lm][lq * 8]);
        }
#pragma unroll
        for (int sm = 0; sm < 4; ++sm)
#pragma unroll
            for (int sn = 0; sn < 4; ++sn)
                acc[sm][sn] = __builtin_amdgcn_mfma_f32_16x16x32_bf16(af[sm], bfr[sn], acc[sm][sn], 0, 0, 0);
        __syncthreads();
    }

#pragma unroll
    for (int sm = 0; sm < 4; ++sm) {
#pragma unroll
        for (int v = 0; v < 4; ++v) {
            int m = mBase + wm + sm * 16 + lq * 4 + v;
#pragma unroll
            for (int sn = 0; sn < 4; ++sn) {
                int n = nBase + wn + sn * 16 + lm;
                int cop = n & 1023;
                float bias = (cop < C1) ? b1r[cop] : b1i[cop - C1];
                Y[(size_t)m * 16384 + n] = f2b(acc[sm][sn][v] + bias);
            }
        }
    }
}

// ---------------- BN stats: vectorized x8, 64 blocks of per-block partials ----------------
__global__ void bn_stats_v(const bf16* __restrict__ Y, float* __restrict__ P,
                           int C, int logG, int rowsPerSlice) {
    const int tid = threadIdx.x;
    const int G = 1 << logG;
    const int g = tid & (G - 1);
    const int slice = tid >> logG;
    const int nsl = 256 >> logG;
    const int r0 = blockIdx.x * rowsPerSlice * nsl + slice * rowsPerSlice;
    const int CC = 2 * C;

    float sr[8] = {}, si[8] = {}, srr[8] = {}, sii[8] = {}, sri[8] = {};
    for (int r = r0; r < r0 + rowsPerSlice; ++r) {
        const bf16* p = Y + (size_t)r * CC + g * 8;
        bf16x8 vr8 = *(const bf16x8*)p;
        bf16x8 vi8 = *(const bf16x8*)(p + C);
#pragma unroll
        for (int j = 0; j < 8; ++j) {
            float vr = s2f(vr8[j]), vi = s2f(vi8[j]);
            sr[j] += vr; si[j] += vi;
            srr[j] += vr * vr; sii[j] += vi * vi; sri[j] += vr * vi;
        }
    }
    __shared__ float red[5][512];
    for (int i = tid; i < 5 * 512; i += 256) ((float*)red)[i] = 0.f;
    __syncthreads();
#pragma unroll
    for (int j = 0; j < 8; ++j) {
        int c = g * 8 + j;
        atomicAdd(&red[0][c], sr[j]);
        atomicAdd(&red[1][c], si[j]);
        atomicAdd(&red[2][c], srr[j]);
        atomicAdd(&red[3][c], sii[j]);
        atomicAdd(&red[4][c], sri[j]);
    }
    __syncthreads();
    for (int c = tid; c < C; c += 256) {
        float* dst = P + ((size_t)blockIdx.x * C + c) * 5;
        dst[0] = red[0][c]; dst[1] = red[1][c]; dst[2] = red[2][c];
        dst[3] = red[3][c]; dst[4] = red[4][c];
    }
}

// ---------------- coef: reduce 64 partials + whitening + affine fold ----------------
__global__ void bn_coef_v(const float* __restrict__ P,
                          const float* __restrict__ grr, const float* __restrict__ gri,
                          const float* __restrict__ gii,
                          const float* __restrict__ betar, const float* __restrict__ betai,
                          float* __restrict__ coef, int C, float invN) {
    int c = blockIdx.x * blockDim.x + threadIdx.x;
    if (c >= C) return;
    float sr = 0, si = 0, srr = 0, sii = 0, sri = 0;
    for (int b = 0; b < 64; ++b) {
        const float* p = P + ((size_t)b * C + c) * 5;
        sr += p[0]; si += p[1]; srr += p[2]; sii += p[3]; sri += p[4];
    }
    float mr = sr * invN, mi = si * invN;
    float crr = srr * invN - mr * mr + EPS;
    float cii = sii * invN - mi * mi + EPS;
    float cri = sri * invN - mr * mi;
    float s = sqrtf(crr * cii - cri * cri);
    float t = sqrtf(crr + cii + 2.f * s);
    float inv = 1.f / (s * t);
    float rrr = (cii + s) * inv, rii = (crr + s) * inv, rri = -cri * inv;
    float Grr = grr[c], Gri = gri[c], Gii = gii[c];
    float arr = Grr * rrr + Gri * rri, ari = Grr * rri + Gri * rii;
    float air = Gri * rrr + Gii * rri, aii = Gri * rri + Gii * rii;
    coef[0 * C + c] = arr;
    coef[1 * C + c] = ari;
    coef[2 * C + c] = betar[c] - arr * mr - ari * mi;
    coef[3 * C + c] = air;
    coef[4 * C + c] = aii;
    coef[5 * C + c] = betai[c] - air * mr - aii * mi;
}

// ---------------- BN apply+ReLU: vectorized x8 ----------------
__global__ void bn_apply_v(bf16* __restrict__ Y, const float* __restrict__ coef,
                           int C, int logG, int total) {
    int idx = blockIdx.x * 256 + threadIdx.x;
    if (idx >= total) return;
    int G = 1 << logG;
    int g = idx & (G - 1);
    size_t base = (size_t)(idx >> logG) * 2 * C + g * 8;
    bf16x8 vr8 = *(const bf16x8*)(Y + base);
    bf16x8 vi8 = *(const bf16x8*)(Y + base + C);
    bf16x8 or8, oi8;
#pragma unroll
    for (int j = 0; j < 8; ++j) {
        int c = g * 8 + j;
        float vr = s2f(vr8[j]), vi = s2f(vi8[j]);
        float orr = fmaxf(coef[0 * C + c] * vr + coef[1 * C + c] * vi + coef[2 * C + c], 0.f);
        float oii = fmaxf(coef[3 * C + c] * vr + coef[4 * C + c] * vi + coef[5 * C + c], 0.f);
        or8[j] = f2s(orr); oi8[j] = f2s(oii);
    }
    *(bf16x8*)(Y + base) = or8;
    *(bf16x8*)(Y + base + C) = oi8;
}

// ---------------- MFMA GEMM 128x128, B direct-from-global (fragment panels) ----------------
// A staged in LDS (im2col gather); B fragments loaded coalesced from swizzled Wall,
// double-buffered across K-steps to hide global latency under MFMA.
template<int CIN, int S, int N>
__global__ __launch_bounds__(256, 2) void gemm_convt_bd(
    const bf16* __restrict__ X, const bf16* __restrict__ Wall,
    const float* __restrict__ biasr, const float* __restrict__ biasi,
    bf16* __restrict__ Y) {
    constexpr int K = 4 * CIN, TWOK = 8 * CIN, C2I = 2 * CIN, C2O = 2 * N, HOUT = 2 * S;
    __shared__ short As[128][40];
    const int cls = blockIdx.z;
    const int py = cls >> 1, px = cls & 1;
    const int tid = threadIdx.x;
    const int mBase = blockIdx.x * 128, nBase = blockIdx.y * 128;
    const int wid = tid >> 6, lane = tid & 63;
    const int wm = (wid >> 1) * 64, wn = (wid & 1) * 64;
    const int lm = lane & 15, lq = lane >> 4;
    const int dh0 = py ? 1 : 0, dh1 = py ? 0 : -1;
    const int dw0 = px ? 1 : 0, dw1 = px ? 0 : -1;

    // per-wave fragment base into the swizzled weight panels
    const bf16* Wp = Wall
        + ((size_t)(cls * (C2O / 128) + blockIdx.y) * (TWOK / 32)) * 4096
        + ((wn >> 6) * 4) * 512 + lane * 8;

    f32x4 acc[4][4] = {};
    bf16x8 bq[4];
#pragma unroll
    for (int sn = 0; sn < 4; ++sn) bq[sn] = *(const bf16x8*)(Wp + sn * 512);

    for (int k0 = 0; k0 < TWOK; k0 += 32) {
#pragma unroll
        for (int it = 0; it < 2; ++it) {
            int slot = tid + it * 256;          // 512 A slots of 8 bf16
            int row = slot >> 2, kc = (slot & 3) * 8;
            int k = k0 + kc;
            int p = k >= K; int kk = k - p * K;
            int t = kk / CIN, ci = kk - t * CIN;
            int a = t >> 1, e = t & 1;
            int m = mBase + row;
            int b = m / (S * S); int rem = m - b * (S * S);
            int i = rem / S, j = rem % S;
            int ih = i + (a ? dh1 : dh0);
            int iw = j + (e ? dw1 : dw0);
            uint4 v = {0u, 0u, 0u, 0u};
            if ((unsigned)ih < (unsigned)S && (unsigned)iw < (unsigned)S)
                v = *(const uint4*)(X + ((size_t)((b * S + ih) * S + iw) * C2I + p * CIN + ci));
            *(uint4*)(&As[row][kc]) = v;
        }
        __syncthreads();
        bf16x8 bcur[4];
#pragma unroll
        for (int sn = 0; sn < 4; ++sn) bcur[sn] = bq[sn];
        if (k0 + 32 < TWOK) {
            const bf16* Wn = Wp + (size_t)((k0 >> 5) + 1) * 4096;
#pragma unroll
            for (int sn = 0; sn < 4; ++sn) bq[sn] = *(const bf16x8*)(Wn + sn * 512);
        }
        bf16x8 af[4];
#pragma unroll
        for (int s = 0; s < 4; ++s)
            af[s] = *(const bf16x8*)(&As[wm + s * 16 + lm][lq * 8]);
#pragma unroll
        for (int sm = 0; sm < 4; ++sm)
#pragma unroll
            for (int sn = 0; sn < 4; ++sn)
                acc[sm][sn] = __builtin_amdgcn_mfma_f32_16x16x32_bf16(af[sm], bcur[sn], acc[sm][sn], 0, 0, 0);
        __syncthreads();
    }

#pragma unroll
    for (int sm = 0; sm < 4; ++sm) {
#pragma unroll
        for (int v = 0; v < 4; ++v) {
            int m = mBase + wm + sm * 16 + lq * 4 + v;
            int b = m / (S * S); int rem = m - b * (S * S);
            int i = rem / S, j = rem % S;
            int oh = 2 * i + py, ow = 2 * j + px;
            size_t rowoff = (size_t)((b * HOUT + oh) * HOUT + ow) * C2O;
#pragma unroll
            for (int sn = 0; sn < 4; ++sn) {
                int n = nBase + wn + sn * 16 + lm;
                float bias = (n < N) ? biasr[n] : biasi[n - N];
                Y[rowoff + n] = f2b(acc[sm][sn][v] + bias);
            }
        }
    }
}

// ---------------- layer4 via MFMA ----------------
__global__ __launch_bounds__(256, 2) void conv4_mfma(
    const bf16* __restrict__ X, const bf16* __restrict__ Wall,
    const float* __restrict__ br, float* __restrict__ out) {
    constexpr int CIN = 128, S = 16, K = 512, TWOK = 1024, C2I = 256;
    __shared__ short As[128][40];
    __shared__ short Bs[16][40];
    const int cls = blockIdx.z;
    const int py = cls >> 1, px = cls & 1;
    const bf16* W = Wall + (size_t)cls * 16 * TWOK;
    const int tid = threadIdx.x;
    const int mBase = blockIdx.x * 128;
    const int wid = tid >> 6, lane = tid & 63;
    const int wm = wid * 32;
    const int lm = lane & 15, lq = lane >> 4;
    const int dh0 = py ? 1 : 0, dh1 = py ? 0 : -1;
    const int dw0 = px ? 1 : 0, dw1 = px ? 0 : -1;

    f32x4 acc[2] = {};

    for (int k0 = 0; k0 < TWOK; k0 += 32) {
#pragma unroll
        for (int it = 0; it < 2; ++it) {
            int slot = tid + it * 256;
            int row = slot >> 2, kc = (slot & 3) * 8;
            int k = k0 + kc;
            int p = k >= K; int kk = k - p * K;
            int t = kk >> 7, ci = kk & 127;
            int a = t >> 1, e = t & 1;
            int m = mBase + row;
            int b = m >> 8; int rem = m & 255;
            int i = rem >> 4, j = rem & 15;
            int ih = i + (a ? dh1 : dh0);
            int iw = j + (e ? dw1 : dw0);
            uint4 v = {0u, 0u, 0u, 0u};
            if ((unsigned)ih < (unsigned)S && (unsigned)iw < (unsigned)S)
                v = *(const uint4*)(X + ((size_t)((b * S + ih) * S + iw) * C2I + p * CIN + ci));
            *(uint4*)(&As[row][kc]) = v;
        }
        if (tid < 64) {
            int row = tid >> 2, kc = (tid & 3) * 8;
            uint4 w = *(const uint4*)(W + (size_t)row * TWOK + k0 + kc);
            *(uint4*)(&Bs[row][kc]) = w;
        }
        __syncthreads();
        bf16x8 bfr = *(const bf16x8*)(&Bs[lm][lq * 8]);
        bf16x8 af0 = *(const bf16x8*)(&As[wm + lm][lq * 8]);
        bf16x8 af1 = *(const bf16x8*)(&As[wm + 16 + lm][lq * 8]);
        acc[0] = __builtin_amdgcn_mfma_f32_16x16x32_bf16(af0, bfr, acc[0], 0, 0, 0);
        acc[1] = __builtin_amdgcn_mfma_f32_16x16x32_bf16(af1, bfr, acc[1], 0, 0, 0);
        __syncthreads();
    }

    int n = lm;
    if (n < NCH) {
        float bias = br[n];
#pragma unroll
        for (int s = 0; s < 2; ++s) {
#pragma unroll
            for (int v = 0; v < 4; ++v) {
                int m = mBase + wm + s * 16 + lq * 4 + v;
                int b = m >> 8; int rem = m & 255;
                int i = rem >> 4, j = rem & 15;
                int oh = 2 * i + py, ow = 2 * j + px;
                out[((size_t)(b * NCH + n) * 32 + oh) * 32 + ow] = tanhf(acc[s][v] + bias);
            }
        }
    }
}

extern "C" void kernel_launch(void* const* d_in, const int* in_sizes, int n_in,
                              void* d_out, int out_size, void* d_ws, size_t ws_size,
                              hipStream_t stream) {
    const float* noise_re = (const float*)d_in[0];
    const float* noise_im = (const float*)d_in[1];
    const int*   labels   = (const int*)d_in[2];
    const float* emb      = (const float*)d_in[3];
    const float* w1r = (const float*)d_in[4],  *w1i = (const float*)d_in[5];
    const float* b1r = (const float*)d_in[6],  *b1i = (const float*)d_in[7];
    const float* g1rr = (const float*)d_in[8], *g1ri = (const float*)d_in[9], *g1ii = (const float*)d_in[10];
    const float* n1br = (const float*)d_in[11], *n1bi = (const float*)d_in[12];
    const float* w2r = (const float*)d_in[13], *w2i = (const float*)d_in[14];
    const float* b2r = (const float*)d_in[15], *b2i = (const float*)d_in[16];
    const float* g2rr = (const float*)d_in[17], *g2ri = (const float*)d_in[18], *g2ii = (const float*)d_in[19];
    const float* n2br = (const float*)d_in[20], *n2bi = (const float*)d_in[21];
    const float* w3r = (const float*)d_in[22], *w3i = (const float*)d_in[23];
    const float* b3r = (const float*)d_in[24], *b3i = (const float*)d_in[25];
    const float* g3rr = (const float*)d_in[26], *g3ri = (const float*)d_in[27], *g3ii = (const float*)d_in[28];
    const float* n3br = (const float*)d_in[29], *n3bi = (const float*)d_in[30];
    const float* w4r = (const float*)d_in[31], *w4i = (const float*)d_in[32];
    const float* b4r = (const float*)d_in[33], *b4i = (const float*)d_in[34];

    // ---- workspace layout (bytes) ----
    // y3cl region [0, 33554432) — written by gemmL3. Overlays (dead before gemmL3):
    //   x1cl   [0, 8388608)
    //   B1     [8388608, 15728640)
    //   W2all  [15728640, 32505856)   swizzled panels [4][512][4096]
    //   part12 [32505856, 33161216)   64*512*5 fp32 (BN1, BN2 partials)
    // y2cl  [33554432, 50331648)
    // W3all [50331648, 54525952)      swizzled panels; after gemmL3 -> part3 overlay
    // tail: coef1 [54525952) coef2 [54538240) coef3 [54544384)
    //       x0bf [54547456) W4all [54662144, 54793216)
    char* ws = (char*)d_ws;
    bf16* y3cl = (bf16*)ws;
    bf16* x1cl = (bf16*)ws;
    bf16* B1    = (bf16*)(ws + 8388608);
    bf16* W2all = (bf16*)(ws + 15728640);
    float* part12 = (float*)(ws + 32505856);
    bf16* y2cl  = (bf16*)(ws + 33554432);
    bf16* W3all = (bf16*)(ws + 50331648);
    float* part3 = (float*)(ws + 50331648);   // overlays W3all AFTER gemmL3
    float* coef1 = (float*)(ws + 54525952);
    float* coef2 = (float*)(ws + 54538240);
    float* coef3 = (float*)(ws + 54544384);
    bf16* x0bf  = (bf16*)(ws + 54547456);
    bf16* W4all = (bf16*)(ws + 54662144);

    build_x0bf<<<224, 256, 0, stream>>>(noise_re, noise_im, labels, emb, x0bf);
    wprep_combined<<<NB_W1 + NB_W2 + NB_W3 + NB_W4, 256, 0, stream>>>(
        w1r, w1i, w2r, w2i, w3r, w3i, w4r, w4i, B1, W2all, W3all, W4all);

    // L1 GEMM -> x1cl
    gemm1<<<dim3(2, 128), 256, 0, stream>>>(x0bf, B1, b1r, b1i, x1cl);

    // BN1 (C=512, rows=4096): 64 blocks, logG=6 (nsl=4), rowsPerSlice=16
    bn_stats_v<<<64, 256, 0, stream>>>(x1cl, part12, C1, 6, 16);
    bn_coef_v<<<2, 256, 0, stream>>>(part12, g1rr, g1ri, g1ii, n1br, n1bi, coef1, C1, 1.f / 4096.f);
    bn_apply_v<<<1024, 256, 0, stream>>>(x1cl, coef1, C1, 6, 4096 * 64);

    // L2 GEMM: 128x128 tiles, B-direct, 4 classes -> 512 blocks
    gemm_convt_bd<C1, 4, C2><<<dim3(32, 4, 4), 256, 0, stream>>>(x1cl, W2all, b2r, b2i, y2cl);

    // BN2 (C=256, rows=16384): 64 blocks, logG=5 (nsl=8), rowsPerSlice=32
    bn_stats_v<<<64, 256, 0, stream>>>(y2cl, part12, C2, 5, 32);
    bn_coef_v<<<1, 256, 0, stream>>>(part12, g2rr, g2ri, g2ii, n2br, n2bi, coef2, C2, 1.f / 16384.f);
    bn_apply_v<<<2048, 256, 0, stream>>>(y2cl, coef2, C2, 5, 16384 * 32);

    // L3 GEMM: 128x128 tiles, B-direct, 4 classes -> 1024 blocks
    gemm_convt_bd<C2, 8, C3><<<dim3(128, 2, 4), 256, 0, stream>>>(y2cl, W3all, b3r, b3i, y3cl);

    // BN3 (C=128, rows=65536): 64 blocks, logG=4 (nsl=16), rowsPerSlice=64
    bn_stats_v<<<64, 256, 0, stream>>>(y3cl, part3, C3, 4, 64);
    bn_coef_v<<<1, 256, 0, stream>>>(part3, g3rr, g3ri, g3ii, n3br, n3bi, coef3, C3, 1.f / 65536.f);
    bn_apply_v<<<4096, 256, 0, stream>>>(y3cl, coef3, C3, 4, 65536 * 16);

    // L4: MFMA + tanh -> d_out (real part, fp32)
    conv4_mfma<<<dim3(512, 1, 4), 256, 0, stream>>>(y3cl, W4all, b4r, (float*)d_out);
}

// Round 14
// 556.778 us; speedup vs baseline: 22.2807x; 1.0377x over previous
//
#include <hip/hip_runtime.h>
#include <hip/hip_bf16.h>
#include <math.h>

#define BATCH 256
#define LAT 100
#define NCLS 10
#define CIN0 110
#define C1 512
#define C2 256
#define C3 128
#define NCH 3
#define EPS 1e-5f

typedef __hip_bfloat16 bf16;
typedef short bf16x8 __attribute__((ext_vector_type(8)));
typedef float f32x4 __attribute__((ext_vector_type(4)));

__device__ __forceinline__ float b2f(bf16 v) { return __bfloat162float(v); }
__device__ __forceinline__ bf16 f2b(float v) { return __float2bfloat16(v); }
__device__ __forceinline__ float s2f(short s) {
    unsigned u = ((unsigned)(unsigned short)s) << 16;
    return __builtin_bit_cast(float, u);
}
__device__ __forceinline__ short f2s(float f) {
    bf16 b = __float2bfloat16(f);
    return *(short*)&b;
}

// ---------------- combined prep: B1 | W2all | W3all | W4all | x0bf ----------------
#define NB_W1 14336
#define NB_W2 32768
#define NB_W3 8192
#define NB_W4 256
#define NB_X0 224

__device__ __forceinline__ void w1prep_body(const float* wr, const float* wi, bf16* B, int idx) {
    if (idx >= 16384 * 224) return;
    int n = idx / 224, k = idx - n * 224;
    int p = n >> 10, cop = n & 1023;
    int pk = k >= 112; int ci = k - pk * 112;
    float v = 0.f;
    if (ci < CIN0) {
        int co = (cop < C1) ? cop : cop - C1;
        size_t widx = ((size_t)ci * C1 + co) * 16 + p;
        float vr = wr[widx], vi = wi[widx];
        v = (cop < C1) ? (pk ? -vi : vr) : (pk ? vr : vi);
    }
    B[idx] = f2b(v);
}

template<int CIN, int N>
__device__ __forceinline__ void wprep_panel_body(const float* wr, const float* wi, bf16* W,
                                                 size_t idx) {
    constexpr int K = 4 * CIN, TWOK = 8 * CIN;
    size_t per_cls = (size_t)2 * N * TWOK;
    if (idx >= 4 * per_cls) return;
    int cls = (int)(idx / per_cls);
    size_t r = idx - (size_t)cls * per_cls;
    size_t chunk_nb = (size_t)TWOK * 128;
    int nb = (int)(r / chunk_nb);
    int r2 = (int)(r - (size_t)nb * chunk_nb);
    int kb = r2 >> 12;
    int w = r2 & 4095;
    int f = w >> 9;
    int l = (w >> 3) & 63;
    int j = w & 7;
    int n = nb * 128 + (f >> 2) * 64 + (f & 3) * 16 + (l & 15);
    int k = kb * 32 + (l >> 4) * 8 + j;
    // weight value for (cls, n, k)
    int py = cls >> 1, px = cls & 1;
    int p = k >= K; int kk = k - p * K;
    int t = kk / CIN, ci = kk - t * CIN;   // CIN constexpr pow2 -> shifts
    int a = t >> 1, e = t & 1;
    int kh = py ? (a ? 2 : 0) : (a ? 3 : 1);
    int kw = px ? (e ? 2 : 0) : (e ? 3 : 1);
    int co = (n < N) ? n : n - N;
    size_t widx = ((size_t)ci * N + co) * 16 + kh * 4 + kw;
    float vr = wr[widx], vi = wi[widx];
    float v = (n < N) ? (p ? -vi : vr) : (p ? vr : vi);
    W[idx] = f2b(v);
}

__device__ __forceinline__ void wprep4_body(const float* wr, const float* wi, bf16* W, int idx) {
    if (idx >= 65536) return;
    int cls = idx >> 14, rem = idx & 16383;
    int py = cls >> 1, px = cls & 1;
    int n = rem >> 10, k = rem & 1023;
    float v = 0.f;
    if (n < NCH) {
        int p = k >= 512; int kk = k - p * 512;
        int t = kk >> 7, ci = kk & 127;
        int a = t >> 1, e = t & 1;
        int kh = py ? (a ? 2 : 0) : (a ? 3 : 1);
        int kw = px ? (e ? 2 : 0) : (e ? 3 : 1);
        size_t widx = ((size_t)ci * NCH + n) * 16 + kh * 4 + kw;
        v = p ? -wi[widx] : wr[widx];
    }
    W[idx] = f2b(v);
}

__device__ __forceinline__ void x0_body(const float* nre, const float* nim,
                                        const int* labels, const float* emb,
                                        bf16* A, int idx) {
    if (idx >= BATCH * 224) return;
    int b = idx / 224, k = idx - b * 224;
    int p = k >= 112; int ci = k - p * 112;
    float v = 0.f;
    if (ci < CIN0) {
        if (!p) v = (ci < LAT) ? nre[b * LAT + ci] : emb[labels[b] * NCLS + (ci - LAT)];
        else    v = (ci < LAT) ? nim[b * LAT + ci] : 0.f;
    }
    A[idx] = f2b(v);
}

__global__ void prep_combined(const float* __restrict__ w1r, const float* __restrict__ w1i,
                              const float* __restrict__ w2r, const float* __restrict__ w2i,
                              const float* __restrict__ w3r, const float* __restrict__ w3i,
                              const float* __restrict__ w4r, const float* __restrict__ w4i,
                              const float* __restrict__ nre, const float* __restrict__ nim,
                              const int* __restrict__ labels, const float* __restrict__ emb,
                              bf16* __restrict__ B1, bf16* __restrict__ W2all,
                              bf16* __restrict__ W3all, bf16* __restrict__ W4all,
                              bf16* __restrict__ x0bf) {
    int bid = blockIdx.x;
    if (bid < NB_W1) {
        w1prep_body(w1r, w1i, B1, bid * 256 + threadIdx.x);
    } else if (bid < NB_W1 + NB_W2) {
        wprep_panel_body<C1, C2>(w2r, w2i, W2all, (size_t)(bid - NB_W1) * 256 + threadIdx.x);
    } else if (bid < NB_W1 + NB_W2 + NB_W3) {
        wprep_panel_body<C2, C3>(w3r, w3i, W3all, (size_t)(bid - NB_W1 - NB_W2) * 256 + threadIdx.x);
    } else if (bid < NB_W1 + NB_W2 + NB_W3 + NB_W4) {
        wprep4_body(w4r, w4i, W4all, (bid - NB_W1 - NB_W2 - NB_W3) * 256 + threadIdx.x);
    } else {
        x0_body(nre, nim, labels, emb, x0bf,
                (bid - NB_W1 - NB_W2 - NB_W3 - NB_W4) * 256 + threadIdx.x);
    }
}

// ---------------- gemm1: C[256][16384] = A[256][224] x B1^T -> x1cl ----------------
__global__ __launch_bounds__(256, 1) void gemm1(
    const bf16* __restrict__ A, const bf16* __restrict__ B,
    const float* __restrict__ b1r, const float* __restrict__ b1i,
    bf16* __restrict__ Y) {
    __shared__ short As[128][40];
    __shared__ short Bs[128][40];
    const int tid = threadIdx.x;
    const int mBase = blockIdx.x * 128, nBase = blockIdx.y * 128;
    const int wid = tid >> 6, lane = tid & 63;
    const int wm = (wid >> 1) * 64, wn = (wid & 1) * 64;
    const int lm = lane & 15, lq = lane >> 4;

    f32x4 acc[4][4] = {};

    for (int k0 = 0; k0 < 224; k0 += 32) {
#pragma unroll
        for (int it = 0; it < 2; ++it) {
            int slot = tid + it * 256;
            int row = slot >> 2, kc = (slot & 3) * 8;
            int k = k0 + kc;
            *(uint4*)(&As[row][kc]) = *(const uint4*)(A + (size_t)(mBase + row) * 224 + k);
            *(uint4*)(&Bs[row][kc]) = *(const uint4*)(B + (size_t)(nBase + row) * 224 + k);
        }
        __syncthreads();
        bf16x8 af[4], bfr[4];
#pragma unroll
        for (int s = 0; s < 4; ++s) {
            af[s]  = *(const bf16x8*)(&As[wm + s * 16 + lm][lq * 8]);
            bfr[s] = *(const bf16x8*)(&Bs[wn + s * 16 + lm][lq * 8]);
        }
#pragma unroll
        for (int sm = 0; sm < 4; ++sm)
#pragma unroll
            for (int sn = 0; sn < 4; ++sn)
                acc[sm][sn] = __builtin_amdgcn_mfma_f32_16x16x32_bf16(af[sm], bfr[sn], acc[sm][sn], 0, 0, 0);
        __syncthreads();
    }

#pragma unroll
    for (int sm = 0; sm < 4; ++sm) {
#pragma unroll
        for (int v = 0; v < 4; ++v) {
            int m = mBase + wm + sm * 16 + lq * 4 + v;
#pragma unroll
            for (int sn = 0; sn < 4; ++sn) {
                int n = nBase + wn + sn * 16 + lm;
                int cop = n & 1023;
                float bias = (cop < C1) ? b1r[cop] : b1i[cop - C1];
                Y[(size_t)m * 16384 + n] = f2b(acc[sm][sn][v] + bias);
            }
        }
    }
}

// ---------------- BN stats: vectorized x8, 64 blocks of per-block partials ----------------
__global__ void bn_stats_v(const bf16* __restrict__ Y, float* __restrict__ P,
                           int C, int logG, int rowsPerSlice) {
    const int tid = threadIdx.x;
    const int G = 1 << logG;
    const int g = tid & (G - 1);
    const int slice = tid >> logG;
    const int nsl = 256 >> logG;
    const int r0 = blockIdx.x * rowsPerSlice * nsl + slice * rowsPerSlice;
    const int CC = 2 * C;

    float sr[8] = {}, si[8] = {}, srr[8] = {}, sii[8] = {}, sri[8] = {};
    for (int r = r0; r < r0 + rowsPerSlice; ++r) {
        const bf16* p = Y + (size_t)r * CC + g * 8;
        bf16x8 vr8 = *(const bf16x8*)p;
        bf16x8 vi8 = *(const bf16x8*)(p + C);
#pragma unroll
        for (int j = 0; j < 8; ++j) {
            float vr = s2f(vr8[j]), vi = s2f(vi8[j]);
            sr[j] += vr; si[j] += vi;
            srr[j] += vr * vr; sii[j] += vi * vi; sri[j] += vr * vi;
        }
    }
    __shared__ float red[5][512];
    for (int i = tid; i < 5 * 512; i += 256) ((float*)red)[i] = 0.f;
    __syncthreads();
#pragma unroll
    for (int j = 0; j < 8; ++j) {
        int c = g * 8 + j;
        atomicAdd(&red[0][c], sr[j]);
        atomicAdd(&red[1][c], si[j]);
        atomicAdd(&red[2][c], srr[j]);
        atomicAdd(&red[3][c], sii[j]);
        atomicAdd(&red[4][c], sri[j]);
    }
    __syncthreads();
    for (int c = tid; c < C; c += 256) {
        float* dst = P + ((size_t)blockIdx.x * C + c) * 5;
        dst[0] = red[0][c]; dst[1] = red[1][c]; dst[2] = red[2][c];
        dst[3] = red[3][c]; dst[4] = red[4][c];
    }
}

// ---------------- coef: reduce 64 partials + whitening + affine fold ----------------
__global__ void bn_coef_v(const float* __restrict__ P,
                          const float* __restrict__ grr, const float* __restrict__ gri,
                          const float* __restrict__ gii,
                          const float* __restrict__ betar, const float* __restrict__ betai,
                          float* __restrict__ coef, int C, float invN) {
    int c = blockIdx.x * blockDim.x + threadIdx.x;
    if (c >= C) return;
    float sr = 0, si = 0, srr = 0, sii = 0, sri = 0;
    for (int b = 0; b < 64; ++b) {
        const float* p = P + ((size_t)b * C + c) * 5;
        sr += p[0]; si += p[1]; srr += p[2]; sii += p[3]; sri += p[4];
    }
    float mr = sr * invN, mi = si * invN;
    float crr = srr * invN - mr * mr + EPS;
    float cii = sii * invN - mi * mi + EPS;
    float cri = sri * invN - mr * mi;
    float s = sqrtf(crr * cii - cri * cri);
    float t = sqrtf(crr + cii + 2.f * s);
    float inv = 1.f / (s * t);
    float rrr = (cii + s) * inv, rii = (crr + s) * inv, rri = -cri * inv;
    float Grr = grr[c], Gri = gri[c], Gii = gii[c];
    float arr = Grr * rrr + Gri * rri, ari = Grr * rri + Gri * rii;
    float air = Gri * rrr + Gii * rri, aii = Gri * rri + Gii * rii;
    coef[0 * C + c] = arr;
    coef[1 * C + c] = ari;
    coef[2 * C + c] = betar[c] - arr * mr - ari * mi;
    coef[3 * C + c] = air;
    coef[4 * C + c] = aii;
    coef[5 * C + c] = betai[c] - air * mr - aii * mi;
}

// ---------------- BN apply+ReLU: vectorized x8 ----------------
__global__ void bn_apply_v(bf16* __restrict__ Y, const float* __restrict__ coef,
                           int C, int logG, int total) {
    int idx = blockIdx.x * 256 + threadIdx.x;
    if (idx >= total) return;
    int G = 1 << logG;
    int g = idx & (G - 1);
    size_t base = (size_t)(idx >> logG) * 2 * C + g * 8;
    bf16x8 vr8 = *(const bf16x8*)(Y + base);
    bf16x8 vi8 = *(const bf16x8*)(Y + base + C);
    bf16x8 or8, oi8;
#pragma unroll
    for (int j = 0; j < 8; ++j) {
        int c = g * 8 + j;
        float vr = s2f(vr8[j]), vi = s2f(vi8[j]);
        float orr = fmaxf(coef[0 * C + c] * vr + coef[1 * C + c] * vi + coef[2 * C + c], 0.f);
        float oii = fmaxf(coef[3 * C + c] * vr + coef[4 * C + c] * vi + coef[5 * C + c], 0.f);
        or8[j] = f2s(orr); oi8[j] = f2s(oii);
    }
    *(bf16x8*)(Y + base) = or8;
    *(bf16x8*)(Y + base + C) = oi8;
}

// ---------------- MFMA GEMM 128x128, B direct, software-pipelined A (1 barrier/step) ----------------
template<int CIN, int S, int N>
__global__ __launch_bounds__(256, 2) void gemm_convt_bd(
    const bf16* __restrict__ X, const bf16* __restrict__ Wall,
    const float* __restrict__ biasr, const float* __restrict__ biasi,
    bf16* __restrict__ Y) {
    constexpr int K = 4 * CIN, TWOK = 8 * CIN, C2I = 2 * CIN, C2O = 2 * N, HOUT = 2 * S;
    constexpr int NSTEP = TWOK / 32;
    __shared__ short As[2][128][40];
    const int cls = blockIdx.z;
    const int py = cls >> 1, px = cls & 1;
    const int tid = threadIdx.x;
    const int mBase = blockIdx.x * 128, nBase = blockIdx.y * 128;
    const int wid = tid >> 6, lane = tid & 63;
    const int wm = (wid >> 1) * 64, wn = (wid & 1) * 64;
    const int lm = lane & 15, lq = lane >> 4;
    const int dh0 = py ? 1 : 0, dh1 = py ? 0 : -1;
    const int dw0 = px ? 1 : 0, dw1 = px ? 0 : -1;

    const bf16* Wp = Wall
        + ((size_t)(cls * (C2O / 128) + blockIdx.y) * (TWOK / 32)) * 4096
        + ((wn >> 6) * 4) * 512 + lane * 8;

    // per-thread A-slot constants
    int rowA[2], kcA[2], bA[2], iA[2], jA[2];
#pragma unroll
    for (int it = 0; it < 2; ++it) {
        int slot = tid + it * 256;
        rowA[it] = slot >> 2; kcA[it] = (slot & 3) * 8;
        int m = mBase + rowA[it];
        int b = m / (S * S); int rem = m - b * (S * S);
        bA[it] = b; iA[it] = rem / S; jA[it] = rem % S;
    }

    auto loadA = [&](int ks, uint4* av) {
#pragma unroll
        for (int it = 0; it < 2; ++it) {
            int k = ks * 32 + kcA[it];
            int p = k >= K; int kk = k - p * K;
            int t = kk / CIN, ci = kk - t * CIN;
            int a = t >> 1, e = t & 1;
            int ih = iA[it] + (a ? dh1 : dh0);
            int iw = jA[it] + (e ? dw1 : dw0);
            uint4 v = {0u, 0u, 0u, 0u};
            if ((unsigned)ih < (unsigned)S && (unsigned)iw < (unsigned)S)
                v = *(const uint4*)(X + ((size_t)((bA[it] * S + ih) * S + iw) * C2I + p * CIN + ci));
            av[it] = v;
        }
    };

    f32x4 acc[4][4] = {};
    bf16x8 bq[4];
#pragma unroll
    for (int sn = 0; sn < 4; ++sn) bq[sn] = *(const bf16x8*)(Wp + sn * 512);

    {   // prologue: stage step 0
        uint4 av[2];
        loadA(0, av);
#pragma unroll
        for (int it = 0; it < 2; ++it) *(uint4*)(&As[0][rowA[it]][kcA[it]]) = av[it];
    }
    __syncthreads();

    for (int ks = 0; ks < NSTEP; ++ks) {
        const int cur = ks & 1;
        uint4 av[2];
        if (ks + 1 < NSTEP) loadA(ks + 1, av);      // global loads in flight
        bf16x8 bcur[4];
#pragma unroll
        for (int sn = 0; sn < 4; ++sn) bcur[sn] = bq[sn];
        if (ks + 1 < NSTEP) {
            const bf16* Wn = Wp + (size_t)(ks + 1) * 4096;
#pragma unroll
            for (int sn = 0; sn < 4; ++sn) bq[sn] = *(const bf16x8*)(Wn + sn * 512);
        }
        bf16x8 af[4];
#pragma unroll
        for (int s = 0; s < 4; ++s)
            af[s] = *(const bf16x8*)(&As[cur][wm + s * 16 + lm][lq * 8]);
#pragma unroll
        for (int sm = 0; sm < 4; ++sm)
#pragma unroll
            for (int sn = 0; sn < 4; ++sn)
                acc[sm][sn] = __builtin_amdgcn_mfma_f32_16x16x32_bf16(af[sm], bcur[sn], acc[sm][sn], 0, 0, 0);
        if (ks + 1 < NSTEP) {
#pragma unroll
            for (int it = 0; it < 2; ++it) *(uint4*)(&As[1 - cur][rowA[it]][kcA[it]]) = av[it];
        }
        __syncthreads();
    }

#pragma unroll
    for (int sm = 0; sm < 4; ++sm) {
#pragma unroll
        for (int v = 0; v < 4; ++v) {
            int m = mBase + wm + sm * 16 + lq * 4 + v;
            int b = m / (S * S); int rem = m - b * (S * S);
            int i = rem / S, j = rem % S;
            int oh = 2 * i + py, ow = 2 * j + px;
            size_t rowoff = (size_t)((b * HOUT + oh) * HOUT + ow) * C2O;
#pragma unroll
            for (int sn = 0; sn < 4; ++sn) {
                int n = nBase + wn + sn * 16 + lm;
                float bias = (n < N) ? biasr[n] : biasi[n - N];
                Y[rowoff + n] = f2b(acc[sm][sn][v] + bias);
            }
        }
    }
}

// ---------------- layer4 via MFMA ----------------
__global__ __launch_bounds__(256, 2) void conv4_mfma(
    const bf16* __restrict__ X, const bf16* __restrict__ Wall,
    const float* __restrict__ br, float* __restrict__ out) {
    constexpr int CIN = 128, S = 16, K = 512, TWOK = 1024, C2I = 256;
    __shared__ short As[128][40];
    __shared__ short Bs[16][40];
    const int cls = blockIdx.z;
    const int py = cls >> 1, px = cls & 1;
    const bf16* W = Wall + (size_t)cls * 16 * TWOK;
    const int tid = threadIdx.x;
    const int mBase = blockIdx.x * 128;
    const int wid = tid >> 6, lane = tid & 63;
    const int wm = wid * 32;
    const int lm = lane & 15, lq = lane >> 4;
    const int dh0 = py ? 1 : 0, dh1 = py ? 0 : -1;
    const int dw0 = px ? 1 : 0, dw1 = px ? 0 : -1;

    f32x4 acc[2] = {};

    for (int k0 = 0; k0 < TWOK; k0 += 32) {
#pragma unroll
        for (int it = 0; it < 2; ++it) {
            int slot = tid + it * 256;
            int row = slot >> 2, kc = (slot & 3) * 8;
            int k = k0 + kc;
            int p = k >= K; int kk = k - p * K;
            int t = kk >> 7, ci = kk & 127;
            int a = t >> 1, e = t & 1;
            int m = mBase + row;
            int b = m >> 8; int rem = m & 255;
            int i = rem >> 4, j = rem & 15;
            int ih = i + (a ? dh1 : dh0);
            int iw = j + (e ? dw1 : dw0);
            uint4 v = {0u, 0u, 0u, 0u};
            if ((unsigned)ih < (unsigned)S && (unsigned)iw < (unsigned)S)
                v = *(const uint4*)(X + ((size_t)((b * S + ih) * S + iw) * C2I + p * CIN + ci));
            *(uint4*)(&As[row][kc]) = v;
        }
        if (tid < 64) {
            int row = tid >> 2, kc = (tid & 3) * 8;
            uint4 w = *(const uint4*)(W + (size_t)row * TWOK + k0 + kc);
            *(uint4*)(&Bs[row][kc]) = w;
        }
        __syncthreads();
        bf16x8 bfr = *(const bf16x8*)(&Bs[lm][lq * 8]);
        bf16x8 af0 = *(const bf16x8*)(&As[wm + lm][lq * 8]);
        bf16x8 af1 = *(const bf16x8*)(&As[wm + 16 + lm][lq * 8]);
        acc[0] = __builtin_amdgcn_mfma_f32_16x16x32_bf16(af0, bfr, acc[0], 0, 0, 0);
        acc[1] = __builtin_amdgcn_mfma_f32_16x16x32_bf16(af1, bfr, acc[1], 0, 0, 0);
        __syncthreads();
    }

    int n = lm;
    if (n < NCH) {
        float bias = br[n];
#pragma unroll
        for (int s = 0; s < 2; ++s) {
#pragma unroll
            for (int v = 0; v < 4; ++v) {
                int m = mBase + wm + s * 16 + lq * 4 + v;
                int b = m >> 8; int rem = m & 255;
                int i = rem >> 4, j = rem & 15;
                int oh = 2 * i + py, ow = 2 * j + px;
                out[((size_t)(b * NCH + n) * 32 + oh) * 32 + ow] = tanhf(acc[s][v] + bias);
            }
        }
    }
}

extern "C" void kernel_launch(void* const* d_in, const int* in_sizes, int n_in,
                              void* d_out, int out_size, void* d_ws, size_t ws_size,
                              hipStream_t stream) {
    const float* noise_re = (const float*)d_in[0];
    const float* noise_im = (const float*)d_in[1];
    const int*   labels   = (const int*)d_in[2];
    const float* emb      = (const float*)d_in[3];
    const float* w1r = (const float*)d_in[4],  *w1i = (const float*)d_in[5];
    const float* b1r = (const float*)d_in[6],  *b1i = (const float*)d_in[7];
    const float* g1rr = (const float*)d_in[8], *g1ri = (const float*)d_in[9], *g1ii = (const float*)d_in[10];
    const float* n1br = (const float*)d_in[11], *n1bi = (const float*)d_in[12];
    const float* w2r = (const float*)d_in[13], *w2i = (const float*)d_in[14];
    const float* b2r = (const float*)d_in[15], *b2i = (const float*)d_in[16];
    const float* g2rr = (const float*)d_in[17], *g2ri = (const float*)d_in[18], *g2ii = (const float*)d_in[19];
    const float* n2br = (const float*)d_in[20], *n2bi = (const float*)d_in[21];
    const float* w3r = (const float*)d_in[22], *w3i = (const float*)d_in[23];
    const float* b3r = (const float*)d_in[24], *b3i = (const float*)d_in[25];
    const float* g3rr = (const float*)d_in[26], *g3ri = (const float*)d_in[27], *g3ii = (const float*)d_in[28];
    const float* n3br = (const float*)d_in[29], *n3bi = (const float*)d_in[30];
    const float* w4r = (const float*)d_in[31], *w4i = (const float*)d_in[32];
    const float* b4r = (const float*)d_in[33], *b4i = (const float*)d_in[34];

    // ---- workspace layout (bytes) ---- (same as R13)
    char* ws = (char*)d_ws;
    bf16* y3cl = (bf16*)ws;
    bf16* x1cl = (bf16*)ws;
    bf16* B1    = (bf16*)(ws + 8388608);
    bf16* W2all = (bf16*)(ws + 15728640);
    float* part12 = (float*)(ws + 32505856);
    bf16* y2cl  = (bf16*)(ws + 33554432);
    bf16* W3all = (bf16*)(ws + 50331648);
    float* part3 = (float*)(ws + 50331648);   // overlays W3all AFTER gemmL3
    float* coef1 = (float*)(ws + 54525952);
    float* coef2 = (float*)(ws + 54538240);
    float* coef3 = (float*)(ws + 54544384);
    bf16* x0bf  = (bf16*)(ws + 54547456);
    bf16* W4all = (bf16*)(ws + 54662144);

    prep_combined<<<NB_W1 + NB_W2 + NB_W3 + NB_W4 + NB_X0, 256, 0, stream>>>(
        w1r, w1i, w2r, w2i, w3r, w3i, w4r, w4i,
        noise_re, noise_im, labels, emb,
        B1, W2all, W3all, W4all, x0bf);

    // L1 GEMM -> x1cl
    gemm1<<<dim3(2, 128), 256, 0, stream>>>(x0bf, B1, b1r, b1i, x1cl);

    // BN1 (C=512, rows=4096)
    bn_stats_v<<<64, 256, 0, stream>>>(x1cl, part12, C1, 6, 16);
    bn_coef_v<<<2, 256, 0, stream>>>(part12, g1rr, g1ri, g1ii, n1br, n1bi, coef1, C1, 1.f / 4096.f);
    bn_apply_v<<<1024, 256, 0, stream>>>(x1cl, coef1, C1, 6, 4096 * 64);

    // L2 GEMM: pipelined, B-direct -> 512 blocks
    gemm_convt_bd<C1, 4, C2><<<dim3(32, 4, 4), 256, 0, stream>>>(x1cl, W2all, b2r, b2i, y2cl);

    // BN2 (C=256, rows=16384)
    bn_stats_v<<<64, 256, 0, stream>>>(y2cl, part12, C2, 5, 32);
    bn_coef_v<<<1, 256, 0, stream>>>(part12, g2rr, g2ri, g2ii, n2br, n2bi, coef2, C2, 1.f / 16384.f);
    bn_apply_v<<<2048, 256, 0, stream>>>(y2cl, coef2, C2, 5, 16384 * 32);

    // L3 GEMM: pipelined, B-direct -> 1024 blocks
    gemm_convt_bd<C2, 8, C3><<<dim3(128, 2, 4), 256, 0, stream>>>(y2cl, W3all, b3r, b3i, y3cl);

    // BN3 (C=128, rows=65536)
    bn_stats_v<<<64, 256, 0, stream>>>(y3cl, part3, C3, 4, 64);
    bn_coef_v<<<1, 256, 0, stream>>>(part3, g3rr, g3ri, g3ii, n3br, n3bi, coef3, C3, 1.f / 65536.f);
    bn_apply_v<<<4096, 256, 0, stream>>>(y3cl, coef3, C3, 4, 65536 * 16);

    // L4: MFMA + tanh -> d_out (real part, fp32)
    conv4_mfma<<<dim3(512, 1, 4), 256, 0, stream>>>(y3cl, W4all, b4r, (float*)d_out);
}

// Round 15
// 543.959 us; speedup vs baseline: 22.8058x; 1.0236x over previous
//
#include <hip/hip_runtime.h>
#include <hip/hip_bf16.h>
#include <math.h>

#define BATCH 256
#define LAT 100
#define NCLS 10
#define CIN0 110
#define C1 512
#define C2 256
#define C3 128
#define NCH 3
#define EPS 1e-5f

typedef __hip_bfloat16 bf16;
typedef short bf16x8 __attribute__((ext_vector_type(8)));
typedef float f32x4 __attribute__((ext_vector_type(4)));

__device__ __forceinline__ float b2f(bf16 v) { return __bfloat162float(v); }
__device__ __forceinline__ bf16 f2b(float v) { return __float2bfloat16(v); }
__device__ __forceinline__ float s2f(short s) {
    unsigned u = ((unsigned)(unsigned short)s) << 16;
    return __builtin_bit_cast(float, u);
}
__device__ __forceinline__ short f2s(float f) {
    bf16 b = __float2bfloat16(f);
    return *(short*)&b;
}

// ---------------- combined prep: B1 | W2all | W3all | W4all | x0bf ----------------
#define NB_W1 14336
#define NB_W2 32768
#define NB_W3 8192
#define NB_W4 256
#define NB_X0 224

__device__ __forceinline__ void w1prep_body(const float* wr, const float* wi, bf16* B, int idx) {
    if (idx >= 16384 * 224) return;
    int n = idx / 224, k = idx - n * 224;
    int p = n >> 10, cop = n & 1023;
    int pk = k >= 112; int ci = k - pk * 112;
    float v = 0.f;
    if (ci < CIN0) {
        int co = (cop < C1) ? cop : cop - C1;
        size_t widx = ((size_t)ci * C1 + co) * 16 + p;
        float vr = wr[widx], vi = wi[widx];
        v = (cop < C1) ? (pk ? -vi : vr) : (pk ? vr : vi);
    }
    B[idx] = f2b(v);
}

template<int CIN, int N>
__device__ __forceinline__ void wprep_panel_body(const float* wr, const float* wi, bf16* W,
                                                 size_t idx) {
    constexpr int K = 4 * CIN, TWOK = 8 * CIN;
    size_t per_cls = (size_t)2 * N * TWOK;
    if (idx >= 4 * per_cls) return;
    int cls = (int)(idx / per_cls);
    size_t r = idx - (size_t)cls * per_cls;
    size_t chunk_nb = (size_t)TWOK * 128;
    int nb = (int)(r / chunk_nb);
    int r2 = (int)(r - (size_t)nb * chunk_nb);
    int kb = r2 >> 12;
    int w = r2 & 4095;
    int f = w >> 9;
    int l = (w >> 3) & 63;
    int j = w & 7;
    int n = nb * 128 + (f >> 2) * 64 + (f & 3) * 16 + (l & 15);
    int k = kb * 32 + (l >> 4) * 8 + j;
    int py = cls >> 1, px = cls & 1;
    int p = k >= K; int kk = k - p * K;
    int t = kk / CIN, ci = kk - t * CIN;
    int a = t >> 1, e = t & 1;
    int kh = py ? (a ? 2 : 0) : (a ? 3 : 1);
    int kw = px ? (e ? 2 : 0) : (e ? 3 : 1);
    int co = (n < N) ? n : n - N;
    size_t widx = ((size_t)ci * N + co) * 16 + kh * 4 + kw;
    float vr = wr[widx], vi = wi[widx];
    float v = (n < N) ? (p ? -vi : vr) : (p ? vr : vi);
    W[idx] = f2b(v);
}

__device__ __forceinline__ void wprep4_body(const float* wr, const float* wi, bf16* W, int idx) {
    if (idx >= 65536) return;
    int cls = idx >> 14, rem = idx & 16383;
    int py = cls >> 1, px = cls & 1;
    int n = rem >> 10, k = rem & 1023;
    float v = 0.f;
    if (n < NCH) {
        int p = k >= 512; int kk = k - p * 512;
        int t = kk >> 7, ci = kk & 127;
        int a = t >> 1, e = t & 1;
        int kh = py ? (a ? 2 : 0) : (a ? 3 : 1);
        int kw = px ? (e ? 2 : 0) : (e ? 3 : 1);
        size_t widx = ((size_t)ci * NCH + n) * 16 + kh * 4 + kw;
        v = p ? -wi[widx] : wr[widx];
    }
    W[idx] = f2b(v);
}

__device__ __forceinline__ void x0_body(const float* nre, const float* nim,
                                        const int* labels, const float* emb,
                                        bf16* A, int idx) {
    if (idx >= BATCH * 224) return;
    int b = idx / 224, k = idx - b * 224;
    int p = k >= 112; int ci = k - p * 112;
    float v = 0.f;
    if (ci < CIN0) {
        if (!p) v = (ci < LAT) ? nre[b * LAT + ci] : emb[labels[b] * NCLS + (ci - LAT)];
        else    v = (ci < LAT) ? nim[b * LAT + ci] : 0.f;
    }
    A[idx] = f2b(v);
}

__global__ void prep_combined(const float* __restrict__ w1r, const float* __restrict__ w1i,
                              const float* __restrict__ w2r, const float* __restrict__ w2i,
                              const float* __restrict__ w3r, const float* __restrict__ w3i,
                              const float* __restrict__ w4r, const float* __restrict__ w4i,
                              const float* __restrict__ nre, const float* __restrict__ nim,
                              const int* __restrict__ labels, const float* __restrict__ emb,
                              bf16* __restrict__ B1, bf16* __restrict__ W2all,
                              bf16* __restrict__ W3all, bf16* __restrict__ W4all,
                              bf16* __restrict__ x0bf) {
    int bid = blockIdx.x;
    if (bid < NB_W1) {
        w1prep_body(w1r, w1i, B1, bid * 256 + threadIdx.x);
    } else if (bid < NB_W1 + NB_W2) {
        wprep_panel_body<C1, C2>(w2r, w2i, W2all, (size_t)(bid - NB_W1) * 256 + threadIdx.x);
    } else if (bid < NB_W1 + NB_W2 + NB_W3) {
        wprep_panel_body<C2, C3>(w3r, w3i, W3all, (size_t)(bid - NB_W1 - NB_W2) * 256 + threadIdx.x);
    } else if (bid < NB_W1 + NB_W2 + NB_W3 + NB_W4) {
        wprep4_body(w4r, w4i, W4all, (bid - NB_W1 - NB_W2 - NB_W3) * 256 + threadIdx.x);
    } else {
        x0_body(nre, nim, labels, emb, x0bf,
                (bid - NB_W1 - NB_W2 - NB_W3 - NB_W4) * 256 + threadIdx.x);
    }
}

// ---------------- gemm1: C[256][16384] = A[256][224] x B1^T -> x1cl ----------------
__global__ __launch_bounds__(256, 1) void gemm1(
    const bf16* __restrict__ A, const bf16* __restrict__ B,
    const float* __restrict__ b1r, const float* __restrict__ b1i,
    bf16* __restrict__ Y) {
    __shared__ short As[128][40];
    __shared__ short Bs[128][40];
    const int tid = threadIdx.x;
    const int mBase = blockIdx.x * 128, nBase = blockIdx.y * 128;
    const int wid = tid >> 6, lane = tid & 63;
    const int wm = (wid >> 1) * 64, wn = (wid & 1) * 64;
    const int lm = lane & 15, lq = lane >> 4;

    f32x4 acc[4][4] = {};

    for (int k0 = 0; k0 < 224; k0 += 32) {
#pragma unroll
        for (int it = 0; it < 2; ++it) {
            int slot = tid + it * 256;
            int row = slot >> 2, kc = (slot & 3) * 8;
            int k = k0 + kc;
            *(uint4*)(&As[row][kc]) = *(const uint4*)(A + (size_t)(mBase + row) * 224 + k);
            *(uint4*)(&Bs[row][kc]) = *(const uint4*)(B + (size_t)(nBase + row) * 224 + k);
        }
        __syncthreads();
        bf16x8 af[4], bfr[4];
#pragma unroll
        for (int s = 0; s < 4; ++s) {
            af[s]  = *(const bf16x8*)(&As[wm + s * 16 + lm][lq * 8]);
            bfr[s] = *(const bf16x8*)(&Bs[wn + s * 16 + lm][lq * 8]);
        }
#pragma unroll
        for (int sm = 0; sm < 4; ++sm)
#pragma unroll
            for (int sn = 0; sn < 4; ++sn)
                acc[sm][sn] = __builtin_amdgcn_mfma_f32_16x16x32_bf16(af[sm], bfr[sn], acc[sm][sn], 0, 0, 0);
        __syncthreads();
    }

#pragma unroll
    for (int sm = 0; sm < 4; ++sm) {
#pragma unroll
        for (int v = 0; v < 4; ++v) {
            int m = mBase + wm + sm * 16 + lq * 4 + v;
#pragma unroll
            for (int sn = 0; sn < 4; ++sn) {
                int n = nBase + wn + sn * 16 + lm;
                int cop = n & 1023;
                float bias = (cop < C1) ? b1r[cop] : b1i[cop - C1];
                Y[(size_t)m * 16384 + n] = f2b(acc[sm][sn][v] + bias);
            }
        }
    }
}

// ---------------- BN stats: vectorized x8, 128 blocks of per-block partials ----------------
__global__ void bn_stats_v(const bf16* __restrict__ Y, float* __restrict__ P,
                           int C, int logG, int rowsPerSlice) {
    const int tid = threadIdx.x;
    const int G = 1 << logG;
    const int g = tid & (G - 1);
    const int slice = tid >> logG;
    const int nsl = 256 >> logG;
    const int r0 = blockIdx.x * rowsPerSlice * nsl + slice * rowsPerSlice;
    const int CC = 2 * C;

    float sr[8] = {}, si[8] = {}, srr[8] = {}, sii[8] = {}, sri[8] = {};
    for (int r = r0; r < r0 + rowsPerSlice; ++r) {
        const bf16* p = Y + (size_t)r * CC + g * 8;
        bf16x8 vr8 = *(const bf16x8*)p;
        bf16x8 vi8 = *(const bf16x8*)(p + C);
#pragma unroll
        for (int j = 0; j < 8; ++j) {
            float vr = s2f(vr8[j]), vi = s2f(vi8[j]);
            sr[j] += vr; si[j] += vi;
            srr[j] += vr * vr; sii[j] += vi * vi; sri[j] += vr * vi;
        }
    }
    __shared__ float red[5][512];
    for (int i = tid; i < 5 * 512; i += 256) ((float*)red)[i] = 0.f;
    __syncthreads();
#pragma unroll
    for (int j = 0; j < 8; ++j) {
        int c = g * 8 + j;
        atomicAdd(&red[0][c], sr[j]);
        atomicAdd(&red[1][c], si[j]);
        atomicAdd(&red[2][c], srr[j]);
        atomicAdd(&red[3][c], sii[j]);
        atomicAdd(&red[4][c], sri[j]);
    }
    __syncthreads();
    for (int c = tid; c < C; c += 256) {
        float* dst = P + ((size_t)blockIdx.x * C + c) * 5;
        dst[0] = red[0][c]; dst[1] = red[1][c]; dst[2] = red[2][c];
        dst[3] = red[3][c]; dst[4] = red[4][c];
    }
}

// ---------------- coef: reduce 128 partials + whitening + affine fold ----------------
__global__ void bn_coef_v(const float* __restrict__ P,
                          const float* __restrict__ grr, const float* __restrict__ gri,
                          const float* __restrict__ gii,
                          const float* __restrict__ betar, const float* __restrict__ betai,
                          float* __restrict__ coef, int C, float invN) {
    int c = blockIdx.x * blockDim.x + threadIdx.x;
    if (c >= C) return;
    float sr = 0, si = 0, srr = 0, sii = 0, sri = 0;
    for (int b = 0; b < 128; ++b) {
        const float* p = P + ((size_t)b * C + c) * 5;
        sr += p[0]; si += p[1]; srr += p[2]; sii += p[3]; sri += p[4];
    }
    float mr = sr * invN, mi = si * invN;
    float crr = srr * invN - mr * mr + EPS;
    float cii = sii * invN - mi * mi + EPS;
    float cri = sri * invN - mr * mi;
    float s = sqrtf(crr * cii - cri * cri);
    float t = sqrtf(crr + cii + 2.f * s);
    float inv = 1.f / (s * t);
    float rrr = (cii + s) * inv, rii = (crr + s) * inv, rri = -cri * inv;
    float Grr = grr[c], Gri = gri[c], Gii = gii[c];
    float arr = Grr * rrr + Gri * rri, ari = Grr * rri + Gri * rii;
    float air = Gri * rrr + Gii * rri, aii = Gri * rri + Gii * rii;
    coef[0 * C + c] = arr;
    coef[1 * C + c] = ari;
    coef[2 * C + c] = betar[c] - arr * mr - ari * mi;
    coef[3 * C + c] = air;
    coef[4 * C + c] = aii;
    coef[5 * C + c] = betai[c] - air * mr - aii * mi;
}

// ---------------- BN apply+ReLU: vectorized x8 ----------------
__global__ void bn_apply_v(bf16* __restrict__ Y, const float* __restrict__ coef,
                           int C, int logG, int total) {
    int idx = blockIdx.x * 256 + threadIdx.x;
    if (idx >= total) return;
    int G = 1 << logG;
    int g = idx & (G - 1);
    size_t base = (size_t)(idx >> logG) * 2 * C + g * 8;
    bf16x8 vr8 = *(const bf16x8*)(Y + base);
    bf16x8 vi8 = *(const bf16x8*)(Y + base + C);
    bf16x8 or8, oi8;
#pragma unroll
    for (int j = 0; j < 8; ++j) {
        int c = g * 8 + j;
        float vr = s2f(vr8[j]), vi = s2f(vi8[j]);
        float orr = fmaxf(coef[0 * C + c] * vr + coef[1 * C + c] * vi + coef[2 * C + c], 0.f);
        float oii = fmaxf(coef[3 * C + c] * vr + coef[4 * C + c] * vi + coef[5 * C + c], 0.f);
        or8[j] = f2s(orr); oi8[j] = f2s(oii);
    }
    *(bf16x8*)(Y + base) = or8;
    *(bf16x8*)(Y + base + C) = oi8;
}

// ---------------- MFMA GEMM 128x128, B direct, pipelined, hoisted A-addresses ----------------
template<int CIN, int S, int N>
__global__ __launch_bounds__(256, 2) void gemm_convt_bd(
    const bf16* __restrict__ X, const bf16* __restrict__ Wall,
    const float* __restrict__ biasr, const float* __restrict__ biasi,
    bf16* __restrict__ Y) {
    constexpr int K = 4 * CIN, TWOK = 8 * CIN, C2I = 2 * CIN, C2O = 2 * N, HOUT = 2 * S;
    constexpr int NSTEP = TWOK / 32;
    constexpr int CPS = CIN / 32;                 // 32-wide k-chunks per (p,t) section
    constexpr int LOG_CPS = (CIN == 512) ? 4 : 3;
    __shared__ short As[2][128][40];
    const int cls = blockIdx.z;
    const int py = cls >> 1, px = cls & 1;
    const int tid = threadIdx.x;
    const int mBase = blockIdx.x * 128, nBase = blockIdx.y * 128;
    const int wid = tid >> 6, lane = tid & 63;
    const int wm = (wid >> 1) * 64, wn = (wid & 1) * 64;
    const int lm = lane & 15, lq = lane >> 4;
    const int dh0 = py ? 1 : 0, dh1 = py ? 0 : -1;
    const int dw0 = px ? 1 : 0, dw1 = px ? 0 : -1;

    const bf16* Wp = Wall
        + ((size_t)(cls * (C2O / 128) + blockIdx.y) * (TWOK / 32)) * 4096
        + ((wn >> 6) * 4) * 512 + lane * 8;

    // hoisted per-thread A constants: tap offsets (sentinel -1 = out of bounds)
    int rowA[2], kcA[2];
    long offT[2][4];
#pragma unroll
    for (int it = 0; it < 2; ++it) {
        int slot = tid + it * 256;
        rowA[it] = slot >> 2; kcA[it] = (slot & 3) * 8;
        int m = mBase + rowA[it];
        int b = m / (S * S); int rem = m - b * (S * S);
        int i = rem / S, j = rem % S;
#pragma unroll
        for (int t = 0; t < 4; ++t) {
            int a = t >> 1, e = t & 1;
            int ih = i + (a ? dh1 : dh0);
            int iw = j + (e ? dw1 : dw0);
            offT[it][t] = ((unsigned)ih < (unsigned)S && (unsigned)iw < (unsigned)S)
                ? (long)((b * S + ih) * S + iw) * C2I : -1L;
        }
    }

    auto loadA = [&](int kb, uint4* av) {
        int sec = kb >> LOG_CPS;
        int ci0 = (kb & (CPS - 1)) << 5;
        int p = sec >> 2, t = sec & 3;
#pragma unroll
        for (int it = 0; it < 2; ++it) {
            long o = offT[it][t];
            uint4 v = {0u, 0u, 0u, 0u};
            if (o >= 0)
                v = *(const uint4*)(X + o + p * CIN + ci0 + kcA[it]);
            av[it] = v;
        }
    };

    f32x4 acc[4][4] = {};
    bf16x8 bq[4];
#pragma unroll
    for (int sn = 0; sn < 4; ++sn) bq[sn] = *(const bf16x8*)(Wp + sn * 512);

    {
        uint4 av[2];
        loadA(0, av);
#pragma unroll
        for (int it = 0; it < 2; ++it) *(uint4*)(&As[0][rowA[it]][kcA[it]]) = av[it];
    }
    __syncthreads();

    for (int ks = 0; ks < NSTEP; ++ks) {
        const int cur = ks & 1;
        uint4 av[2];
        if (ks + 1 < NSTEP) loadA(ks + 1, av);
        bf16x8 bcur[4];
#pragma unroll
        for (int sn = 0; sn < 4; ++sn) bcur[sn] = bq[sn];
        if (ks + 1 < NSTEP) {
            const bf16* Wn = Wp + (size_t)(ks + 1) * 4096;
#pragma unroll
            for (int sn = 0; sn < 4; ++sn) bq[sn] = *(const bf16x8*)(Wn + sn * 512);
        }
        bf16x8 af[4];
#pragma unroll
        for (int s = 0; s < 4; ++s)
            af[s] = *(const bf16x8*)(&As[cur][wm + s * 16 + lm][lq * 8]);
#pragma unroll
        for (int sm = 0; sm < 4; ++sm)
#pragma unroll
            for (int sn = 0; sn < 4; ++sn)
                acc[sm][sn] = __builtin_amdgcn_mfma_f32_16x16x32_bf16(af[sm], bcur[sn], acc[sm][sn], 0, 0, 0);
        if (ks + 1 < NSTEP) {
#pragma unroll
            for (int it = 0; it < 2; ++it) *(uint4*)(&As[1 - cur][rowA[it]][kcA[it]]) = av[it];
        }
        __syncthreads();
    }

#pragma unroll
    for (int sm = 0; sm < 4; ++sm) {
#pragma unroll
        for (int v = 0; v < 4; ++v) {
            int m = mBase + wm + sm * 16 + lq * 4 + v;
            int b = m / (S * S); int rem = m - b * (S * S);
            int i = rem / S, j = rem % S;
            int oh = 2 * i + py, ow = 2 * j + px;
            size_t rowoff = (size_t)((b * HOUT + oh) * HOUT + ow) * C2O;
#pragma unroll
            for (int sn = 0; sn < 4; ++sn) {
                int n = nBase + wn + sn * 16 + lm;
                float bias = (n < N) ? biasr[n] : biasi[n - N];
                Y[rowoff + n] = f2b(acc[sm][sn][v] + bias);
            }
        }
    }
}

// ---------------- layer4 via MFMA, hoisted A-addresses ----------------
__global__ __launch_bounds__(256, 2) void conv4_mfma(
    const bf16* __restrict__ X, const bf16* __restrict__ Wall,
    const float* __restrict__ br, float* __restrict__ out) {
    constexpr int CIN = 128, S = 16, K = 512, TWOK = 1024, C2I = 256;
    constexpr int CPS = 4, LOG_CPS = 2;
    __shared__ short As[128][40];
    __shared__ short Bs[16][40];
    const int cls = blockIdx.z;
    const int py = cls >> 1, px = cls & 1;
    const bf16* W = Wall + (size_t)cls * 16 * TWOK;
    const int tid = threadIdx.x;
    const int mBase = blockIdx.x * 128;
    const int wid = tid >> 6, lane = tid & 63;
    const int wm = wid * 32;
    const int lm = lane & 15, lq = lane >> 4;
    const int dh0 = py ? 1 : 0, dh1 = py ? 0 : -1;
    const int dw0 = px ? 1 : 0, dw1 = px ? 0 : -1;

    int rowA[2], kcA[2];
    long offT[2][4];
#pragma unroll
    for (int it = 0; it < 2; ++it) {
        int slot = tid + it * 256;
        rowA[it] = slot >> 2; kcA[it] = (slot & 3) * 8;
        int m = mBase + rowA[it];
        int b = m >> 8; int rem = m & 255;
        int i = rem >> 4, j = rem & 15;
#pragma unroll
        for (int t = 0; t < 4; ++t) {
            int a = t >> 1, e = t & 1;
            int ih = i + (a ? dh1 : dh0);
            int iw = j + (e ? dw1 : dw0);
            offT[it][t] = ((unsigned)ih < (unsigned)S && (unsigned)iw < (unsigned)S)
                ? (long)((b * S + ih) * S + iw) * C2I : -1L;
        }
    }

    f32x4 acc[2] = {};

    for (int kb = 0; kb < TWOK / 32; ++kb) {
        int sec = kb >> LOG_CPS;
        int ci0 = (kb & (CPS - 1)) << 5;
        int p = sec >> 2, t = sec & 3;
#pragma unroll
        for (int it = 0; it < 2; ++it) {
            long o = offT[it][t];
            uint4 v = {0u, 0u, 0u, 0u};
            if (o >= 0)
                v = *(const uint4*)(X + o + p * CIN + ci0 + kcA[it]);
            *(uint4*)(&As[rowA[it]][kcA[it]]) = v;
        }
        if (tid < 64) {
            int row = tid >> 2, kc = (tid & 3) * 8;
            uint4 w = *(const uint4*)(W + (size_t)row * TWOK + kb * 32 + kc);
            *(uint4*)(&Bs[row][kc]) = w;
        }
        __syncthreads();
        bf16x8 bfr = *(const bf16x8*)(&Bs[lm][lq * 8]);
        bf16x8 af0 = *(const bf16x8*)(&As[wm + lm][lq * 8]);
        bf16x8 af1 = *(const bf16x8*)(&As[wm + 16 + lm][lq * 8]);
        acc[0] = __builtin_amdgcn_mfma_f32_16x16x32_bf16(af0, bfr, acc[0], 0, 0, 0);
        acc[1] = __builtin_amdgcn_mfma_f32_16x16x32_bf16(af1, bfr, acc[1], 0, 0, 0);
        __syncthreads();
    }

    int n = lm;
    if (n < NCH) {
        float bias = br[n];
#pragma unroll
        for (int s = 0; s < 2; ++s) {
#pragma unroll
            for (int v = 0; v < 4; ++v) {
                int m = mBase + wm + s * 16 + lq * 4 + v;
                int b = m >> 8; int rem = m & 255;
                int i = rem >> 4, j = rem & 15;
                int oh = 2 * i + py, ow = 2 * j + px;
                out[((size_t)(b * NCH + n) * 32 + oh) * 32 + ow] = tanhf(acc[s][v] + bias);
            }
        }
    }
}

extern "C" void kernel_launch(void* const* d_in, const int* in_sizes, int n_in,
                              void* d_out, int out_size, void* d_ws, size_t ws_size,
                              hipStream_t stream) {
    const float* noise_re = (const float*)d_in[0];
    const float* noise_im = (const float*)d_in[1];
    const int*   labels   = (const int*)d_in[2];
    const float* emb      = (const float*)d_in[3];
    const float* w1r = (const float*)d_in[4],  *w1i = (const float*)d_in[5];
    const float* b1r = (const float*)d_in[6],  *b1i = (const float*)d_in[7];
    const float* g1rr = (const float*)d_in[8], *g1ri = (const float*)d_in[9], *g1ii = (const float*)d_in[10];
    const float* n1br = (const float*)d_in[11], *n1bi = (const float*)d_in[12];
    const float* w2r = (const float*)d_in[13], *w2i = (const float*)d_in[14];
    const float* b2r = (const float*)d_in[15], *b2i = (const float*)d_in[16];
    const float* g2rr = (const float*)d_in[17], *g2ri = (const float*)d_in[18], *g2ii = (const float*)d_in[19];
    const float* n2br = (const float*)d_in[20], *n2bi = (const float*)d_in[21];
    const float* w3r = (const float*)d_in[22], *w3i = (const float*)d_in[23];
    const float* b3r = (const float*)d_in[24], *b3i = (const float*)d_in[25];
    const float* g3rr = (const float*)d_in[26], *g3ri = (const float*)d_in[27], *g3ii = (const float*)d_in[28];
    const float* n3br = (const float*)d_in[29], *n3bi = (const float*)d_in[30];
    const float* w4r = (const float*)d_in[31], *w4i = (const float*)d_in[32];
    const float* b4r = (const float*)d_in[33], *b4i = (const float*)d_in[34];

    // ---- workspace layout (bytes) ----
    // y3cl region [0, 33554432) — written by gemmL3. Overlays (dead before gemmL3):
    //   x1cl   [0, 8388608)
    //   B1     [8388608, 15728640)   -> after gemm1: part12 (128*512*5*4 = 1.31 MB)
    //   W2all  [15728640, 32505856)
    // y2cl  [33554432, 50331648)
    // W3all [50331648, 54525952)     -> after gemmL3: part3
    // tail: coef1 [54525952) coef2 [54538240) coef3 [54544384)
    //       x0bf [54547456) W4all [54662144, 54793216)
    char* ws = (char*)d_ws;
    bf16* y3cl = (bf16*)ws;
    bf16* x1cl = (bf16*)ws;
    bf16* B1    = (bf16*)(ws + 8388608);
    float* part12 = (float*)(ws + 8388608);   // overlays B1 AFTER gemm1 consumed it
    bf16* W2all = (bf16*)(ws + 15728640);
    bf16* y2cl  = (bf16*)(ws + 33554432);
    bf16* W3all = (bf16*)(ws + 50331648);
    float* part3 = (float*)(ws + 50331648);   // overlays W3all AFTER gemmL3
    float* coef1 = (float*)(ws + 54525952);
    float* coef2 = (float*)(ws + 54538240);
    float* coef3 = (float*)(ws + 54544384);
    bf16* x0bf  = (bf16*)(ws + 54547456);
    bf16* W4all = (bf16*)(ws + 54662144);

    prep_combined<<<NB_W1 + NB_W2 + NB_W3 + NB_W4 + NB_X0, 256, 0, stream>>>(
        w1r, w1i, w2r, w2i, w3r, w3i, w4r, w4i,
        noise_re, noise_im, labels, emb,
        B1, W2all, W3all, W4all, x0bf);

    // L1 GEMM -> x1cl
    gemm1<<<dim3(2, 128), 256, 0, stream>>>(x0bf, B1, b1r, b1i, x1cl);

    // BN1 (C=512, rows=4096): 128 blocks, logG=6 (nsl=4), rowsPerSlice=8
    bn_stats_v<<<128, 256, 0, stream>>>(x1cl, part12, C1, 6, 8);
    bn_coef_v<<<2, 256, 0, stream>>>(part12, g1rr, g1ri, g1ii, n1br, n1bi, coef1, C1, 1.f / 4096.f);
    bn_apply_v<<<1024, 256, 0, stream>>>(x1cl, coef1, C1, 6, 4096 * 64);

    // L2 GEMM: pipelined, B-direct -> 512 blocks
    gemm_convt_bd<C1, 4, C2><<<dim3(32, 4, 4), 256, 0, stream>>>(x1cl, W2all, b2r, b2i, y2cl);

    // BN2 (C=256, rows=16384): 128 blocks, logG=5 (nsl=8), rowsPerSlice=16
    bn_stats_v<<<128, 256, 0, stream>>>(y2cl, part12, C2, 5, 16);
    bn_coef_v<<<1, 256, 0, stream>>>(part12, g2rr, g2ri, g2ii, n2br, n2bi, coef2, C2, 1.f / 16384.f);
    bn_apply_v<<<2048, 256, 0, stream>>>(y2cl, coef2, C2, 5, 16384 * 32);

    // L3 GEMM: pipelined, B-direct -> 1024 blocks
    gemm_convt_bd<C2, 8, C3><<<dim3(128, 2, 4), 256, 0, stream>>>(y2cl, W3all, b3r, b3i, y3cl);

    // BN3 (C=128, rows=65536): 128 blocks, logG=4 (nsl=16), rowsPerSlice=32
    bn_stats_v<<<128, 256, 0, stream>>>(y3cl, part3, C3, 4, 32);
    bn_coef_v<<<1, 256, 0, stream>>>(part3, g3rr, g3ri, g3ii, n3br, n3bi, coef3, C3, 1.f / 65536.f);
    bn_apply_v<<<4096, 256, 0, stream>>>(y3cl, coef3, C3, 4, 65536 * 16);

    // L4: MFMA + tanh -> d_out (real part, fp32)
    conv4_mfma<<<dim3(512, 1, 4), 256, 0, stream>>>(y3cl, W4all, b4r, (float*)d_out);
}

// Round 16
// 486.759 us; speedup vs baseline: 25.4857x; 1.1175x over previous
//
#include <hip/hip_runtime.h>
#include <hip/hip_bf16.h>
#include <math.h>

#define BATCH 256
#define LAT 100
#define NCLS 10
#define CIN0 110
#define C1 512
#define C2 256
#define C3 128
#define NCH 3
#define EPS 1e-5f

typedef __hip_bfloat16 bf16;
typedef short bf16x8 __attribute__((ext_vector_type(8)));
typedef float f32x4 __attribute__((ext_vector_type(4)));

__device__ __forceinline__ float b2f(bf16 v) { return __bfloat162float(v); }
__device__ __forceinline__ bf16 f2b(float v) { return __float2bfloat16(v); }
__device__ __forceinline__ float s2f(short s) {
    unsigned u = ((unsigned)(unsigned short)s) << 16;
    return __builtin_bit_cast(float, u);
}
__device__ __forceinline__ short f2s(float f) {
    bf16 b = __float2bfloat16(f);
    return *(short*)&b;
}

// ---------------- combined prep: B1 | W2all | W3all | W4all | x0bf ----------------
// Column (n) order of B1/W2all/W3all is PAIR-INTERLEAVED: n' = 2c + part
// (part 0=real-output row, 1=imag-output row) so gemm epilogues can pair
// re/im in adjacent lanes for BN sri stats via shfl_xor.
#define NB_W1 14336
#define NB_W2 32768
#define NB_W3 8192
#define NB_W4 256
#define NB_X0 224

__device__ __forceinline__ void w1prep_body(const float* wr, const float* wi, bf16* B, int idx) {
    if (idx >= 16384 * 224) return;
    int n = idx / 224, k = idx - n * 224;
    int p = n >> 10;                 // spatial position 0..15
    int c = (n & 1023) >> 1;         // channel
    int part = n & 1;                // 0=re row, 1=im row
    int pk = k >= 112; int ci = k - pk * 112;
    float v = 0.f;
    if (ci < CIN0) {
        size_t widx = ((size_t)ci * C1 + c) * 16 + p;
        float vr = wr[widx], vi = wi[widx];
        v = (part == 0) ? (pk ? -vi : vr) : (pk ? vr : vi);
    }
    B[idx] = f2b(v);
}

template<int CIN, int N>
__device__ __forceinline__ void wprep_panel_body(const float* wr, const float* wi, bf16* W,
                                                 size_t idx) {
    constexpr int K = 4 * CIN, TWOK = 8 * CIN;
    size_t per_cls = (size_t)2 * N * TWOK;
    if (idx >= 4 * per_cls) return;
    int cls = (int)(idx / per_cls);
    size_t r = idx - (size_t)cls * per_cls;
    size_t chunk_nb = (size_t)TWOK * 128;
    int nb = (int)(r / chunk_nb);
    int r2 = (int)(r - (size_t)nb * chunk_nb);
    int kb = r2 >> 12;
    int w = r2 & 4095;
    int f = w >> 9;
    int l = (w >> 3) & 63;
    int j = w & 7;
    int n_virt = nb * 128 + (f >> 2) * 64 + (f & 3) * 16 + (l & 15);
    int k = kb * 32 + (l >> 4) * 8 + j;
    int c = n_virt >> 1, part = n_virt & 1;       // pair-interleaved remap
    int py = cls >> 1, px = cls & 1;
    int p = k >= K; int kk = k - p * K;
    int t = kk / CIN, ci = kk - t * CIN;
    int a = t >> 1, e = t & 1;
    int kh = py ? (a ? 2 : 0) : (a ? 3 : 1);
    int kw = px ? (e ? 2 : 0) : (e ? 3 : 1);
    size_t widx = ((size_t)ci * N + c) * 16 + kh * 4 + kw;
    float vr = wr[widx], vi = wi[widx];
    float v = (part == 0) ? (p ? -vi : vr) : (p ? vr : vi);
    W[idx] = f2b(v);
}

__device__ __forceinline__ void wprep4_body(const float* wr, const float* wi, bf16* W, int idx) {
    if (idx >= 65536) return;
    int cls = idx >> 14, rem = idx & 16383;
    int py = cls >> 1, px = cls & 1;
    int n = rem >> 10, k = rem & 1023;
    float v = 0.f;
    if (n < NCH) {
        int p = k >= 512; int kk = k - p * 512;
        int t = kk >> 7, ci = kk & 127;
        int a = t >> 1, e = t & 1;
        int kh = py ? (a ? 2 : 0) : (a ? 3 : 1);
        int kw = px ? (e ? 2 : 0) : (e ? 3 : 1);
        size_t widx = ((size_t)ci * NCH + n) * 16 + kh * 4 + kw;
        v = p ? -wi[widx] : wr[widx];
    }
    W[idx] = f2b(v);
}

__device__ __forceinline__ void x0_body(const float* nre, const float* nim,
                                        const int* labels, const float* emb,
                                        bf16* A, int idx) {
    if (idx >= BATCH * 224) return;
    int b = idx / 224, k = idx - b * 224;
    int p = k >= 112; int ci = k - p * 112;
    float v = 0.f;
    if (ci < CIN0) {
        if (!p) v = (ci < LAT) ? nre[b * LAT + ci] : emb[labels[b] * NCLS + (ci - LAT)];
        else    v = (ci < LAT) ? nim[b * LAT + ci] : 0.f;
    }
    A[idx] = f2b(v);
}

__global__ void prep_combined(const float* __restrict__ w1r, const float* __restrict__ w1i,
                              const float* __restrict__ w2r, const float* __restrict__ w2i,
                              const float* __restrict__ w3r, const float* __restrict__ w3i,
                              const float* __restrict__ w4r, const float* __restrict__ w4i,
                              const float* __restrict__ nre, const float* __restrict__ nim,
                              const int* __restrict__ labels, const float* __restrict__ emb,
                              bf16* __restrict__ B1, bf16* __restrict__ W2all,
                              bf16* __restrict__ W3all, bf16* __restrict__ W4all,
                              bf16* __restrict__ x0bf) {
    int bid = blockIdx.x;
    if (bid < NB_W1) {
        w1prep_body(w1r, w1i, B1, bid * 256 + threadIdx.x);
    } else if (bid < NB_W1 + NB_W2) {
        wprep_panel_body<C1, C2>(w2r, w2i, W2all, (size_t)(bid - NB_W1) * 256 + threadIdx.x);
    } else if (bid < NB_W1 + NB_W2 + NB_W3) {
        wprep_panel_body<C2, C3>(w3r, w3i, W3all, (size_t)(bid - NB_W1 - NB_W2) * 256 + threadIdx.x);
    } else if (bid < NB_W1 + NB_W2 + NB_W3 + NB_W4) {
        wprep4_body(w4r, w4i, W4all, (bid - NB_W1 - NB_W2 - NB_W3) * 256 + threadIdx.x);
    } else {
        x0_body(nre, nim, labels, emb, x0bf,
                (bid - NB_W1 - NB_W2 - NB_W3 - NB_W4) * 256 + threadIdx.x);
    }
}

// ---------------- epilogue-stats helper: LDS reduce + global atomics ----------------
// red: 64 channels x 5 stats in (reused) LDS; caller provides s1/s2/sp per sn.
__device__ __forceinline__ void epi_stats_flush(float* red, float* Sstat, int Cn,
                                                int cBaseGlobal, int tid,
                                                const int* clArr, const float* s1,
                                                const float* s2, const float* sp, int isRe) {
    for (int i = tid; i < 320; i += 256) red[i] = 0.f;
    __syncthreads();
#pragma unroll
    for (int sn = 0; sn < 4; ++sn) {
        int cl = clArr[sn];
        if (isRe) {
            atomicAdd(&red[cl * 5 + 0], s1[sn]);
            atomicAdd(&red[cl * 5 + 2], s2[sn]);
            atomicAdd(&red[cl * 5 + 4], sp[sn]);
        } else {
            atomicAdd(&red[cl * 5 + 1], s1[sn]);
            atomicAdd(&red[cl * 5 + 3], s2[sn]);
        }
    }
    __syncthreads();
    for (int i = tid; i < 320; i += 256) {
        int cl = i / 5, st = i - cl * 5;
        atomicAdd(&Sstat[st * Cn + cBaseGlobal + cl], red[i]);
    }
}

// ---------------- gemm1: C[256][16384] = A[256][224] x B1^T -> x1cl, + BN1 stats ----------------
__global__ __launch_bounds__(256, 1) void gemm1(
    const bf16* __restrict__ A, const bf16* __restrict__ B,
    const float* __restrict__ b1r, const float* __restrict__ b1i,
    bf16* __restrict__ Y, float* __restrict__ Sstat) {
    __shared__ short As[128][40];
    __shared__ short Bs[128][40];
    const int tid = threadIdx.x;
    const int mBase = blockIdx.x * 128, nBase = blockIdx.y * 128;
    const int wid = tid >> 6, lane = tid & 63;
    const int wm = (wid >> 1) * 64, wn = (wid & 1) * 64;
    const int lm = lane & 15, lq = lane >> 4;

    f32x4 acc[4][4] = {};

    for (int k0 = 0; k0 < 224; k0 += 32) {
#pragma unroll
        for (int it = 0; it < 2; ++it) {
            int slot = tid + it * 256;
            int row = slot >> 2, kc = (slot & 3) * 8;
            int k = k0 + kc;
            *(uint4*)(&As[row][kc]) = *(const uint4*)(A + (size_t)(mBase + row) * 224 + k);
            *(uint4*)(&Bs[row][kc]) = *(const uint4*)(B + (size_t)(nBase + row) * 224 + k);
        }
        __syncthreads();
        bf16x8 af[4], bfr[4];
#pragma unroll
        for (int s = 0; s < 4; ++s) {
            af[s]  = *(const bf16x8*)(&As[wm + s * 16 + lm][lq * 8]);
            bfr[s] = *(const bf16x8*)(&Bs[wn + s * 16 + lm][lq * 8]);
        }
#pragma unroll
        for (int sm = 0; sm < 4; ++sm)
#pragma unroll
            for (int sn = 0; sn < 4; ++sn)
                acc[sm][sn] = __builtin_amdgcn_mfma_f32_16x16x32_bf16(af[sm], bfr[sn], acc[sm][sn], 0, 0, 0);
        __syncthreads();
    }

    const int pos = nBase >> 10;
    float s1[4] = {}, s2[4] = {}, sp[4] = {};
    int clArr[4];
#pragma unroll
    for (int sn = 0; sn < 4; ++sn) clArr[sn] = (wn + sn * 16 + lm) >> 1;
    const int part = lm & 1;

#pragma unroll
    for (int sm = 0; sm < 4; ++sm) {
#pragma unroll
        for (int v = 0; v < 4; ++v) {
            int m = mBase + wm + sm * 16 + lq * 4 + v;
#pragma unroll
            for (int sn = 0; sn < 4; ++sn) {
                int n = nBase + wn + sn * 16 + lm;
                int c = (n & 1023) >> 1;
                float bias = part ? b1i[c] : b1r[c];
                float val = acc[sm][sn][v] + bias;
                float pv = __shfl_xor(val, 1, 64);
                s1[sn] += val; s2[sn] += val * val;
                if (!part) sp[sn] += val * pv;
                Y[(size_t)m * 16384 + (pos << 10) + part * 512 + c] = f2b(val);
            }
        }
    }
    epi_stats_flush((float*)As, Sstat, C1, (nBase & 1023) >> 1, tid, clArr, s1, s2, sp, !part);
}

// ---------------- BN apply+ReLU with INLINE coef from stat totals ----------------
__global__ void bn_apply_v2(bf16* __restrict__ Y, const float* __restrict__ S,
                            const float* __restrict__ grr, const float* __restrict__ gri,
                            const float* __restrict__ gii,
                            const float* __restrict__ betar, const float* __restrict__ betai,
                            int C, int logG, int total, float invN) {
    int idx = blockIdx.x * 256 + threadIdx.x;
    if (idx >= total) return;
    int G = 1 << logG;
    int g = idx & (G - 1);
    size_t base = (size_t)(idx >> logG) * 2 * C + g * 8;
    bf16x8 vr8 = *(const bf16x8*)(Y + base);
    bf16x8 vi8 = *(const bf16x8*)(Y + base + C);
    bf16x8 or8, oi8;
#pragma unroll
    for (int j = 0; j < 8; ++j) {
        int c = g * 8 + j;
        float sr = S[c], si = S[C + c], srr = S[2 * C + c], sii = S[3 * C + c], sri = S[4 * C + c];
        float mr = sr * invN, mi = si * invN;
        float crr = srr * invN - mr * mr + EPS;
        float cii = sii * invN - mi * mi + EPS;
        float cri = sri * invN - mr * mi;
        float s = sqrtf(crr * cii - cri * cri);
        float t = sqrtf(crr + cii + 2.f * s);
        float inv = 1.f / (s * t);
        float rrr = (cii + s) * inv, rii = (crr + s) * inv, rri = -cri * inv;
        float Grr = grr[c], Gri = gri[c], Gii = gii[c];
        float arr = Grr * rrr + Gri * rri, ari = Grr * rri + Gri * rii;
        float air = Gri * rrr + Gii * rri, aii = Gri * rri + Gii * rii;
        float cR = betar[c] - arr * mr - ari * mi;
        float cI = betai[c] - air * mr - aii * mi;
        float vr = s2f(vr8[j]), vi = s2f(vi8[j]);
        or8[j] = f2s(fmaxf(arr * vr + ari * vi + cR, 0.f));
        oi8[j] = f2s(fmaxf(air * vr + aii * vi + cI, 0.f));
    }
    *(bf16x8*)(Y + base) = or8;
    *(bf16x8*)(Y + base + C) = oi8;
}

// ---------------- MFMA GEMM 128x128, B direct, pipelined, + BN stats epilogue ----------------
template<int CIN, int S, int N>
__global__ __launch_bounds__(256, 2) void gemm_convt_bd(
    const bf16* __restrict__ X, const bf16* __restrict__ Wall,
    const float* __restrict__ biasr, const float* __restrict__ biasi,
    bf16* __restrict__ Y, float* __restrict__ Sstat) {
    constexpr int K = 4 * CIN, TWOK = 8 * CIN, C2I = 2 * CIN, C2O = 2 * N, HOUT = 2 * S;
    constexpr int NSTEP = TWOK / 32;
    constexpr int CPS = CIN / 32;
    constexpr int LOG_CPS = (CIN == 512) ? 4 : 3;
    __shared__ short As[2][128][40];
    const int cls = blockIdx.z;
    const int py = cls >> 1, px = cls & 1;
    const int tid = threadIdx.x;
    const int mBase = blockIdx.x * 128, nBase = blockIdx.y * 128;
    const int wid = tid >> 6, lane = tid & 63;
    const int wm = (wid >> 1) * 64, wn = (wid & 1) * 64;
    const int lm = lane & 15, lq = lane >> 4;
    const int dh0 = py ? 1 : 0, dh1 = py ? 0 : -1;
    const int dw0 = px ? 1 : 0, dw1 = px ? 0 : -1;

    const bf16* Wp = Wall
        + ((size_t)(cls * (C2O / 128) + blockIdx.y) * (TWOK / 32)) * 4096
        + ((wn >> 6) * 4) * 512 + lane * 8;

    int rowA[2], kcA[2];
    long offT[2][4];
#pragma unroll
    for (int it = 0; it < 2; ++it) {
        int slot = tid + it * 256;
        rowA[it] = slot >> 2; kcA[it] = (slot & 3) * 8;
        int m = mBase + rowA[it];
        int b = m / (S * S); int rem = m - b * (S * S);
        int i = rem / S, j = rem % S;
#pragma unroll
        for (int t = 0; t < 4; ++t) {
            int a = t >> 1, e = t & 1;
            int ih = i + (a ? dh1 : dh0);
            int iw = j + (e ? dw1 : dw0);
            offT[it][t] = ((unsigned)ih < (unsigned)S && (unsigned)iw < (unsigned)S)
                ? (long)((b * S + ih) * S + iw) * C2I : -1L;
        }
    }

    auto loadA = [&](int kb, uint4* av) {
        int sec = kb >> LOG_CPS;
        int ci0 = (kb & (CPS - 1)) << 5;
        int p = sec >> 2, t = sec & 3;
#pragma unroll
        for (int it = 0; it < 2; ++it) {
            long o = offT[it][t];
            uint4 v = {0u, 0u, 0u, 0u};
            if (o >= 0)
                v = *(const uint4*)(X + o + p * CIN + ci0 + kcA[it]);
            av[it] = v;
        }
    };

    f32x4 acc[4][4] = {};
    bf16x8 bq[4];
#pragma unroll
    for (int sn = 0; sn < 4; ++sn) bq[sn] = *(const bf16x8*)(Wp + sn * 512);

    {
        uint4 av[2];
        loadA(0, av);
#pragma unroll
        for (int it = 0; it < 2; ++it) *(uint4*)(&As[0][rowA[it]][kcA[it]]) = av[it];
    }
    __syncthreads();

    for (int ks = 0; ks < NSTEP; ++ks) {
        const int cur = ks & 1;
        uint4 av[2];
        if (ks + 1 < NSTEP) loadA(ks + 1, av);
        bf16x8 bcur[4];
#pragma unroll
        for (int sn = 0; sn < 4; ++sn) bcur[sn] = bq[sn];
        if (ks + 1 < NSTEP) {
            const bf16* Wn = Wp + (size_t)(ks + 1) * 4096;
#pragma unroll
            for (int sn = 0; sn < 4; ++sn) bq[sn] = *(const bf16x8*)(Wn + sn * 512);
        }
        bf16x8 af[4];
#pragma unroll
        for (int s = 0; s < 4; ++s)
            af[s] = *(const bf16x8*)(&As[cur][wm + s * 16 + lm][lq * 8]);
#pragma unroll
        for (int sm = 0; sm < 4; ++sm)
#pragma unroll
            for (int sn = 0; sn < 4; ++sn)
                acc[sm][sn] = __builtin_amdgcn_mfma_f32_16x16x32_bf16(af[sm], bcur[sn], acc[sm][sn], 0, 0, 0);
        if (ks + 1 < NSTEP) {
#pragma unroll
            for (int it = 0; it < 2; ++it) *(uint4*)(&As[1 - cur][rowA[it]][kcA[it]]) = av[it];
        }
        __syncthreads();
    }

    float s1[4] = {}, s2[4] = {}, sp[4] = {};
    int clArr[4];
#pragma unroll
    for (int sn = 0; sn < 4; ++sn) clArr[sn] = (wn + sn * 16 + lm) >> 1;
    const int part = lm & 1;

#pragma unroll
    for (int sm = 0; sm < 4; ++sm) {
#pragma unroll
        for (int v = 0; v < 4; ++v) {
            int m = mBase + wm + sm * 16 + lq * 4 + v;
            int b = m / (S * S); int rem = m - b * (S * S);
            int i = rem / S, j = rem % S;
            int oh = 2 * i + py, ow = 2 * j + px;
            size_t rowoff = (size_t)((b * HOUT + oh) * HOUT + ow) * C2O;
#pragma unroll
            for (int sn = 0; sn < 4; ++sn) {
                int n = nBase + wn + sn * 16 + lm;
                int c = n >> 1;
                float bias = part ? biasi[c] : biasr[c];
                float val = acc[sm][sn][v] + bias;
                float pv = __shfl_xor(val, 1, 64);
                s1[sn] += val; s2[sn] += val * val;
                if (!part) sp[sn] += val * pv;
                Y[rowoff + part * N + c] = f2b(val);
            }
        }
    }
    epi_stats_flush((float*)As, Sstat, N, nBase >> 1, tid, clArr, s1, s2, sp, !part);
}

// ---------------- layer4 via MFMA, M-tile 256, hoisted A-addresses ----------------
__global__ __launch_bounds__(256, 2) void conv4_mfma(
    const bf16* __restrict__ X, const bf16* __restrict__ Wall,
    const float* __restrict__ br, float* __restrict__ out) {
    constexpr int S = 16, TWOK = 1024, C2I = 256, CIN = 128;
    constexpr int CPS = 4, LOG_CPS = 2;
    __shared__ short As[256][40];
    __shared__ short Bs[16][40];
    const int cls = blockIdx.z;
    const int py = cls >> 1, px = cls & 1;
    const bf16* W = Wall + (size_t)cls * 16 * TWOK;
    const int tid = threadIdx.x;
    const int mBase = blockIdx.x * 256;
    const int wid = tid >> 6, lane = tid & 63;
    const int wm = wid * 64;
    const int lm = lane & 15, lq = lane >> 4;
    const int dh0 = py ? 1 : 0, dh1 = py ? 0 : -1;
    const int dw0 = px ? 1 : 0, dw1 = px ? 0 : -1;

    int rowA[4], kcA[4];
    long offT[4][4];
#pragma unroll
    for (int it = 0; it < 4; ++it) {
        int slot = tid + it * 256;
        rowA[it] = slot >> 2; kcA[it] = (slot & 3) * 8;
        int m = mBase + rowA[it];
        int b = m >> 8; int rem = m & 255;
        int i = rem >> 4, j = rem & 15;
#pragma unroll
        for (int t = 0; t < 4; ++t) {
            int a = t >> 1, e = t & 1;
            int ih = i + (a ? dh1 : dh0);
            int iw = j + (e ? dw1 : dw0);
            offT[it][t] = ((unsigned)ih < (unsigned)S && (unsigned)iw < (unsigned)S)
                ? (long)((b * S + ih) * S + iw) * C2I : -1L;
        }
    }

    f32x4 acc[4] = {};

    for (int kb = 0; kb < TWOK / 32; ++kb) {
        int sec = kb >> LOG_CPS;
        int ci0 = (kb & (CPS - 1)) << 5;
        int p = sec >> 2, t = sec & 3;
#pragma unroll
        for (int it = 0; it < 4; ++it) {
            long o = offT[it][t];
            uint4 v = {0u, 0u, 0u, 0u};
            if (o >= 0)
                v = *(const uint4*)(X + o + p * CIN + ci0 + kcA[it]);
            *(uint4*)(&As[rowA[it]][kcA[it]]) = v;
        }
        if (tid < 64) {
            int row = tid >> 2, kc = (tid & 3) * 8;
            uint4 w = *(const uint4*)(W + (size_t)row * TWOK + kb * 32 + kc);
            *(uint4*)(&Bs[row][kc]) = w;
        }
        __syncthreads();
        bf16x8 bfr = *(const bf16x8*)(&Bs[lm][lq * 8]);
#pragma unroll
        for (int s = 0; s < 4; ++s) {
            bf16x8 af = *(const bf16x8*)(&As[wm + s * 16 + lm][lq * 8]);
            acc[s] = __builtin_amdgcn_mfma_f32_16x16x32_bf16(af, bfr, acc[s], 0, 0, 0);
        }
        __syncthreads();
    }

    int n = lm;
    if (n < NCH) {
        float bias = br[n];
#pragma unroll
        for (int s = 0; s < 4; ++s) {
#pragma unroll
            for (int v = 0; v < 4; ++v) {
                int m = mBase + wm + s * 16 + lq * 4 + v;
                int b = m >> 8; int rem = m & 255;
                int i = rem >> 4, j = rem & 15;
                int oh = 2 * i + py, ow = 2 * j + px;
                out[((size_t)(b * NCH + n) * 32 + oh) * 32 + ow] = tanhf(acc[s][v] + bias);
            }
        }
    }
}

extern "C" void kernel_launch(void* const* d_in, const int* in_sizes, int n_in,
                              void* d_out, int out_size, void* d_ws, size_t ws_size,
                              hipStream_t stream) {
    const float* noise_re = (const float*)d_in[0];
    const float* noise_im = (const float*)d_in[1];
    const int*   labels   = (const int*)d_in[2];
    const float* emb      = (const float*)d_in[3];
    const float* w1r = (const float*)d_in[4],  *w1i = (const float*)d_in[5];
    const float* b1r = (const float*)d_in[6],  *b1i = (const float*)d_in[7];
    const float* g1rr = (const float*)d_in[8], *g1ri = (const float*)d_in[9], *g1ii = (const float*)d_in[10];
    const float* n1br = (const float*)d_in[11], *n1bi = (const float*)d_in[12];
    const float* w2r = (const float*)d_in[13], *w2i = (const float*)d_in[14];
    const float* b2r = (const float*)d_in[15], *b2i = (const float*)d_in[16];
    const float* g2rr = (const float*)d_in[17], *g2ri = (const float*)d_in[18], *g2ii = (const float*)d_in[19];
    const float* n2br = (const float*)d_in[20], *n2bi = (const float*)d_in[21];
    const float* w3r = (const float*)d_in[22], *w3i = (const float*)d_in[23];
    const float* b3r = (const float*)d_in[24], *b3i = (const float*)d_in[25];
    const float* g3rr = (const float*)d_in[26], *g3ri = (const float*)d_in[27], *g3ii = (const float*)d_in[28];
    const float* n3br = (const float*)d_in[29], *n3bi = (const float*)d_in[30];
    const float* w4r = (const float*)d_in[31], *w4i = (const float*)d_in[32];
    const float* b4r = (const float*)d_in[33], *b4i = (const float*)d_in[34];

    // ---- workspace layout (bytes) ----
    // y3cl [0, 33554432). Overlays (dead before gemmL3):
    //   x1cl [0, 8388608) ; B1 [8388608, 15728640) ; W2all [15728640, 32505856)
    // y2cl  [33554432, 50331648)
    // W3all [50331648, 54525952)
    // tail: x0bf [54547456) W4all [54662144, 54793216)
    //       stats: S1 [54793216, +10240) S2 [54803456, +5120) S3 [54808576, +2560)
    char* ws = (char*)d_ws;
    bf16* y3cl = (bf16*)ws;
    bf16* x1cl = (bf16*)ws;
    bf16* B1    = (bf16*)(ws + 8388608);
    bf16* W2all = (bf16*)(ws + 15728640);
    bf16* y2cl  = (bf16*)(ws + 33554432);
    bf16* W3all = (bf16*)(ws + 50331648);
    bf16* x0bf  = (bf16*)(ws + 54547456);
    bf16* W4all = (bf16*)(ws + 54662144);
    float* S1 = (float*)(ws + 54793216);
    float* S2 = (float*)(ws + 54803456);
    float* S3 = (float*)(ws + 54808576);

    (void)hipMemsetAsync(S1, 0, 17920, stream);   // zeros S1,S2,S3 (contiguous)

    prep_combined<<<NB_W1 + NB_W2 + NB_W3 + NB_W4 + NB_X0, 256, 0, stream>>>(
        w1r, w1i, w2r, w2i, w3r, w3i, w4r, w4i,
        noise_re, noise_im, labels, emb,
        B1, W2all, W3all, W4all, x0bf);

    // L1 GEMM (+BN1 stats) -> x1cl
    gemm1<<<dim3(2, 128), 256, 0, stream>>>(x0bf, B1, b1r, b1i, x1cl, S1);
    bn_apply_v2<<<1024, 256, 0, stream>>>(x1cl, S1, g1rr, g1ri, g1ii, n1br, n1bi,
                                          C1, 6, 4096 * 64, 1.f / 4096.f);

    // L2 GEMM (+BN2 stats) -> y2cl
    gemm_convt_bd<C1, 4, C2><<<dim3(32, 4, 4), 256, 0, stream>>>(x1cl, W2all, b2r, b2i, y2cl, S2);
    bn_apply_v2<<<2048, 256, 0, stream>>>(y2cl, S2, g2rr, g2ri, g2ii, n2br, n2bi,
                                          C2, 5, 16384 * 32, 1.f / 16384.f);

    // L3 GEMM (+BN3 stats) -> y3cl
    gemm_convt_bd<C2, 8, C3><<<dim3(128, 2, 4), 256, 0, stream>>>(y2cl, W3all, b3r, b3i, y3cl, S3);
    bn_apply_v2<<<4096, 256, 0, stream>>>(y3cl, S3, g3rr, g3ri, g3ii, n3br, n3bi,
                                          C3, 4, 65536 * 16, 1.f / 65536.f);

    // L4: MFMA + tanh -> d_out (real part, fp32), M-tile 256
    conv4_mfma<<<dim3(256, 1, 4), 256, 0, stream>>>(y3cl, W4all, b4r, (float*)d_out);
}

// Round 17
// 483.475 us; speedup vs baseline: 25.6588x; 1.0068x over previous
//
#include <hip/hip_runtime.h>
#include <hip/hip_bf16.h>
#include <math.h>

#define BATCH 256
#define LAT 100
#define NCLS 10
#define CIN0 110
#define C1 512
#define C2 256
#define C3 128
#define NCH 3
#define EPS 1e-5f

typedef __hip_bfloat16 bf16;
typedef short bf16x8 __attribute__((ext_vector_type(8)));
typedef float f32x4 __attribute__((ext_vector_type(4)));

__device__ __forceinline__ float b2f(bf16 v) { return __bfloat162float(v); }
__device__ __forceinline__ bf16 f2b(float v) { return __float2bfloat16(v); }
__device__ __forceinline__ float s2f(short s) {
    unsigned u = ((unsigned)(unsigned short)s) << 16;
    return __builtin_bit_cast(float, u);
}
__device__ __forceinline__ short f2s(float f) {
    bf16 b = __float2bfloat16(f);
    return *(short*)&b;
}

// ======== INTERLEAVED complex channel layout everywhere ========
// Activations: [spatial][2C] with channel index 2c+part (part 0=re, 1=im).
// GEMM k-order: tap-major sections of width 2*CIN; within a section q=2ci+p.
// B panels encode W accordingly; columns n' = 2c+part (pair-interleaved).

#define NB_W1 14336
#define NB_W2 32768
#define NB_W3 8192
#define NB_W4 256
#define NB_X0 224

__device__ __forceinline__ void w1prep_body(const float* wr, const float* wi, bf16* B, int idx) {
    if (idx >= 16384 * 224) return;
    int n = idx / 224, k = idx - n * 224;
    int p = n >> 10;                 // spatial position 0..15
    int c = (n & 1023) >> 1;         // channel
    int part = n & 1;
    int pk = k >= 112; int ci = k - pk * 112;
    float v = 0.f;
    if (ci < CIN0) {
        size_t widx = ((size_t)ci * C1 + c) * 16 + p;
        float vr = wr[widx], vi = wi[widx];
        v = (part == 0) ? (pk ? -vi : vr) : (pk ? vr : vi);
    }
    B[idx] = f2b(v);
}

template<int CIN, int N>
__device__ __forceinline__ void wprep_panel_body(const float* wr, const float* wi, bf16* W,
                                                 size_t idx) {
    constexpr int TWOK = 8 * CIN, C2I = 2 * CIN;
    size_t per_cls = (size_t)2 * N * TWOK;
    if (idx >= 4 * per_cls) return;
    int cls = (int)(idx / per_cls);
    size_t r = idx - (size_t)cls * per_cls;
    size_t chunk_nb = (size_t)TWOK * 128;
    int nb = (int)(r / chunk_nb);
    int r2 = (int)(r - (size_t)nb * chunk_nb);
    int kb = r2 >> 12;
    int w = r2 & 4095;
    int f = w >> 9;
    int l = (w >> 3) & 63;
    int j = w & 7;
    int n_virt = nb * 128 + (f >> 2) * 64 + (f & 3) * 16 + (l & 15);
    int k = kb * 32 + (l >> 4) * 8 + j;
    int c = n_virt >> 1, part = n_virt & 1;
    // interleaved k decode: tap-major, q = 2*ci + p
    int t = k / C2I;
    int q = k & (C2I - 1);
    int ci = q >> 1, p = q & 1;
    int py = cls >> 1, px = cls & 1;
    int a = t >> 1, e = t & 1;
    int kh = py ? (a ? 2 : 0) : (a ? 3 : 1);
    int kw = px ? (e ? 2 : 0) : (e ? 3 : 1);
    size_t widx = ((size_t)ci * N + c) * 16 + kh * 4 + kw;
    float vr = wr[widx], vi = wi[widx];
    float v = (part == 0) ? (p ? -vi : vr) : (p ? vr : vi);
    W[idx] = f2b(v);
}

__device__ __forceinline__ void wprep4_body(const float* wr, const float* wi, bf16* W, int idx) {
    if (idx >= 65536) return;
    int cls = idx >> 14, rem = idx & 16383;
    int py = cls >> 1, px = cls & 1;
    int n = rem >> 10, k = rem & 1023;
    float v = 0.f;
    if (n < NCH) {
        int t = k >> 8, q = k & 255;
        int ci = q >> 1, p = q & 1;
        int a = t >> 1, e = t & 1;
        int kh = py ? (a ? 2 : 0) : (a ? 3 : 1);
        int kw = px ? (e ? 2 : 0) : (e ? 3 : 1);
        size_t widx = ((size_t)ci * NCH + n) * 16 + kh * 4 + kw;
        v = p ? -wi[widx] : wr[widx];
    }
    W[idx] = f2b(v);
}

__device__ __forceinline__ void x0_body(const float* nre, const float* nim,
                                        const int* labels, const float* emb,
                                        bf16* A, int idx) {
    if (idx >= BATCH * 224) return;
    int b = idx / 224, k = idx - b * 224;
    int p = k >= 112; int ci = k - p * 112;
    float v = 0.f;
    if (ci < CIN0) {
        if (!p) v = (ci < LAT) ? nre[b * LAT + ci] : emb[labels[b] * NCLS + (ci - LAT)];
        else    v = (ci < LAT) ? nim[b * LAT + ci] : 0.f;
    }
    A[idx] = f2b(v);
}

__global__ void prep_combined(const float* __restrict__ w1r, const float* __restrict__ w1i,
                              const float* __restrict__ w2r, const float* __restrict__ w2i,
                              const float* __restrict__ w3r, const float* __restrict__ w3i,
                              const float* __restrict__ w4r, const float* __restrict__ w4i,
                              const float* __restrict__ nre, const float* __restrict__ nim,
                              const int* __restrict__ labels, const float* __restrict__ emb,
                              bf16* __restrict__ B1, bf16* __restrict__ W2all,
                              bf16* __restrict__ W3all, bf16* __restrict__ W4all,
                              bf16* __restrict__ x0bf) {
    int bid = blockIdx.x;
    if (bid < NB_W1) {
        w1prep_body(w1r, w1i, B1, bid * 256 + threadIdx.x);
    } else if (bid < NB_W1 + NB_W2) {
        wprep_panel_body<C1, C2>(w2r, w2i, W2all, (size_t)(bid - NB_W1) * 256 + threadIdx.x);
    } else if (bid < NB_W1 + NB_W2 + NB_W3) {
        wprep_panel_body<C2, C3>(w3r, w3i, W3all, (size_t)(bid - NB_W1 - NB_W2) * 256 + threadIdx.x);
    } else if (bid < NB_W1 + NB_W2 + NB_W3 + NB_W4) {
        wprep4_body(w4r, w4i, W4all, (bid - NB_W1 - NB_W2 - NB_W3) * 256 + threadIdx.x);
    } else {
        x0_body(nre, nim, labels, emb, x0bf,
                (bid - NB_W1 - NB_W2 - NB_W3 - NB_W4) * 256 + threadIdx.x);
    }
}

// ---------------- epilogue-stats helper: LDS reduce + global atomics ----------------
__device__ __forceinline__ void epi_stats_flush(float* red, float* Sstat, int Cn,
                                                int cBaseGlobal, int tid,
                                                const int* clArr, const float* s1,
                                                const float* s2, const float* sp, int isRe) {
    for (int i = tid; i < 320; i += 256) red[i] = 0.f;
    __syncthreads();
#pragma unroll
    for (int sn = 0; sn < 4; ++sn) {
        int cl = clArr[sn];
        if (isRe) {
            atomicAdd(&red[cl * 5 + 0], s1[sn]);
            atomicAdd(&red[cl * 5 + 2], s2[sn]);
            atomicAdd(&red[cl * 5 + 4], sp[sn]);
        } else {
            atomicAdd(&red[cl * 5 + 1], s1[sn]);
            atomicAdd(&red[cl * 5 + 3], s2[sn]);
        }
    }
    __syncthreads();
    for (int i = tid; i < 320; i += 256) {
        int cl = i / 5, st = i - cl * 5;
        atomicAdd(&Sstat[st * Cn + cBaseGlobal + cl], red[i]);
    }
}

// ---------------- gemm1 -> x1cl (interleaved), + BN1 stats ----------------
__global__ __launch_bounds__(256, 1) void gemm1(
    const bf16* __restrict__ A, const bf16* __restrict__ B,
    const float* __restrict__ b1r, const float* __restrict__ b1i,
    bf16* __restrict__ Y, float* __restrict__ Sstat) {
    __shared__ short As[128][40];
    __shared__ short Bs[128][40];
    const int tid = threadIdx.x;
    const int mBase = blockIdx.x * 128, nBase = blockIdx.y * 128;
    const int wid = tid >> 6, lane = tid & 63;
    const int wm = (wid >> 1) * 64, wn = (wid & 1) * 64;
    const int lm = lane & 15, lq = lane >> 4;

    f32x4 acc[4][4] = {};

    for (int k0 = 0; k0 < 224; k0 += 32) {
#pragma unroll
        for (int it = 0; it < 2; ++it) {
            int slot = tid + it * 256;
            int row = slot >> 2, kc = (slot & 3) * 8;
            int k = k0 + kc;
            *(uint4*)(&As[row][kc]) = *(const uint4*)(A + (size_t)(mBase + row) * 224 + k);
            *(uint4*)(&Bs[row][kc]) = *(const uint4*)(B + (size_t)(nBase + row) * 224 + k);
        }
        __syncthreads();
        bf16x8 af[4], bfr[4];
#pragma unroll
        for (int s = 0; s < 4; ++s) {
            af[s]  = *(const bf16x8*)(&As[wm + s * 16 + lm][lq * 8]);
            bfr[s] = *(const bf16x8*)(&Bs[wn + s * 16 + lm][lq * 8]);
        }
#pragma unroll
        for (int sm = 0; sm < 4; ++sm)
#pragma unroll
            for (int sn = 0; sn < 4; ++sn)
                acc[sm][sn] = __builtin_amdgcn_mfma_f32_16x16x32_bf16(af[sm], bfr[sn], acc[sm][sn], 0, 0, 0);
        __syncthreads();
    }

    float s1[4] = {}, s2[4] = {}, sp[4] = {};
    int clArr[4];
#pragma unroll
    for (int sn = 0; sn < 4; ++sn) clArr[sn] = (wn + sn * 16 + lm) >> 1;
    const int part = lm & 1;

#pragma unroll
    for (int sm = 0; sm < 4; ++sm) {
#pragma unroll
        for (int v = 0; v < 4; ++v) {
            int m = mBase + wm + sm * 16 + lq * 4 + v;
#pragma unroll
            for (int sn = 0; sn < 4; ++sn) {
                int n = nBase + wn + sn * 16 + lm;
                int c = (n & 1023) >> 1;
                float bias = part ? b1i[c] : b1r[c];
                float val = acc[sm][sn][v] + bias;
                float pv = __shfl_xor(val, 1, 64);
                s1[sn] += val; s2[sn] += val * val;
                if (!part) sp[sn] += val * pv;
                Y[(size_t)m * 16384 + n] = f2b(val);    // contiguous across lanes
            }
        }
    }
    epi_stats_flush((float*)As, Sstat, C1, (nBase & 1023) >> 1, tid, clArr, s1, s2, sp, !part);
}

// ---------------- BN apply+ReLU, interleaved single-stream, inline coef ----------------
__global__ void bn_apply_v2(bf16* __restrict__ Y, const float* __restrict__ S,
                            const float* __restrict__ grr, const float* __restrict__ gri,
                            const float* __restrict__ gii,
                            const float* __restrict__ betar, const float* __restrict__ betai,
                            int C, int total8, float invN) {
    int idx = blockIdx.x * 256 + threadIdx.x;
    if (idx >= total8) return;
    size_t base = (size_t)idx * 8;
    int c0 = ((int)(base & (size_t)(2 * C - 1))) >> 1;
    bf16x8 v8 = *(const bf16x8*)(Y + base);
    bf16x8 o8;
#pragma unroll
    for (int u = 0; u < 4; ++u) {
        int c = c0 + u;
        float sr = S[c], si = S[C + c], srr = S[2 * C + c], sii = S[3 * C + c], sri = S[4 * C + c];
        float mr = sr * invN, mi = si * invN;
        float crr = srr * invN - mr * mr + EPS;
        float cii = sii * invN - mi * mi + EPS;
        float cri = sri * invN - mr * mi;
        float s = sqrtf(crr * cii - cri * cri);
        float t = sqrtf(crr + cii + 2.f * s);
        float inv = 1.f / (s * t);
        float rrr = (cii + s) * inv, rii = (crr + s) * inv, rri = -cri * inv;
        float Grr = grr[c], Gri = gri[c], Gii = gii[c];
        float arr = Grr * rrr + Gri * rri, ari = Grr * rri + Gri * rii;
        float air = Gri * rrr + Gii * rri, aii = Gri * rri + Gii * rii;
        float cR = betar[c] - arr * mr - ari * mi;
        float cI = betai[c] - air * mr - aii * mi;
        float vr = s2f(v8[2 * u]), vi = s2f(v8[2 * u + 1]);
        o8[2 * u]     = f2s(fmaxf(arr * vr + ari * vi + cR, 0.f));
        o8[2 * u + 1] = f2s(fmaxf(air * vr + aii * vi + cI, 0.f));
    }
    *(bf16x8*)(Y + base) = o8;
}

// ---------------- MFMA GEMM 128x128, B direct, pipelined, interleaved layout ----------------
template<int CIN, int S, int N>
__global__ __launch_bounds__(256, 2) void gemm_convt_bd(
    const bf16* __restrict__ X, const bf16* __restrict__ Wall,
    const float* __restrict__ biasr, const float* __restrict__ biasi,
    bf16* __restrict__ Y, float* __restrict__ Sstat) {
    constexpr int TWOK = 8 * CIN, C2I = 2 * CIN, C2O = 2 * N, HOUT = 2 * S;
    constexpr int NSTEP = TWOK / 32;
    constexpr int CPS = C2I / 32;                 // 32-wide chunks per tap section
    constexpr int LOG_CPS = (CIN == 512) ? 5 : 4;
    __shared__ short As[2][128][40];
    const int cls = blockIdx.z;
    const int py = cls >> 1, px = cls & 1;
    const int tid = threadIdx.x;
    const int mBase = blockIdx.x * 128, nBase = blockIdx.y * 128;
    const int wid = tid >> 6, lane = tid & 63;
    const int wm = (wid >> 1) * 64, wn = (wid & 1) * 64;
    const int lm = lane & 15, lq = lane >> 4;
    const int dh0 = py ? 1 : 0, dh1 = py ? 0 : -1;
    const int dw0 = px ? 1 : 0, dw1 = px ? 0 : -1;

    const bf16* Wp = Wall
        + ((size_t)(cls * (C2O / 128) + blockIdx.y) * (TWOK / 32)) * 4096
        + ((wn >> 6) * 4) * 512 + lane * 8;

    int rowA[2], kcA[2];
    long offT[2][4];
#pragma unroll
    for (int it = 0; it < 2; ++it) {
        int slot = tid + it * 256;
        rowA[it] = slot >> 2; kcA[it] = (slot & 3) * 8;
        int m = mBase + rowA[it];
        int b = m / (S * S); int rem = m - b * (S * S);
        int i = rem / S, j = rem % S;
#pragma unroll
        for (int t = 0; t < 4; ++t) {
            int a = t >> 1, e = t & 1;
            int ih = i + (a ? dh1 : dh0);
            int iw = j + (e ? dw1 : dw0);
            offT[it][t] = ((unsigned)ih < (unsigned)S && (unsigned)iw < (unsigned)S)
                ? (long)((b * S + ih) * S + iw) * C2I : -1L;
        }
    }

    auto loadA = [&](int kb, uint4* av) {
        int t = kb >> LOG_CPS;
        int q0 = (kb & (CPS - 1)) << 5;
#pragma unroll
        for (int it = 0; it < 2; ++it) {
            long o = offT[it][t];
            uint4 v = {0u, 0u, 0u, 0u};
            if (o >= 0)
                v = *(const uint4*)(X + o + q0 + kcA[it]);
            av[it] = v;
        }
    };

    f32x4 acc[4][4] = {};
    bf16x8 bq[4];
#pragma unroll
    for (int sn = 0; sn < 4; ++sn) bq[sn] = *(const bf16x8*)(Wp + sn * 512);

    {
        uint4 av[2];
        loadA(0, av);
#pragma unroll
        for (int it = 0; it < 2; ++it) *(uint4*)(&As[0][rowA[it]][kcA[it]]) = av[it];
    }
    __syncthreads();

    for (int ks = 0; ks < NSTEP; ++ks) {
        const int cur = ks & 1;
        uint4 av[2];
        if (ks + 1 < NSTEP) loadA(ks + 1, av);
        bf16x8 bcur[4];
#pragma unroll
        for (int sn = 0; sn < 4; ++sn) bcur[sn] = bq[sn];
        if (ks + 1 < NSTEP) {
            const bf16* Wn = Wp + (size_t)(ks + 1) * 4096;
#pragma unroll
            for (int sn = 0; sn < 4; ++sn) bq[sn] = *(const bf16x8*)(Wn + sn * 512);
        }
        bf16x8 af[4];
#pragma unroll
        for (int s = 0; s < 4; ++s)
            af[s] = *(const bf16x8*)(&As[cur][wm + s * 16 + lm][lq * 8]);
#pragma unroll
        for (int sm = 0; sm < 4; ++sm)
#pragma unroll
            for (int sn = 0; sn < 4; ++sn)
                acc[sm][sn] = __builtin_amdgcn_mfma_f32_16x16x32_bf16(af[sm], bcur[sn], acc[sm][sn], 0, 0, 0);
        if (ks + 1 < NSTEP) {
#pragma unroll
            for (int it = 0; it < 2; ++it) *(uint4*)(&As[1 - cur][rowA[it]][kcA[it]]) = av[it];
        }
        __syncthreads();
    }

    float s1[4] = {}, s2[4] = {}, sp[4] = {};
    int clArr[4];
#pragma unroll
    for (int sn = 0; sn < 4; ++sn) clArr[sn] = (wn + sn * 16 + lm) >> 1;
    const int part = lm & 1;

#pragma unroll
    for (int sm = 0; sm < 4; ++sm) {
#pragma unroll
        for (int v = 0; v < 4; ++v) {
            int m = mBase + wm + sm * 16 + lq * 4 + v;
            int b = m / (S * S); int rem = m - b * (S * S);
            int i = rem / S, j = rem % S;
            int oh = 2 * i + py, ow = 2 * j + px;
            size_t rowoff = (size_t)((b * HOUT + oh) * HOUT + ow) * C2O;
#pragma unroll
            for (int sn = 0; sn < 4; ++sn) {
                int n = nBase + wn + sn * 16 + lm;
                int c = n >> 1;
                float bias = part ? biasi[c] : biasr[c];
                float val = acc[sm][sn][v] + bias;
                float pv = __shfl_xor(val, 1, 64);
                s1[sn] += val; s2[sn] += val * val;
                if (!part) sp[sn] += val * pv;
                Y[rowoff + n] = f2b(val);               // contiguous across lanes
            }
        }
    }
    epi_stats_flush((float*)As, Sstat, N, nBase >> 1, tid, clArr, s1, s2, sp, !part);
}

// ---------------- layer4 via MFMA, M-tile 256, interleaved X ----------------
__global__ __launch_bounds__(256, 2) void conv4_mfma(
    const bf16* __restrict__ X, const bf16* __restrict__ Wall,
    const float* __restrict__ br, float* __restrict__ out) {
    constexpr int S = 16, TWOK = 1024, C2I = 256;
    __shared__ short As[256][40];
    __shared__ short Bs[16][40];
    const int cls = blockIdx.z;
    const int py = cls >> 1, px = cls & 1;
    const bf16* W = Wall + (size_t)cls * 16 * TWOK;
    const int tid = threadIdx.x;
    const int mBase = blockIdx.x * 256;
    const int wid = tid >> 6, lane = tid & 63;
    const int wm = wid * 64;
    const int lm = lane & 15, lq = lane >> 4;
    const int dh0 = py ? 1 : 0, dh1 = py ? 0 : -1;
    const int dw0 = px ? 1 : 0, dw1 = px ? 0 : -1;

    int rowA[4], kcA[4];
    long offT[4][4];
#pragma unroll
    for (int it = 0; it < 4; ++it) {
        int slot = tid + it * 256;
        rowA[it] = slot >> 2; kcA[it] = (slot & 3) * 8;
        int m = mBase + rowA[it];
        int b = m >> 8; int rem = m & 255;
        int i = rem >> 4, j = rem & 15;
#pragma unroll
        for (int t = 0; t < 4; ++t) {
            int a = t >> 1, e = t & 1;
            int ih = i + (a ? dh1 : dh0);
            int iw = j + (e ? dw1 : dw0);
            offT[it][t] = ((unsigned)ih < (unsigned)S && (unsigned)iw < (unsigned)S)
                ? (long)((b * S + ih) * S + iw) * C2I : -1L;
        }
    }

    f32x4 acc[4] = {};

    for (int kb = 0; kb < TWOK / 32; ++kb) {
        int t = kb >> 3;              // 8 chunks per 256-wide tap section
        int q0 = (kb & 7) << 5;
#pragma unroll
        for (int it = 0; it < 4; ++it) {
            long o = offT[it][t];
            uint4 v = {0u, 0u, 0u, 0u};
            if (o >= 0)
                v = *(const uint4*)(X + o + q0 + kcA[it]);
            *(uint4*)(&As[rowA[it]][kcA[it]]) = v;
        }
        if (tid < 64) {
            int row = tid >> 2, kc = (tid & 3) * 8;
            uint4 w = *(const uint4*)(W + (size_t)row * TWOK + kb * 32 + kc);
            *(uint4*)(&Bs[row][kc]) = w;
        }
        __syncthreads();
        bf16x8 bfr = *(const bf16x8*)(&Bs[lm][lq * 8]);
#pragma unroll
        for (int s = 0; s < 4; ++s) {
            bf16x8 af = *(const bf16x8*)(&As[wm + s * 16 + lm][lq * 8]);
            acc[s] = __builtin_amdgcn_mfma_f32_16x16x32_bf16(af, bfr, acc[s], 0, 0, 0);
        }
        __syncthreads();
    }

    int n = lm;
    if (n < NCH) {
        float bias = br[n];
#pragma unroll
        for (int s = 0; s < 4; ++s) {
#pragma unroll
            for (int v = 0; v < 4; ++v) {
                int m = mBase + wm + s * 16 + lq * 4 + v;
                int b = m >> 8; int rem = m & 255;
                int i = rem >> 4, j = rem & 15;
                int oh = 2 * i + py, ow = 2 * j + px;
                out[((size_t)(b * NCH + n) * 32 + oh) * 32 + ow] = tanhf(acc[s][v] + bias);
            }
        }
    }
}

extern "C" void kernel_launch(void* const* d_in, const int* in_sizes, int n_in,
                              void* d_out, int out_size, void* d_ws, size_t ws_size,
                              hipStream_t stream) {
    const float* noise_re = (const float*)d_in[0];
    const float* noise_im = (const float*)d_in[1];
    const int*   labels   = (const int*)d_in[2];
    const float* emb      = (const float*)d_in[3];
    const float* w1r = (const float*)d_in[4],  *w1i = (const float*)d_in[5];
    const float* b1r = (const float*)d_in[6],  *b1i = (const float*)d_in[7];
    const float* g1rr = (const float*)d_in[8], *g1ri = (const float*)d_in[9], *g1ii = (const float*)d_in[10];
    const float* n1br = (const float*)d_in[11], *n1bi = (const float*)d_in[12];
    const float* w2r = (const float*)d_in[13], *w2i = (const float*)d_in[14];
    const float* b2r = (const float*)d_in[15], *b2i = (const float*)d_in[16];
    const float* g2rr = (const float*)d_in[17], *g2ri = (const float*)d_in[18], *g2ii = (const float*)d_in[19];
    const float* n2br = (const float*)d_in[20], *n2bi = (const float*)d_in[21];
    const float* w3r = (const float*)d_in[22], *w3i = (const float*)d_in[23];
    const float* b3r = (const float*)d_in[24], *b3i = (const float*)d_in[25];
    const float* g3rr = (const float*)d_in[26], *g3ri = (const float*)d_in[27], *g3ii = (const float*)d_in[28];
    const float* n3br = (const float*)d_in[29], *n3bi = (const float*)d_in[30];
    const float* w4r = (const float*)d_in[31], *w4i = (const float*)d_in[32];
    const float* b4r = (const float*)d_in[33], *b4i = (const float*)d_in[34];

    // ---- workspace layout (bytes) ---- (same as R16)
    char* ws = (char*)d_ws;
    bf16* y3cl = (bf16*)ws;
    bf16* x1cl = (bf16*)ws;
    bf16* B1    = (bf16*)(ws + 8388608);
    bf16* W2all = (bf16*)(ws + 15728640);
    bf16* y2cl  = (bf16*)(ws + 33554432);
    bf16* W3all = (bf16*)(ws + 50331648);
    bf16* x0bf  = (bf16*)(ws + 54547456);
    bf16* W4all = (bf16*)(ws + 54662144);
    float* S1 = (float*)(ws + 54793216);
    float* S2 = (float*)(ws + 54803456);
    float* S3 = (float*)(ws + 54808576);

    (void)hipMemsetAsync(S1, 0, 17920, stream);   // zeros S1,S2,S3 (contiguous)

    prep_combined<<<NB_W1 + NB_W2 + NB_W3 + NB_W4 + NB_X0, 256, 0, stream>>>(
        w1r, w1i, w2r, w2i, w3r, w3i, w4r, w4i,
        noise_re, noise_im, labels, emb,
        B1, W2all, W3all, W4all, x0bf);

    // L1 GEMM (+BN1 stats) -> x1cl (interleaved)
    gemm1<<<dim3(2, 128), 256, 0, stream>>>(x0bf, B1, b1r, b1i, x1cl, S1);
    bn_apply_v2<<<2048, 256, 0, stream>>>(x1cl, S1, g1rr, g1ri, g1ii, n1br, n1bi,
                                          C1, 524288, 1.f / 4096.f);

    // L2 GEMM (+BN2 stats) -> y2cl
    gemm_convt_bd<C1, 4, C2><<<dim3(32, 4, 4), 256, 0, stream>>>(x1cl, W2all, b2r, b2i, y2cl, S2);
    bn_apply_v2<<<4096, 256, 0, stream>>>(y2cl, S2, g2rr, g2ri, g2ii, n2br, n2bi,
                                          C2, 1048576, 1.f / 16384.f);

    // L3 GEMM (+BN3 stats) -> y3cl
    gemm_convt_bd<C2, 8, C3><<<dim3(128, 2, 4), 256, 0, stream>>>(y2cl, W3all, b3r, b3i, y3cl, S3);
    bn_apply_v2<<<8192, 256, 0, stream>>>(y3cl, S3, g3rr, g3ri, g3ii, n3br, n3bi,
                                          C3, 2097152, 1.f / 65536.f);

    // L4: MFMA + tanh -> d_out (real part, fp32), M-tile 256
    conv4_mfma<<<dim3(256, 1, 4), 256, 0, stream>>>(y3cl, W4all, b4r, (float*)d_out);
}

// Round 18
// 463.737 us; speedup vs baseline: 26.7509x; 1.0426x over previous
//
#include <hip/hip_runtime.h>
#include <hip/hip_bf16.h>
#include <math.h>

#define BATCH 256
#define LAT 100
#define NCLS 10
#define CIN0 110
#define C1 512
#define C2 256
#define C3 128
#define NCH 3
#define EPS 1e-5f
#define NCOPY 8

typedef __hip_bfloat16 bf16;
typedef short bf16x8 __attribute__((ext_vector_type(8)));
typedef float f32x4 __attribute__((ext_vector_type(4)));

__device__ __forceinline__ float b2f(bf16 v) { return __bfloat162float(v); }
__device__ __forceinline__ bf16 f2b(float v) { return __float2bfloat16(v); }
__device__ __forceinline__ float s2f(short s) {
    unsigned u = ((unsigned)(unsigned short)s) << 16;
    return __builtin_bit_cast(float, u);
}
__device__ __forceinline__ short f2s(float f) {
    bf16 b = __float2bfloat16(f);
    return *(short*)&b;
}

// ======== INTERLEAVED complex channel layout everywhere ========
// Activations: [spatial][2C], channel index 2c+part. GEMM k-order: tap-major
// sections of width 2*CIN, q=2ci+p within a section. B-panel columns n'=2c+part.

#define NB_W1 14336
#define NB_W2 32768
#define NB_W3 8192
#define NB_W4 256
#define NB_X0 224

__device__ __forceinline__ void w1prep_body(const float* wr, const float* wi, bf16* B, int idx) {
    if (idx >= 16384 * 224) return;
    int n = idx / 224, k = idx - n * 224;
    int p = n >> 10;
    int c = (n & 1023) >> 1;
    int part = n & 1;
    int pk = k >= 112; int ci = k - pk * 112;
    float v = 0.f;
    if (ci < CIN0) {
        size_t widx = ((size_t)ci * C1 + c) * 16 + p;
        float vr = wr[widx], vi = wi[widx];
        v = (part == 0) ? (pk ? -vi : vr) : (pk ? vr : vi);
    }
    B[idx] = f2b(v);
}

template<int CIN, int N>
__device__ __forceinline__ void wprep_panel_body(const float* wr, const float* wi, bf16* W,
                                                 size_t idx) {
    constexpr int TWOK = 8 * CIN, C2I = 2 * CIN;
    size_t per_cls = (size_t)2 * N * TWOK;
    if (idx >= 4 * per_cls) return;
    int cls = (int)(idx / per_cls);
    size_t r = idx - (size_t)cls * per_cls;
    size_t chunk_nb = (size_t)TWOK * 128;
    int nb = (int)(r / chunk_nb);
    int r2 = (int)(r - (size_t)nb * chunk_nb);
    int kb = r2 >> 12;
    int w = r2 & 4095;
    int f = w >> 9;
    int l = (w >> 3) & 63;
    int j = w & 7;
    int n_virt = nb * 128 + (f >> 2) * 64 + (f & 3) * 16 + (l & 15);
    int k = kb * 32 + (l >> 4) * 8 + j;
    int c = n_virt >> 1, part = n_virt & 1;
    int t = k / C2I;
    int q = k & (C2I - 1);
    int ci = q >> 1, p = q & 1;
    int py = cls >> 1, px = cls & 1;
    int a = t >> 1, e = t & 1;
    int kh = py ? (a ? 2 : 0) : (a ? 3 : 1);
    int kw = px ? (e ? 2 : 0) : (e ? 3 : 1);
    size_t widx = ((size_t)ci * N + c) * 16 + kh * 4 + kw;
    float vr = wr[widx], vi = wi[widx];
    float v = (part == 0) ? (p ? -vi : vr) : (p ? vr : vi);
    W[idx] = f2b(v);
}

__device__ __forceinline__ void wprep4_body(const float* wr, const float* wi, bf16* W, int idx) {
    if (idx >= 65536) return;
    int cls = idx >> 14, rem = idx & 16383;
    int py = cls >> 1, px = cls & 1;
    int n = rem >> 10, k = rem & 1023;
    float v = 0.f;
    if (n < NCH) {
        int t = k >> 8, q = k & 255;
        int ci = q >> 1, p = q & 1;
        int a = t >> 1, e = t & 1;
        int kh = py ? (a ? 2 : 0) : (a ? 3 : 1);
        int kw = px ? (e ? 2 : 0) : (e ? 3 : 1);
        size_t widx = ((size_t)ci * NCH + n) * 16 + kh * 4 + kw;
        v = p ? -wi[widx] : wr[widx];
    }
    W[idx] = f2b(v);
}

__device__ __forceinline__ void x0_body(const float* nre, const float* nim,
                                        const int* labels, const float* emb,
                                        bf16* A, int idx) {
    if (idx >= BATCH * 224) return;
    int b = idx / 224, k = idx - b * 224;
    int p = k >= 112; int ci = k - p * 112;
    float v = 0.f;
    if (ci < CIN0) {
        if (!p) v = (ci < LAT) ? nre[b * LAT + ci] : emb[labels[b] * NCLS + (ci - LAT)];
        else    v = (ci < LAT) ? nim[b * LAT + ci] : 0.f;
    }
    A[idx] = f2b(v);
}

__global__ void prep_combined(const float* __restrict__ w1r, const float* __restrict__ w1i,
                              const float* __restrict__ w2r, const float* __restrict__ w2i,
                              const float* __restrict__ w3r, const float* __restrict__ w3i,
                              const float* __restrict__ w4r, const float* __restrict__ w4i,
                              const float* __restrict__ nre, const float* __restrict__ nim,
                              const int* __restrict__ labels, const float* __restrict__ emb,
                              bf16* __restrict__ B1, bf16* __restrict__ W2all,
                              bf16* __restrict__ W3all, bf16* __restrict__ W4all,
                              bf16* __restrict__ x0bf) {
    int bid = blockIdx.x;
    if (bid < NB_W1) {
        w1prep_body(w1r, w1i, B1, bid * 256 + threadIdx.x);
    } else if (bid < NB_W1 + NB_W2) {
        wprep_panel_body<C1, C2>(w2r, w2i, W2all, (size_t)(bid - NB_W1) * 256 + threadIdx.x);
    } else if (bid < NB_W1 + NB_W2 + NB_W3) {
        wprep_panel_body<C2, C3>(w3r, w3i, W3all, (size_t)(bid - NB_W1 - NB_W2) * 256 + threadIdx.x);
    } else if (bid < NB_W1 + NB_W2 + NB_W3 + NB_W4) {
        wprep4_body(w4r, w4i, W4all, (bid - NB_W1 - NB_W2 - NB_W3) * 256 + threadIdx.x);
    } else {
        x0_body(nre, nim, labels, emb, x0bf,
                (bid - NB_W1 - NB_W2 - NB_W3 - NB_W4) * 256 + threadIdx.x);
    }
}

// ------- epilogue-stats: lq-shfl pre-reduce -> LDS -> atomics into XCD-sharded copy -------
// Scopy points at copy base ( [5][Cn] floats ). clArr channels valid for lanes (all lq).
__device__ __forceinline__ void epi_stats_flush(float* red, float* Scopy, int Cn,
                                                int cBaseGlobal, int tid, int lq,
                                                const int* clArr, float* s1,
                                                float* s2, float* sp, int isRe) {
    for (int i = tid; i < 320; i += 256) red[i] = 0.f;
    __syncthreads();
#pragma unroll
    for (int sn = 0; sn < 4; ++sn) {
        s1[sn] += __shfl_xor(s1[sn], 16, 64); s1[sn] += __shfl_xor(s1[sn], 32, 64);
        s2[sn] += __shfl_xor(s2[sn], 16, 64); s2[sn] += __shfl_xor(s2[sn], 32, 64);
        sp[sn] += __shfl_xor(sp[sn], 16, 64); sp[sn] += __shfl_xor(sp[sn], 32, 64);
    }
    if (lq == 0) {
#pragma unroll
        for (int sn = 0; sn < 4; ++sn) {
            int cl = clArr[sn];
            if (isRe) {
                atomicAdd(&red[cl * 5 + 0], s1[sn]);
                atomicAdd(&red[cl * 5 + 2], s2[sn]);
                atomicAdd(&red[cl * 5 + 4], sp[sn]);
            } else {
                atomicAdd(&red[cl * 5 + 1], s1[sn]);
                atomicAdd(&red[cl * 5 + 3], s2[sn]);
            }
        }
    }
    __syncthreads();
    for (int i = tid; i < 320; i += 256) {
        int cl = i / 5, st = i - cl * 5;
        atomicAdd(&Scopy[st * Cn + cBaseGlobal + cl], red[i]);
    }
}

// ---------------- gemm1 -> x1cl (interleaved), + BN1 stats ----------------
__global__ __launch_bounds__(256, 1) void gemm1(
    const bf16* __restrict__ A, const bf16* __restrict__ B,
    const float* __restrict__ b1r, const float* __restrict__ b1i,
    bf16* __restrict__ Y, float* __restrict__ Sstat) {
    __shared__ short As[128][40];
    __shared__ short Bs[128][40];
    const int tid = threadIdx.x;
    const int mBase = blockIdx.x * 128, nBase = blockIdx.y * 128;
    const int wid = tid >> 6, lane = tid & 63;
    const int wm = (wid >> 1) * 64, wn = (wid & 1) * 64;
    const int lm = lane & 15, lq = lane >> 4;

    f32x4 acc[4][4] = {};

    for (int k0 = 0; k0 < 224; k0 += 32) {
#pragma unroll
        for (int it = 0; it < 2; ++it) {
            int slot = tid + it * 256;
            int row = slot >> 2, kc = (slot & 3) * 8;
            int k = k0 + kc;
            *(uint4*)(&As[row][kc]) = *(const uint4*)(A + (size_t)(mBase + row) * 224 + k);
            *(uint4*)(&Bs[row][kc]) = *(const uint4*)(B + (size_t)(nBase + row) * 224 + k);
        }
        __syncthreads();
        bf16x8 af[4], bfr[4];
#pragma unroll
        for (int s = 0; s < 4; ++s) {
            af[s]  = *(const bf16x8*)(&As[wm + s * 16 + lm][lq * 8]);
            bfr[s] = *(const bf16x8*)(&Bs[wn + s * 16 + lm][lq * 8]);
        }
#pragma unroll
        for (int sm = 0; sm < 4; ++sm)
#pragma unroll
            for (int sn = 0; sn < 4; ++sn)
                acc[sm][sn] = __builtin_amdgcn_mfma_f32_16x16x32_bf16(af[sm], bfr[sn], acc[sm][sn], 0, 0, 0);
        __syncthreads();
    }

    float s1[4] = {}, s2[4] = {}, sp[4] = {};
    int clArr[4];
#pragma unroll
    for (int sn = 0; sn < 4; ++sn) clArr[sn] = (wn + sn * 16 + lm) >> 1;
    const int part = lm & 1;

#pragma unroll
    for (int sm = 0; sm < 4; ++sm) {
#pragma unroll
        for (int v = 0; v < 4; ++v) {
            int m = mBase + wm + sm * 16 + lq * 4 + v;
#pragma unroll
            for (int sn = 0; sn < 4; ++sn) {
                int n = nBase + wn + sn * 16 + lm;
                int c = (n & 1023) >> 1;
                float bias = part ? b1i[c] : b1r[c];
                float val = acc[sm][sn][v] + bias;
                float pv = __shfl_xor(val, 1, 64);
                s1[sn] += val; s2[sn] += val * val;
                if (!part) sp[sn] += val * pv;
                Y[(size_t)m * 16384 + n] = f2b(val);
            }
        }
    }
    int copy = (blockIdx.y * gridDim.x + blockIdx.x) & (NCOPY - 1);
    epi_stats_flush((float*)As, Sstat + (size_t)copy * 5 * C1, C1,
                    (nBase & 1023) >> 1, tid, lq, clArr, s1, s2, sp, !part);
}

// ------- BN apply+ReLU: block-cooperative fold of NCOPY stat copies -> LDS coefs -------
__global__ void bn_apply_v3(bf16* __restrict__ Y, const float* __restrict__ Scopies,
                            const float* __restrict__ grr, const float* __restrict__ gri,
                            const float* __restrict__ gii,
                            const float* __restrict__ betar, const float* __restrict__ betai,
                            int C, int total8, float invN) {
    __shared__ float coefs[6][512];
    for (int c = threadIdx.x; c < C; c += 256) {
        float sr = 0, si = 0, srr = 0, sii = 0, sri = 0;
        for (int cp = 0; cp < NCOPY; ++cp) {
            const float* S = Scopies + (size_t)cp * 5 * C;
            sr += S[c]; si += S[C + c]; srr += S[2 * C + c]; sii += S[3 * C + c]; sri += S[4 * C + c];
        }
        float mr = sr * invN, mi = si * invN;
        float crr = srr * invN - mr * mr + EPS;
        float cii = sii * invN - mi * mi + EPS;
        float cri = sri * invN - mr * mi;
        float s = sqrtf(crr * cii - cri * cri);
        float t = sqrtf(crr + cii + 2.f * s);
        float inv = 1.f / (s * t);
        float rrr = (cii + s) * inv, rii = (crr + s) * inv, rri = -cri * inv;
        float Grr = grr[c], Gri = gri[c], Gii = gii[c];
        float arr = Grr * rrr + Gri * rri, ari = Grr * rri + Gri * rii;
        float air = Gri * rrr + Gii * rri, aii = Gri * rri + Gii * rii;
        coefs[0][c] = arr; coefs[1][c] = ari;
        coefs[2][c] = betar[c] - arr * mr - ari * mi;
        coefs[3][c] = air; coefs[4][c] = aii;
        coefs[5][c] = betai[c] - air * mr - aii * mi;
    }
    __syncthreads();
    int idx = blockIdx.x * 256 + threadIdx.x;
    if (idx >= total8) return;
    size_t base = (size_t)idx * 8;
    int c0 = ((int)(base & (size_t)(2 * C - 1))) >> 1;
    bf16x8 v8 = *(const bf16x8*)(Y + base);
    bf16x8 o8;
#pragma unroll
    for (int u = 0; u < 4; ++u) {
        int c = c0 + u;
        float vr = s2f(v8[2 * u]), vi = s2f(v8[2 * u + 1]);
        o8[2 * u]     = f2s(fmaxf(coefs[0][c] * vr + coefs[1][c] * vi + coefs[2][c], 0.f));
        o8[2 * u + 1] = f2s(fmaxf(coefs[3][c] * vr + coefs[4][c] * vi + coefs[5][c], 0.f));
    }
    *(bf16x8*)(Y + base) = o8;
}

// ---------------- MFMA GEMM 128x128, B direct, pipelined, interleaved layout ----------------
template<int CIN, int S, int N>
__global__ __launch_bounds__(256, 2) void gemm_convt_bd(
    const bf16* __restrict__ X, const bf16* __restrict__ Wall,
    const float* __restrict__ biasr, const float* __restrict__ biasi,
    bf16* __restrict__ Y, float* __restrict__ Sstat) {
    constexpr int TWOK = 8 * CIN, C2I = 2 * CIN, C2O = 2 * N, HOUT = 2 * S;
    constexpr int NSTEP = TWOK / 32;
    constexpr int CPS = C2I / 32;
    constexpr int LOG_CPS = (CIN == 512) ? 5 : 4;
    __shared__ short As[2][128][40];
    const int cls = blockIdx.z;
    const int py = cls >> 1, px = cls & 1;
    const int tid = threadIdx.x;
    const int mBase = blockIdx.x * 128, nBase = blockIdx.y * 128;
    const int wid = tid >> 6, lane = tid & 63;
    const int wm = (wid >> 1) * 64, wn = (wid & 1) * 64;
    const int lm = lane & 15, lq = lane >> 4;
    const int dh0 = py ? 1 : 0, dh1 = py ? 0 : -1;
    const int dw0 = px ? 1 : 0, dw1 = px ? 0 : -1;

    const bf16* Wp = Wall
        + ((size_t)(cls * (C2O / 128) + blockIdx.y) * (TWOK / 32)) * 4096
        + ((wn >> 6) * 4) * 512 + lane * 8;

    int rowA[2], kcA[2];
    long offT[2][4];
#pragma unroll
    for (int it = 0; it < 2; ++it) {
        int slot = tid + it * 256;
        rowA[it] = slot >> 2; kcA[it] = (slot & 3) * 8;
        int m = mBase + rowA[it];
        int b = m / (S * S); int rem = m - b * (S * S);
        int i = rem / S, j = rem % S;
#pragma unroll
        for (int t = 0; t < 4; ++t) {
            int a = t >> 1, e = t & 1;
            int ih = i + (a ? dh1 : dh0);
            int iw = j + (e ? dw1 : dw0);
            offT[it][t] = ((unsigned)ih < (unsigned)S && (unsigned)iw < (unsigned)S)
                ? (long)((b * S + ih) * S + iw) * C2I : -1L;
        }
    }

    auto loadA = [&](int kb, uint4* av) {
        int t = kb >> LOG_CPS;
        int q0 = (kb & (CPS - 1)) << 5;
#pragma unroll
        for (int it = 0; it < 2; ++it) {
            long o = offT[it][t];
            uint4 v = {0u, 0u, 0u, 0u};
            if (o >= 0)
                v = *(const uint4*)(X + o + q0 + kcA[it]);
            av[it] = v;
        }
    };

    f32x4 acc[4][4] = {};
    bf16x8 bq[4];
#pragma unroll
    for (int sn = 0; sn < 4; ++sn) bq[sn] = *(const bf16x8*)(Wp + sn * 512);

    {
        uint4 av[2];
        loadA(0, av);
#pragma unroll
        for (int it = 0; it < 2; ++it) *(uint4*)(&As[0][rowA[it]][kcA[it]]) = av[it];
    }
    __syncthreads();

    for (int ks = 0; ks < NSTEP; ++ks) {
        const int cur = ks & 1;
        uint4 av[2];
        if (ks + 1 < NSTEP) loadA(ks + 1, av);
        bf16x8 bcur[4];
#pragma unroll
        for (int sn = 0; sn < 4; ++sn) bcur[sn] = bq[sn];
        if (ks + 1 < NSTEP) {
            const bf16* Wn = Wp + (size_t)(ks + 1) * 4096;
#pragma unroll
            for (int sn = 0; sn < 4; ++sn) bq[sn] = *(const bf16x8*)(Wn + sn * 512);
        }
        bf16x8 af[4];
#pragma unroll
        for (int s = 0; s < 4; ++s)
            af[s] = *(const bf16x8*)(&As[cur][wm + s * 16 + lm][lq * 8]);
#pragma unroll
        for (int sm = 0; sm < 4; ++sm)
#pragma unroll
            for (int sn = 0; sn < 4; ++sn)
                acc[sm][sn] = __builtin_amdgcn_mfma_f32_16x16x32_bf16(af[sm], bcur[sn], acc[sm][sn], 0, 0, 0);
        if (ks + 1 < NSTEP) {
#pragma unroll
            for (int it = 0; it < 2; ++it) *(uint4*)(&As[1 - cur][rowA[it]][kcA[it]]) = av[it];
        }
        __syncthreads();
    }

    float s1[4] = {}, s2[4] = {}, sp[4] = {};
    int clArr[4];
#pragma unroll
    for (int sn = 0; sn < 4; ++sn) clArr[sn] = (wn + sn * 16 + lm) >> 1;
    const int part = lm & 1;

#pragma unroll
    for (int sm = 0; sm < 4; ++sm) {
#pragma unroll
        for (int v = 0; v < 4; ++v) {
            int m = mBase + wm + sm * 16 + lq * 4 + v;
            int b = m / (S * S); int rem = m - b * (S * S);
            int i = rem / S, j = rem % S;
            int oh = 2 * i + py, ow = 2 * j + px;
            size_t rowoff = (size_t)((b * HOUT + oh) * HOUT + ow) * C2O;
#pragma unroll
            for (int sn = 0; sn < 4; ++sn) {
                int n = nBase + wn + sn * 16 + lm;
                int c = n >> 1;
                float bias = part ? biasi[c] : biasr[c];
                float val = acc[sm][sn][v] + bias;
                float pv = __shfl_xor(val, 1, 64);
                s1[sn] += val; s2[sn] += val * val;
                if (!part) sp[sn] += val * pv;
                Y[rowoff + n] = f2b(val);
            }
        }
    }
    int copy = ((blockIdx.z * gridDim.y + blockIdx.y) * gridDim.x + blockIdx.x) & (NCOPY - 1);
    epi_stats_flush((float*)As, Sstat + (size_t)copy * 5 * N, N,
                    nBase >> 1, tid, lq, clArr, s1, s2, sp, !part);
}

// ---------------- layer4 via MFMA, M-tile 256, interleaved X ----------------
__global__ __launch_bounds__(256, 2) void conv4_mfma(
    const bf16* __restrict__ X, const bf16* __restrict__ Wall,
    const float* __restrict__ br, float* __restrict__ out) {
    constexpr int S = 16, TWOK = 1024, C2I = 256;
    __shared__ short As[256][40];
    __shared__ short Bs[16][40];
    const int cls = blockIdx.z;
    const int py = cls >> 1, px = cls & 1;
    const bf16* W = Wall + (size_t)cls * 16 * TWOK;
    const int tid = threadIdx.x;
    const int mBase = blockIdx.x * 256;
    const int wid = tid >> 6, lane = tid & 63;
    const int wm = wid * 64;
    const int lm = lane & 15, lq = lane >> 4;
    const int dh0 = py ? 1 : 0, dh1 = py ? 0 : -1;
    const int dw0 = px ? 1 : 0, dw1 = px ? 0 : -1;

    int rowA[4], kcA[4];
    long offT[4][4];
#pragma unroll
    for (int it = 0; it < 4; ++it) {
        int slot = tid + it * 256;
        rowA[it] = slot >> 2; kcA[it] = (slot & 3) * 8;
        int m = mBase + rowA[it];
        int b = m >> 8; int rem = m & 255;
        int i = rem >> 4, j = rem & 15;
#pragma unroll
        for (int t = 0; t < 4; ++t) {
            int a = t >> 1, e = t & 1;
            int ih = i + (a ? dh1 : dh0);
            int iw = j + (e ? dw1 : dw0);
            offT[it][t] = ((unsigned)ih < (unsigned)S && (unsigned)iw < (unsigned)S)
                ? (long)((b * S + ih) * S + iw) * C2I : -1L;
        }
    }

    f32x4 acc[4] = {};

    for (int kb = 0; kb < TWOK / 32; ++kb) {
        int t = kb >> 3;
        int q0 = (kb & 7) << 5;
#pragma unroll
        for (int it = 0; it < 4; ++it) {
            long o = offT[it][t];
            uint4 v = {0u, 0u, 0u, 0u};
            if (o >= 0)
                v = *(const uint4*)(X + o + q0 + kcA[it]);
            *(uint4*)(&As[rowA[it]][kcA[it]]) = v;
        }
        if (tid < 64) {
            int row = tid >> 2, kc = (tid & 3) * 8;
            uint4 w = *(const uint4*)(W + (size_t)row * TWOK + kb * 32 + kc);
            *(uint4*)(&Bs[row][kc]) = w;
        }
        __syncthreads();
        bf16x8 bfr = *(const bf16x8*)(&Bs[lm][lq * 8]);
#pragma unroll
        for (int s = 0; s < 4; ++s) {
            bf16x8 af = *(const bf16x8*)(&As[wm + s * 16 + lm][lq * 8]);
            acc[s] = __builtin_amdgcn_mfma_f32_16x16x32_bf16(af, bfr, acc[s], 0, 0, 0);
        }
        __syncthreads();
    }

    int n = lm;
    if (n < NCH) {
        float bias = br[n];
#pragma unroll
        for (int s = 0; s < 4; ++s) {
#pragma unroll
            for (int v = 0; v < 4; ++v) {
                int m = mBase + wm + s * 16 + lq * 4 + v;
                int b = m >> 8; int rem = m & 255;
                int i = rem >> 4, j = rem & 15;
                int oh = 2 * i + py, ow = 2 * j + px;
                out[((size_t)(b * NCH + n) * 32 + oh) * 32 + ow] = tanhf(acc[s][v] + bias);
            }
        }
    }
}

extern "C" void kernel_launch(void* const* d_in, const int* in_sizes, int n_in,
                              void* d_out, int out_size, void* d_ws, size_t ws_size,
                              hipStream_t stream) {
    const float* noise_re = (const float*)d_in[0];
    const float* noise_im = (const float*)d_in[1];
    const int*   labels   = (const int*)d_in[2];
    const float* emb      = (const float*)d_in[3];
    const float* w1r = (const float*)d_in[4],  *w1i = (const float*)d_in[5];
    const float* b1r = (const float*)d_in[6],  *b1i = (const float*)d_in[7];
    const float* g1rr = (const float*)d_in[8], *g1ri = (const float*)d_in[9], *g1ii = (const float*)d_in[10];
    const float* n1br = (const float*)d_in[11], *n1bi = (const float*)d_in[12];
    const float* w2r = (const float*)d_in[13], *w2i = (const float*)d_in[14];
    const float* b2r = (const float*)d_in[15], *b2i = (const float*)d_in[16];
    const float* g2rr = (const float*)d_in[17], *g2ri = (const float*)d_in[18], *g2ii = (const float*)d_in[19];
    const float* n2br = (const float*)d_in[20], *n2bi = (const float*)d_in[21];
    const float* w3r = (const float*)d_in[22], *w3i = (const float*)d_in[23];
    const float* b3r = (const float*)d_in[24], *b3i = (const float*)d_in[25];
    const float* g3rr = (const float*)d_in[26], *g3ri = (const float*)d_in[27], *g3ii = (const float*)d_in[28];
    const float* n3br = (const float*)d_in[29], *n3bi = (const float*)d_in[30];
    const float* w4r = (const float*)d_in[31], *w4i = (const float*)d_in[32];
    const float* b4r = (const float*)d_in[33], *b4i = (const float*)d_in[34];

    // ---- workspace layout (bytes) ----
    // y3cl [0, 33554432). Overlays (dead before gemmL3):
    //   x1cl [0, 8388608) ; B1 [8388608, 15728640) ; W2all [15728640, 32505856)
    // y2cl  [33554432, 50331648)
    // W3all [50331648, 54525952)
    // tail: x0bf [54547456) W4all [54662144, 54793216)
    //   stat copies (NCOPY=8): S1 [54793216, +81920) S2 [54875136, +40960) S3 [54916096, +20480)
    char* ws = (char*)d_ws;
    bf16* y3cl = (bf16*)ws;
    bf16* x1cl = (bf16*)ws;
    bf16* B1    = (bf16*)(ws + 8388608);
    bf16* W2all = (bf16*)(ws + 15728640);
    bf16* y2cl  = (bf16*)(ws + 33554432);
    bf16* W3all = (bf16*)(ws + 50331648);
    bf16* x0bf  = (bf16*)(ws + 54547456);
    bf16* W4all = (bf16*)(ws + 54662144);
    float* S1 = (float*)(ws + 54793216);
    float* S2 = (float*)(ws + 54875136);
    float* S3 = (float*)(ws + 54916096);

    (void)hipMemsetAsync(S1, 0, 143360, stream);   // zeros all 8 copies of S1,S2,S3

    prep_combined<<<NB_W1 + NB_W2 + NB_W3 + NB_W4 + NB_X0, 256, 0, stream>>>(
        w1r, w1i, w2r, w2i, w3r, w3i, w4r, w4i,
        noise_re, noise_im, labels, emb,
        B1, W2all, W3all, W4all, x0bf);

    // L1 GEMM (+BN1 stats, sharded) -> x1cl
    gemm1<<<dim3(2, 128), 256, 0, stream>>>(x0bf, B1, b1r, b1i, x1cl, S1);
    bn_apply_v3<<<2048, 256, 0, stream>>>(x1cl, S1, g1rr, g1ri, g1ii, n1br, n1bi,
                                          C1, 524288, 1.f / 4096.f);

    // L2 GEMM (+BN2 stats) -> y2cl
    gemm_convt_bd<C1, 4, C2><<<dim3(32, 4, 4), 256, 0, stream>>>(x1cl, W2all, b2r, b2i, y2cl, S2);
    bn_apply_v3<<<4096, 256, 0, stream>>>(y2cl, S2, g2rr, g2ri, g2ii, n2br, n2bi,
                                          C2, 1048576, 1.f / 16384.f);

    // L3 GEMM (+BN3 stats) -> y3cl
    gemm_convt_bd<C2, 8, C3><<<dim3(128, 2, 4), 256, 0, stream>>>(y2cl, W3all, b3r, b3i, y3cl, S3);
    bn_apply_v3<<<8192, 256, 0, stream>>>(y3cl, S3, g3rr, g3ri, g3ii, n3br, n3bi,
                                          C3, 2097152, 1.f / 65536.f);

    // L4: MFMA + tanh -> d_out (real part, fp32), M-tile 256
    conv4_mfma<<<dim3(256, 1, 4), 256, 0, stream>>>(y3cl, W4all, b4r, (float*)d_out);
}